// Round 16
// baseline (376.999 us; speedup 1.0000x reference)
//
#include <hip/hip_runtime.h>
#include <math.h>

namespace {
constexpr int NB   = 256;          // graphs
constexpr int EPG  = 8192;         // edges per graph
constexpr int ETOT = NB * EPG;     // 2,097,152
constexpr int FH   = 64;           // hidden dim
constexpr int NN0  = NB * 512;     // 131072 nodes at full size
}

// ---- scratch (device globals: write-before-read each call, deterministic) ----
__device__ float g_feat[3][(size_t)NN0 * FH];   // rotating node-feature buffers
__device__ float g_xs[NB * 6 * FH];             // jumping-knowledge concat
__device__ int   g_esrc[2][ETOT];               // compacted edges (stage 0/1)
__device__ int   g_edst[2][ETOT];
__device__ int   g_ecnt[2][NB];
__device__ unsigned short g_csr[ETOT];          // shared CSR (built once/call)
__device__ unsigned int   g_deg[NN0], g_start[NN0];

// ============================================================================
// Dual matmul: zr = x@Wr ; xl = x@Wl + b
// v7: RPB=128 (16 rows/thread); fmaf chains; k4 loop pinned no-unroll
// (v3 lesson: unroll -> weight-load hoist -> 256 VGPR -> spill).
// ============================================================================
template<int K>
__global__ __launch_bounds__(256)
void mm_dual(const float* __restrict__ xext, int in_idx,
             const float* __restrict__ Wr, const float* __restrict__ Wl,
             const float* __restrict__ bias, int zr_idx, int xl_idx)
{
  constexpr int RPB = 128;          // rows per block
  constexpr int KC  = 32;           // k-chunk staged in LDS
  __shared__ float xs[RPB][KC];     // 16 KB
  __shared__ float wrT[KC/4][64][4];// 8 KB
  __shared__ float wlT[KC/4][64][4];// 8 KB
  const float* __restrict__ x = (in_idx < 0) ? xext : g_feat[in_idx];
  float* __restrict__ zr = g_feat[zr_idx];
  float* __restrict__ xl = g_feat[xl_idx];
  const int t = threadIdx.x;
  const int rowbase = blockIdx.x * RPB;
  const int f  = t & 31;
  const int rg = t >> 5;            // 8 row-groups x 16 rows
  const int wv = t >> 6;
  const int wc = t & 63;
  const int wq = t >> 6;
  float ar0[16], ar1[16], al0[16], al1[16];
  #pragma unroll
  for (int r = 0; r < 16; ++r) { ar0[r]=0.f; ar1[r]=0.f; al0[r]=0.f; al1[r]=0.f; }

  for (int c = 0; c < K / KC; ++c) {
    __syncthreads();
    #pragma unroll
    for (int i = 0; i < 4; ++i) {          // x: 1024 slots of 16B = 16 KB
      const int idx = t + i * 256;
      const int r = idx >> 3, q = idx & 7;
      const float* gp = &x[(size_t)(rowbase + r) * K + c * KC + q * 4];
      float* lp = &xs[0][0] + (size_t)(i * 256 + wv * 64) * 4;
      __builtin_amdgcn_global_load_lds(
          (const __attribute__((address_space(1))) unsigned int*)gp,
          (__attribute__((address_space(3))) unsigned int*)lp, 16, 0, 0);
    }
    #pragma unroll
    for (int h = 0; h < 2; ++h) {
      const int kq = wq * 2 + h;
      #pragma unroll
      for (int i = 0; i < 4; ++i) {
        const int krow = c * KC + kq * 4 + i;
        wrT[kq][wc][i] = Wr[(size_t)krow * 64 + wc];
        wlT[kq][wc][i] = Wl[(size_t)krow * 64 + wc];
      }
    }
    __syncthreads();
    #pragma unroll 1
    for (int k4 = 0; k4 < KC / 4; ++k4) {
      const float4 wr0 = *reinterpret_cast<const float4*>(&wrT[k4][f][0]);
      const float4 wr1 = *reinterpret_cast<const float4*>(&wrT[k4][f+32][0]);
      const float4 wl0 = *reinterpret_cast<const float4*>(&wlT[k4][f][0]);
      const float4 wl1 = *reinterpret_cast<const float4*>(&wlT[k4][f+32][0]);
      #pragma unroll
      for (int r = 0; r < 16; ++r) {
        const float4 xv = *reinterpret_cast<const float4*>(&xs[rg*16 + r][k4*4]);
        float a0 = ar0[r], a1 = ar1[r], b0 = al0[r], b1 = al1[r];
        a0 = fmaf(xv.x, wr0.x, a0); a0 = fmaf(xv.y, wr0.y, a0);
        a0 = fmaf(xv.z, wr0.z, a0); a0 = fmaf(xv.w, wr0.w, a0);
        a1 = fmaf(xv.x, wr1.x, a1); a1 = fmaf(xv.y, wr1.y, a1);
        a1 = fmaf(xv.z, wr1.z, a1); a1 = fmaf(xv.w, wr1.w, a1);
        b0 = fmaf(xv.x, wl0.x, b0); b0 = fmaf(xv.y, wl0.y, b0);
        b0 = fmaf(xv.z, wl0.z, b0); b0 = fmaf(xv.w, wl0.w, b0);
        b1 = fmaf(xv.x, wl1.x, b1); b1 = fmaf(xv.y, wl1.y, b1);
        b1 = fmaf(xv.z, wl1.z, b1); b1 = fmaf(xv.w, wl1.w, b1);
        ar0[r] = a0; ar1[r] = a1; al0[r] = b0; al1[r] = b1;
      }
    }
  }
  const float bv0 = bias[f], bv1 = bias[f + 32];
  #pragma unroll
  for (int r = 0; r < 16; ++r) {
    const size_t row = (size_t)(rowbase + rg * 16 + r);
    zr[row * 64 + f]      = ar0[r];
    zr[row * 64 + f + 32] = ar1[r];
    xl[row * 64 + f]      = al0[r] + bv0;
    xl[row * 64 + f + 32] = al1[r] + bv1;
  }
}

// ============================================================================
// agg_full_build: CSR build + zr staged in LDS (128 KB); gather LDS-local.
// ============================================================================
__global__ __launch_bounds__(1024)
void agg_full_build(int zr_idx, int xl_idx,
                    const int* __restrict__ esrc, const int* __restrict__ edst,
                    int out_idx, int xs_off)
{
  __shared__ float zlds[512 * 64];                 // 128 KB
  __shared__ unsigned short csr[EPG];              // 16 KB
  __shared__ unsigned int hist[512], bufA[512], bufB[512];  // 6 KB
  __shared__ float red[16][64];                    // 4 KB
  const float* __restrict__ zr  = g_feat[zr_idx];
  const float* __restrict__ xlb = g_feat[xl_idx];
  float* __restrict__ xout = g_feat[out_idx];
  const int g = blockIdx.x, t = threadIdx.x;
  const int gbase = g * 512, ebase = g * EPG;
  if (t < 512) hist[t] = 0;
  __syncthreads();
  {
    const float4* zsrc = reinterpret_cast<const float4*>(zr + (size_t)gbase * 64);
    float4* zdst = reinterpret_cast<float4*>(zlds);
    #pragma unroll
    for (int i = 0; i < 8; ++i) zdst[t + i * 1024] = zsrc[t + i * 1024];
  }
  for (int e = t; e < EPG; e += 1024)
    atomicAdd(&hist[edst[ebase + e] - gbase], 1u);
  __syncthreads();
  if (t < 512) bufA[t] = hist[t];
  __syncthreads();
  unsigned int *pa = bufA, *pb = bufB;
  for (int off = 1; off < 512; off <<= 1) {
    if (t < 512) {
      unsigned int v = pa[t];
      if (t >= off) v += pa[t - off];
      pb[t] = v;
    }
    __syncthreads();
    unsigned int* tmp = pa; pa = pb; pb = tmp;
  }
  unsigned int excl = 0;
  if (t < 512) excl = pa[t] - hist[t];
  __syncthreads();
  if (t < 512) { bufA[t] = excl; bufB[t] = excl; }
  __syncthreads();
  for (int e = t; e < EPG; e += 1024) {
    const int sl = esrc[ebase + e] - gbase;
    const int dl = edst[ebase + e] - gbase;
    const unsigned int pos = atomicAdd(&bufB[dl], 1u);
    csr[pos] = (unsigned short)sl;
  }
  __syncthreads();
  if (t < 512) { g_deg[gbase + t] = hist[t]; g_start[gbase + t] = bufA[t]; }
  {
    unsigned int* gcsr32 = reinterpret_cast<unsigned int*>(&g_csr[ebase]);
    const unsigned int* lcsr32 = reinterpret_cast<const unsigned int*>(csr);
    for (int i = t; i < EPG/2; i += 1024) gcsr32[i] = lcsr32[i];
  }
  const int lane = t & 63, w = t >> 6;
  float psum = 0.f;
  for (int nd = w; nd < 512; nd += 16) {
    const unsigned int s = bufA[nd], d = hist[nd];
    float a0 = 0.f, a1 = 0.f, a2 = 0.f, a3 = 0.f;
    unsigned int j = 0;
    for (; j + 4 <= d; j += 4) {
      const int i0 = csr[s+j], i1 = csr[s+j+1], i2 = csr[s+j+2], i3 = csr[s+j+3];
      a0 += zlds[i0*64 + lane]; a1 += zlds[i1*64 + lane];
      a2 += zlds[i2*64 + lane]; a3 += zlds[i3*64 + lane];
    }
    for (; j < d; ++j) a0 += zlds[csr[s+j]*64 + lane];
    const float acc = (a0 + a1) + (a2 + a3);
    float v = acc / (float)(d > 0 ? d : 1) + xlb[(size_t)(gbase + nd)*64 + lane];
    v = fmaxf(v, 0.f);
    xout[(size_t)(gbase + nd)*64 + lane] = v;
    psum += v;
  }
  red[w][lane] = psum;
  __syncthreads();
  if (t < 64) {
    float s = 0.f;
    #pragma unroll
    for (int ww = 0; ww < 16; ++ww) s += red[ww][t];
    g_xs[g*384 + xs_off + t] = s * (1.f/512.f);
  }
}

// ============================================================================
// agg_full_use: loads prebuilt CSR + zr slice into LDS, gathers locally.
// ============================================================================
__global__ __launch_bounds__(1024)
void agg_full_use(int zr_idx, int xl_idx, int out_idx, int xs_off)
{
  __shared__ float zlds[512 * 64];                 // 128 KB
  __shared__ unsigned short csr[EPG];              // 16 KB
  __shared__ unsigned int hist[512], start[512];   // 4 KB
  __shared__ float red[16][64];                    // 4 KB  (total 152 KB)
  const float* __restrict__ zr  = g_feat[zr_idx];
  const float* __restrict__ xlb = g_feat[xl_idx];
  float* __restrict__ xout = g_feat[out_idx];
  const int g = blockIdx.x, t = threadIdx.x;
  const int gbase = g * 512, ebase = g * EPG;
  if (t < 512) { hist[t] = g_deg[gbase + t]; start[t] = g_start[gbase + t]; }
  {
    const float4* zsrc = reinterpret_cast<const float4*>(zr + (size_t)gbase * 64);
    float4* zdst = reinterpret_cast<float4*>(zlds);
    #pragma unroll
    for (int i = 0; i < 8; ++i) zdst[t + i * 1024] = zsrc[t + i * 1024];
  }
  {
    const uint4* c4 = reinterpret_cast<const uint4*>(&g_csr[ebase]);  // 16 KB
    uint4* l4 = reinterpret_cast<uint4*>(csr);
    l4[t] = c4[t];                                 // 1024 x 16 B
  }
  __syncthreads();
  const int lane = t & 63, w = t >> 6;
  float psum = 0.f;
  for (int nd = w; nd < 512; nd += 16) {
    const unsigned int s = start[nd], d = hist[nd];
    float a0 = 0.f, a1 = 0.f, a2 = 0.f, a3 = 0.f;
    unsigned int j = 0;
    for (; j + 4 <= d; j += 4) {
      const int i0 = csr[s+j], i1 = csr[s+j+1], i2 = csr[s+j+2], i3 = csr[s+j+3];
      a0 += zlds[i0*64 + lane]; a1 += zlds[i1*64 + lane];
      a2 += zlds[i2*64 + lane]; a3 += zlds[i3*64 + lane];
    }
    for (; j < d; ++j) a0 += zlds[csr[s+j]*64 + lane];
    const float acc = (a0 + a1) + (a2 + a3);
    float v = acc / (float)(d > 0 ? d : 1) + xlb[(size_t)(gbase + nd)*64 + lane];
    v = fmaxf(v, 0.f);
    xout[(size_t)(gbase + nd)*64 + lane] = v;
    psum += v;
  }
  red[w][lane] = psum;
  __syncthreads();
  if (t < 64) {
    float s = 0.f;
    #pragma unroll
    for (int ww = 0; ww < 16; ++ww) s += red[ww][t];
    g_xs[g*384 + xs_off + t] = s * (1.f/512.f);
  }
}

// ============================================================================
// SAG pool 0 (512 -> 57): CSR-based scalar aggregation (no LDS atomics).
// ============================================================================
__global__ __launch_bounds__(512)
void sag_pool0(int in_idx,
               const int* __restrict__ esrc, const int* __restrict__ edst,
               const float* __restrict__ wr, const float* __restrict__ wl,
               const float* __restrict__ pb,
               int xnew_idx, int out_stage)
{
  constexpr int NPER = 512, NPOW2 = 512, KSEL = 57;
  __shared__ float zs[NPER], swl[NPER], sscore[NPER];
  __shared__ unsigned long long keys[NPOW2];
  __shared__ unsigned short pcsr[EPG];
  __shared__ short newpos[NPER];
  __shared__ int scnt;
  const float* __restrict__ xin = g_feat[in_idx];
  float* __restrict__ xnew = g_feat[xnew_idx];
  int* __restrict__ eosrc = g_esrc[out_stage];
  int* __restrict__ eodst = g_edst[out_stage];
  const int g = blockIdx.x, t = threadIdx.x;
  const int gbase = g * NPER, ebase = g * EPG;
  const int lane = t & 63, w = t >> 6;            // 8 waves
  const float wrv = wr[lane], wlv = wl[lane];
  for (int nd = w; nd < NPER; nd += 8) {
    const float v = xin[(size_t)(gbase + nd)*64 + lane];
    float a = v * wrv, b = v * wlv;
    #pragma unroll
    for (int off = 32; off > 0; off >>= 1) {
      a += __shfl_xor(a, off);
      b += __shfl_xor(b, off);
    }
    if (lane == 0) { zs[nd] = a; swl[nd] = b; }
  }
  {
    const unsigned int* gcsr32 = reinterpret_cast<const unsigned int*>(&g_csr[ebase]);
    unsigned int* lcsr32 = reinterpret_cast<unsigned int*>(pcsr);
    for (int i = t; i < EPG/2; i += 512) lcsr32[i] = gcsr32[i];
  }
  if (t == 0) scnt = 0;
  __syncthreads();
  if (t < NPER) {
    const unsigned int s = g_start[gbase + t], d = g_deg[gbase + t];
    float a = 0.f;
    for (unsigned int j = 0; j < d; ++j) a += zs[pcsr[s + j]];
    sscore[t] = a / fmaxf((float)d, 1.f) + pb[0] + swl[t];
  }
  __syncthreads();
  if (t < NPOW2) {
    unsigned long long key = 0ull;
    if (t < NPER) {
      unsigned int u = __float_as_uint(sscore[t]);
      u = (u & 0x80000000u) ? ~u : (u | 0x80000000u);
      key = ((unsigned long long)u << 32) | (unsigned int)(~(unsigned int)t);
    }
    keys[t] = key;
  }
  __syncthreads();
  for (int kk = 2; kk <= NPOW2; kk <<= 1) {
    for (int j = kk >> 1; j > 0; j >>= 1) {
      if (t < NPOW2) {
        const int ixj = t ^ j;
        if (ixj > t) {
          const unsigned long long a = keys[t], bk = keys[ixj];
          const bool up = ((t & kk) == 0);
          if (up ? (a < bk) : (a > bk)) { keys[t] = bk; keys[ixj] = a; }
        }
      }
      __syncthreads();
    }
  }
  if (t < NPER) newpos[t] = -1;
  __syncthreads();
  if (t < KSEL)
    newpos[(int)(~(unsigned int)(keys[t] & 0xffffffffull))] = (short)t;
  __syncthreads();
  for (int r = w; r < KSEL; r += 8) {
    const int old = (int)(~(unsigned int)(keys[r] & 0xffffffffull));
    const float sc = tanhf(sscore[old]);
    xnew[(size_t)(g*KSEL + r)*64 + lane] =
        xin[(size_t)(gbase + old)*64 + lane] * sc;
  }
  for (int e = t; e < EPG; e += 512) {
    const int sl = esrc[ebase + e] - gbase;
    const int dl = edst[ebase + e] - gbase;
    const int ns = newpos[sl], nd2 = newpos[dl];
    if (ns >= 0 && nd2 >= 0) {
      const int slot = atomicAdd(&scnt, 1);
      eosrc[ebase + slot] = g*KSEL + ns;
      eodst[ebase + slot] = g*KSEL + nd2;
    }
  }
  __syncthreads();
  if (t == 0) g_ecnt[out_stage][g] = scnt;
}

// ============================================================================
// Fused tail: per graph, everything after pool0 (convs[1..4], pool1, gmp's).
// ============================================================================
__device__ __forceinline__ void conv_small(
    float* X, float* Z, float* ACC, float* w_s, const float* deg,
    const float* Wr, const float* Wl, const float* bias,
    int n, const int* esrc, const int* edst, int m, int gb, int ebase,
    int xs_off, int g, int t, int lane, int w)
{
  for (int i = t; i < n*64; i += 512) { Z[i] = 0.f; ACC[i] = 0.f; }
  __syncthreads();
  for (int kc = 0; kc < 4; ++kc) {
    for (int i = t; i < 1024; i += 512) w_s[i] = Wr[kc*1024 + i];
    __syncthreads();
    for (int r = w; r < n; r += 8) {
      float zacc = 0.f;
      #pragma unroll
      for (int k = 0; k < 16; ++k)
        zacc = fmaf(X[r*64 + kc*16 + k], w_s[k*64 + lane], zacc);
      Z[r*64 + lane] += zacc;
    }
    __syncthreads();
  }
  for (int e = w; e < m; e += 8) {
    const int sl = esrc[ebase + e] - gb;
    const int dl = edst[ebase + e] - gb;
    atomicAdd(&ACC[dl*64 + lane], Z[sl*64 + lane]);
  }
  __syncthreads();
  for (int i = t; i < n*64; i += 512) {
    const int r = i >> 6, f = i & 63;
    Z[i] = ACC[i] / fmaxf(deg[r], 1.f) + bias[f];
  }
  __syncthreads();
  for (int kc = 0; kc < 4; ++kc) {
    for (int i = t; i < 1024; i += 512) w_s[i] = Wl[kc*1024 + i];
    __syncthreads();
    for (int r = w; r < n; r += 8) {
      float zacc = 0.f;
      #pragma unroll
      for (int k = 0; k < 16; ++k)
        zacc = fmaf(X[r*64 + kc*16 + k], w_s[k*64 + lane], zacc);
      Z[r*64 + lane] += zacc;
    }
    __syncthreads();
  }
  for (int i = t; i < n*64; i += 512) X[i] = fmaxf(Z[i], 0.f);
  __syncthreads();
  if (t < 64) {
    float s = 0.f;
    for (int r = 0; r < n; ++r) s += X[r*64 + t];
    g_xs[g*384 + xs_off + t] = s / (float)n;
  }
  __syncthreads();
}

__global__ __launch_bounds__(512)
void tail(const float* __restrict__ cWr, const float* __restrict__ cWl,
          const float* __restrict__ cb,
          const float* __restrict__ pWr, const float* __restrict__ pWl,
          const float* __restrict__ pb)
{
  __shared__ float X[57*64], Z[57*64], ACC[57*64];   // 42.75 KB
  __shared__ float w_s[16*64];                       // 4 KB
  __shared__ float deg[64];
  __shared__ float zs[64], swl[64], sagg[64], sscore[64];
  __shared__ unsigned long long keys[64];
  __shared__ short newpos[64];
  __shared__ int scnt;
  const int g = blockIdx.x, t = threadIdx.x;
  const int lane = t & 63, w = t >> 6;
  const int ebase = g * EPG;

  for (int i = t; i < 57*64; i += 512) X[i] = g_feat[0][(size_t)(g*57)*64 + i];
  const int m0 = g_ecnt[0][g];
  if (t < 64) deg[t] = 0.f;
  __syncthreads();
  for (int e = t; e < m0; e += 512)
    atomicAdd(&deg[g_edst[0][ebase + e] - g*57], 1.f);
  __syncthreads();

  conv_small(X, Z, ACC, w_s, deg, cWr + 4096,  cWl + 4096,  cb + 64,
             57, g_esrc[0], g_edst[0], m0, g*57, ebase, 128, g, t, lane, w);
  conv_small(X, Z, ACC, w_s, deg, cWr + 8192,  cWl + 8192,  cb + 128,
             57, g_esrc[0], g_edst[0], m0, g*57, ebase, 192, g, t, lane, w);

  // ---- pool1: 57 -> 7 ----
  {
    const float pwrv = pWr[64 + lane], pwlv = pWl[64 + lane];
    for (int r = w; r < 57; r += 8) {
      float a = X[r*64 + lane] * pwrv, b = X[r*64 + lane] * pwlv;
      #pragma unroll
      for (int off = 32; off > 0; off >>= 1) {
        a += __shfl_xor(a, off);
        b += __shfl_xor(b, off);
      }
      if (lane == 0) { zs[r] = a; swl[r] = b; }
    }
    if (t < 64) sagg[t] = 0.f;
    if (t == 0) scnt = 0;
    __syncthreads();
    for (int e = t; e < m0; e += 512)
      atomicAdd(&sagg[g_edst[0][ebase + e] - g*57],
                zs[g_esrc[0][ebase + e] - g*57]);
    __syncthreads();
    if (t < 57) sscore[t] = sagg[t] / fmaxf(deg[t], 1.f) + pb[1] + swl[t];
    __syncthreads();
    if (t < 64) {
      unsigned long long key = 0ull;
      if (t < 57) {
        unsigned int u = __float_as_uint(sscore[t]);
        u = (u & 0x80000000u) ? ~u : (u | 0x80000000u);
        key = ((unsigned long long)u << 32) | (unsigned int)(~(unsigned int)t);
      }
      keys[t] = key;
    }
    __syncthreads();
    for (int kk = 2; kk <= 64; kk <<= 1) {
      for (int j = kk >> 1; j > 0; j >>= 1) {
        if (t < 64) {
          const int ixj = t ^ j;
          if (ixj > t) {
            const unsigned long long a = keys[t], bk = keys[ixj];
            const bool up = ((t & kk) == 0);
            if (up ? (a < bk) : (a > bk)) { keys[t] = bk; keys[ixj] = a; }
          }
        }
        __syncthreads();
      }
    }
    if (t < 64) newpos[t] = -1;
    __syncthreads();
    if (t < 7)
      newpos[(int)(~(unsigned int)(keys[t] & 0xffffffffull))] = (short)t;
    __syncthreads();
    for (int r = w; r < 7; r += 8) {
      const int old = (int)(~(unsigned int)(keys[r] & 0xffffffffull));
      const float sc = tanhf(sscore[old]);
      Z[r*64 + lane] = X[old*64 + lane] * sc;
    }
    for (int e = t; e < m0; e += 512) {
      const int sl = g_esrc[0][ebase + e] - g*57;
      const int dl = g_edst[0][ebase + e] - g*57;
      const int ns = newpos[sl], nd2 = newpos[dl];
      if (ns >= 0 && nd2 >= 0) {
        const int slot = atomicAdd(&scnt, 1);
        g_esrc[1][ebase + slot] = g*7 + ns;
        g_edst[1][ebase + slot] = g*7 + nd2;
      }
    }
    __syncthreads();
    for (int i = t; i < 7*64; i += 512) X[i] = Z[i];
    if (t < 64) deg[t] = 0.f;
    __syncthreads();
  }
  const int m1 = scnt;
  for (int e = t; e < m1; e += 512)
    atomicAdd(&deg[g_edst[1][ebase + e] - g*7], 1.f);
  __syncthreads();

  conv_small(X, Z, ACC, w_s, deg, cWr + 12288, cWl + 12288, cb + 192,
             7, g_esrc[1], g_edst[1], m1, g*7, ebase, 256, g, t, lane, w);
  conv_small(X, Z, ACC, w_s, deg, cWr + 16384, cWl + 16384, cb + 256,
             7, g_esrc[1], g_edst[1], m1, g*7, ebase, 320, g, t, lane, w);
}

// ============================================================================
// MLP head: h=[B,384] -> relu(h@W1+b1) -> @W2+b2 -> log_softmax
// ============================================================================
__global__ __launch_bounds__(64)
void head(const float* __restrict__ W1, const float* __restrict__ b1,
          const float* __restrict__ W2, const float* __restrict__ b2,
          float* __restrict__ out)
{
  __shared__ float h[384], o1[64], lg[2];
  const int g = blockIdx.x, t = threadIdx.x;
  for (int i = t; i < 384; i += 64) h[i] = g_xs[g*384 + i];
  __syncthreads();
  float acc = b1[t];
  for (int j = 0; j < 384; ++j) acc = fmaf(h[j], W1[j*64 + t], acc);
  o1[t] = fmaxf(acc, 0.f);
  __syncthreads();
  if (t < 2) {
    float a2 = b2[t];
    for (int f2 = 0; f2 < 64; ++f2) a2 = fmaf(o1[f2], W2[f2*2 + t], a2);
    lg[t] = a2;
  }
  __syncthreads();
  if (t < 2) {
    const float mx = fmaxf(lg[0], lg[1]);
    const float lse = mx + logf(expf(lg[0]-mx) + expf(lg[1]-mx));
    out[g*2 + t] = lg[t] - lse;
  }
}

// ============================================================================
extern "C" void kernel_launch(void* const* d_in, const int* in_sizes, int n_in,
                              void* d_out, int out_size, void* d_ws, size_t ws_size,
                              hipStream_t stream)
{
  (void)in_sizes; (void)n_in; (void)d_ws; (void)ws_size; (void)out_size;
  const float* x    = (const float*)d_in[0];
  const int*   ei   = (const int*)d_in[1];
  const float* c1Wr = (const float*)d_in[2];
  const float* c1Wl = (const float*)d_in[3];
  const float* c1b  = (const float*)d_in[4];
  const float* cWr  = (const float*)d_in[5];
  const float* cWl  = (const float*)d_in[6];
  const float* cb   = (const float*)d_in[7];
  const float* pWr  = (const float*)d_in[8];
  const float* pWl  = (const float*)d_in[9];
  const float* pb   = (const float*)d_in[10];
  const float* l1W  = (const float*)d_in[11];
  const float* l1b  = (const float*)d_in[12];
  const float* l2W  = (const float*)d_in[13];
  const float* l2b  = (const float*)d_in[14];
  float* out = (float*)d_out;
  const int* esrc = ei;
  const int* edst = ei + ETOT;

  // conv1 (160->64) + relu, xs[0]  (builds the shared CSR)
  mm_dual<160><<<NN0/128, 256, 0, stream>>>(x, -1, c1Wr, c1Wl, c1b, 0, 1);
  agg_full_build<<<NB, 1024, 0, stream>>>(0, 1, esrc, edst, 1, 0);
  // convs[0] + relu, xs[1]  (reuses CSR)
  mm_dual<64><<<NN0/128, 256, 0, stream>>>(nullptr, 1, cWr, cWl, cb, 0, 2);
  agg_full_use<<<NB, 1024, 0, stream>>>(0, 2, 2, 64);
  // pool0: 512 -> 57  (reuses CSR)
  sag_pool0<<<NB, 512, 0, stream>>>(2, esrc, edst, pWr, pWl, pb, 0, 0);
  // fused tail: convs[1..4] + pool1 + gmp's
  tail<<<NB, 512, 0, stream>>>(cWr, cWl, cb, pWr, pWl, pb);
  // head
  head<<<NB, 64, 0, stream>>>(l1W, l1b, l2W, l2b, out);
}

// Round 17
// 373.448 us; speedup vs baseline: 1.0095x; 1.0095x over previous
//
#include <hip/hip_runtime.h>
#include <math.h>

namespace {
constexpr int NB   = 256;          // graphs
constexpr int EPG  = 8192;         // edges per graph
constexpr int ETOT = NB * EPG;     // 2,097,152
constexpr int FH   = 64;           // hidden dim
constexpr int NN0  = NB * 512;     // 131072 nodes at full size
}

// ---- scratch (device globals: write-before-read each call, deterministic) ----
__device__ float g_feat[3][(size_t)NN0 * FH];   // rotating node-feature buffers
__device__ float g_xs[NB * 6 * FH];             // jumping-knowledge concat
__device__ int   g_esrc[2][ETOT];               // compacted edges (stage 0/1)
__device__ int   g_edst[2][ETOT];
__device__ int   g_ecnt[2][NB];
__device__ unsigned short g_csr[ETOT];          // shared CSR (built once/call)
__device__ unsigned int   g_deg[NN0], g_start[NN0];

// ============================================================================
// Dual matmul (v6, RPB=64 — proven 87us; K-independent wall, do not iterate).
// ============================================================================
template<int K>
__global__ __launch_bounds__(256)
void mm_dual(const float* __restrict__ xext, int in_idx,
             const float* __restrict__ Wr, const float* __restrict__ Wl,
             const float* __restrict__ bias, int zr_idx, int xl_idx)
{
  constexpr int RPB = 64;           // rows per block
  constexpr int KC  = 32;           // k-chunk staged in LDS
  __shared__ float xs[RPB][KC];     // 8 KB
  __shared__ float wrT[KC/4][64][4];// 8 KB
  __shared__ float wlT[KC/4][64][4];// 8 KB
  const float* __restrict__ x = (in_idx < 0) ? xext : g_feat[in_idx];
  float* __restrict__ zr = g_feat[zr_idx];
  float* __restrict__ xl = g_feat[xl_idx];
  const int t = threadIdx.x;
  const int rowbase = blockIdx.x * RPB;
  const int f  = t & 31;
  const int rg = t >> 5;
  const int wv = t >> 6;
  const int wc = t & 63;
  const int wq = t >> 6;
  float ar0[8], ar1[8], al0[8], al1[8];
  #pragma unroll
  for (int r = 0; r < 8; ++r) { ar0[r]=0.f; ar1[r]=0.f; al0[r]=0.f; al1[r]=0.f; }

  for (int c = 0; c < K / KC; ++c) {
    __syncthreads();
    #pragma unroll
    for (int i = 0; i < 2; ++i) {
      const int idx = t + i * 256;
      const int r = idx >> 3, q = idx & 7;
      const float* gp = &x[(size_t)(rowbase + r) * K + c * KC + q * 4];
      float* lp = &xs[0][0] + (size_t)(i * 256 + wv * 64) * 4;
      __builtin_amdgcn_global_load_lds(
          (const __attribute__((address_space(1))) unsigned int*)gp,
          (__attribute__((address_space(3))) unsigned int*)lp, 16, 0, 0);
    }
    #pragma unroll
    for (int h = 0; h < 2; ++h) {
      const int kq = wq * 2 + h;
      #pragma unroll
      for (int i = 0; i < 4; ++i) {
        const int krow = c * KC + kq * 4 + i;
        wrT[kq][wc][i] = Wr[(size_t)krow * 64 + wc];
        wlT[kq][wc][i] = Wl[(size_t)krow * 64 + wc];
      }
    }
    __syncthreads();
    #pragma unroll 1
    for (int k4 = 0; k4 < KC / 4; ++k4) {
      const float4 wr0 = *reinterpret_cast<const float4*>(&wrT[k4][f][0]);
      const float4 wr1 = *reinterpret_cast<const float4*>(&wrT[k4][f+32][0]);
      const float4 wl0 = *reinterpret_cast<const float4*>(&wlT[k4][f][0]);
      const float4 wl1 = *reinterpret_cast<const float4*>(&wlT[k4][f+32][0]);
      #pragma unroll
      for (int r = 0; r < 8; ++r) {
        const float4 xv = *reinterpret_cast<const float4*>(&xs[rg*8 + r][k4*4]);
        float a0 = ar0[r], a1 = ar1[r], b0 = al0[r], b1 = al1[r];
        a0 = fmaf(xv.x, wr0.x, a0); a0 = fmaf(xv.y, wr0.y, a0);
        a0 = fmaf(xv.z, wr0.z, a0); a0 = fmaf(xv.w, wr0.w, a0);
        a1 = fmaf(xv.x, wr1.x, a1); a1 = fmaf(xv.y, wr1.y, a1);
        a1 = fmaf(xv.z, wr1.z, a1); a1 = fmaf(xv.w, wr1.w, a1);
        b0 = fmaf(xv.x, wl0.x, b0); b0 = fmaf(xv.y, wl0.y, b0);
        b0 = fmaf(xv.z, wl0.z, b0); b0 = fmaf(xv.w, wl0.w, b0);
        b1 = fmaf(xv.x, wl1.x, b1); b1 = fmaf(xv.y, wl1.y, b1);
        b1 = fmaf(xv.z, wl1.z, b1); b1 = fmaf(xv.w, wl1.w, b1);
        ar0[r] = a0; ar1[r] = a1; al0[r] = b0; al1[r] = b1;
      }
    }
  }
  const float bv0 = bias[f], bv1 = bias[f + 32];
  #pragma unroll
  for (int r = 0; r < 8; ++r) {
    const size_t row = (size_t)(rowbase + rg * 8 + r);
    zr[row * 64 + f]      = ar0[r];
    zr[row * 64 + f + 32] = ar1[r];
    xl[row * 64 + f]      = al0[r] + bv0;
    xl[row * 64 + f + 32] = al1[r] + bv1;
  }
}

// ============================================================================
// agg_full_build: CSR build + zr staged in LDS (128 KB); gather LDS-local.
// ============================================================================
__global__ __launch_bounds__(1024)
void agg_full_build(int zr_idx, int xl_idx,
                    const int* __restrict__ esrc, const int* __restrict__ edst,
                    int out_idx, int xs_off)
{
  __shared__ float zlds[512 * 64];                 // 128 KB
  __shared__ unsigned short csr[EPG];              // 16 KB
  __shared__ unsigned int hist[512], bufA[512], bufB[512];  // 6 KB
  __shared__ float red[16][64];                    // 4 KB
  const float* __restrict__ zr  = g_feat[zr_idx];
  const float* __restrict__ xlb = g_feat[xl_idx];
  float* __restrict__ xout = g_feat[out_idx];
  const int g = blockIdx.x, t = threadIdx.x;
  const int gbase = g * 512, ebase = g * EPG;
  if (t < 512) hist[t] = 0;
  __syncthreads();
  {
    const float4* zsrc = reinterpret_cast<const float4*>(zr + (size_t)gbase * 64);
    float4* zdst = reinterpret_cast<float4*>(zlds);
    #pragma unroll
    for (int i = 0; i < 8; ++i) zdst[t + i * 1024] = zsrc[t + i * 1024];
  }
  for (int e = t; e < EPG; e += 1024)
    atomicAdd(&hist[edst[ebase + e] - gbase], 1u);
  __syncthreads();
  if (t < 512) bufA[t] = hist[t];
  __syncthreads();
  unsigned int *pa = bufA, *pb = bufB;
  for (int off = 1; off < 512; off <<= 1) {
    if (t < 512) {
      unsigned int v = pa[t];
      if (t >= off) v += pa[t - off];
      pb[t] = v;
    }
    __syncthreads();
    unsigned int* tmp = pa; pa = pb; pb = tmp;
  }
  unsigned int excl = 0;
  if (t < 512) excl = pa[t] - hist[t];
  __syncthreads();
  if (t < 512) { bufA[t] = excl; bufB[t] = excl; }
  __syncthreads();
  for (int e = t; e < EPG; e += 1024) {
    const int sl = esrc[ebase + e] - gbase;
    const int dl = edst[ebase + e] - gbase;
    const unsigned int pos = atomicAdd(&bufB[dl], 1u);
    csr[pos] = (unsigned short)sl;
  }
  __syncthreads();
  if (t < 512) { g_deg[gbase + t] = hist[t]; g_start[gbase + t] = bufA[t]; }
  {
    unsigned int* gcsr32 = reinterpret_cast<unsigned int*>(&g_csr[ebase]);
    const unsigned int* lcsr32 = reinterpret_cast<const unsigned int*>(csr);
    for (int i = t; i < EPG/2; i += 1024) gcsr32[i] = lcsr32[i];
  }
  const int lane = t & 63, w = t >> 6;
  float psum = 0.f;
  for (int nd = w; nd < 512; nd += 16) {
    const unsigned int s = bufA[nd], d = hist[nd];
    float a0 = 0.f, a1 = 0.f, a2 = 0.f, a3 = 0.f;
    unsigned int j = 0;
    for (; j + 4 <= d; j += 4) {
      const int i0 = csr[s+j], i1 = csr[s+j+1], i2 = csr[s+j+2], i3 = csr[s+j+3];
      a0 += zlds[i0*64 + lane]; a1 += zlds[i1*64 + lane];
      a2 += zlds[i2*64 + lane]; a3 += zlds[i3*64 + lane];
    }
    for (; j < d; ++j) a0 += zlds[csr[s+j]*64 + lane];
    const float acc = (a0 + a1) + (a2 + a3);
    float v = acc / (float)(d > 0 ? d : 1) + xlb[(size_t)(gbase + nd)*64 + lane];
    v = fmaxf(v, 0.f);
    xout[(size_t)(gbase + nd)*64 + lane] = v;
    psum += v;
  }
  red[w][lane] = psum;
  __syncthreads();
  if (t < 64) {
    float s = 0.f;
    #pragma unroll
    for (int ww = 0; ww < 16; ++ww) s += red[ww][t];
    g_xs[g*384 + xs_off + t] = s * (1.f/512.f);
  }
}

// ============================================================================
// conv_agg_fused v2: replaces mm_dual<64>(full) + agg_full_use.
// Two single-output GEMM passes (keeps live regs ~36, avoids AGPR parking):
//   pass A: xla = X@Wl -> park in global xout (temp);
//   pass B: zacc = X@Wr -> wave overwrites its OWN X rows in LDS (safe:
//           GEMM reads are wave-own-rows only); barrier; LDS gather;
//   epilogue: v = gather/deg + xla(reload, L2-hot) + bias; relu; gmp.
// ============================================================================
__global__ __launch_bounds__(1024)
void conv_agg_fused(int x_idx, const float* __restrict__ Wr,
                    const float* __restrict__ Wl, const float* __restrict__ bias,
                    int out_idx, int xs_off)
{
  __shared__ float zlds[512 * 64];                 // 128 KB: X, then z (in place)
  __shared__ unsigned short csr[EPG];              // 16 KB
  __shared__ unsigned int hist[512], start[512];   // 4 KB
  __shared__ float w_s[1024];                      // 4 KB (Wl then Wr chunks)
  __shared__ float red[16][64];                    // 4 KB   (total 156 KB)
  const float* __restrict__ X1 = g_feat[x_idx];
  float* __restrict__ xout = g_feat[out_idx];
  const int g = blockIdx.x, t = threadIdx.x;
  const int gbase = g * 512, ebase = g * EPG;
  const int lane = t & 63, w = t >> 6;             // 16 waves
  const int ndbase = w * 32;                       // wave owns rows [ndbase,+32)
  // stage X slice + CSR + deg/start
  {
    const float4* src = reinterpret_cast<const float4*>(X1 + (size_t)gbase * 64);
    float4* dst = reinterpret_cast<float4*>(zlds);
    #pragma unroll
    for (int i = 0; i < 8; ++i) dst[t + i * 1024] = src[t + i * 1024];
  }
  if (t < 512) { hist[t] = g_deg[gbase + t]; start[t] = g_start[gbase + t]; }
  {
    const uint4* c4 = reinterpret_cast<const uint4*>(&g_csr[ebase]);
    uint4* l4 = reinterpret_cast<uint4*>(csr);
    l4[t] = c4[t];
  }
  // ---- pass A: xla = X@Wl, park to global ----
  {
    float xla[32];
    #pragma unroll
    for (int i = 0; i < 32; ++i) xla[i] = 0.f;
    #pragma unroll 1
    for (int c = 0; c < 4; ++c) {
      __syncthreads();                             // (1st: staging done; WAR w_s)
      w_s[t] = Wl[c * 1024 + t];
      __syncthreads();
      #pragma unroll 1
      for (int k4 = 0; k4 < 4; ++k4) {
        const int kb = k4 * 4;
        const float w0 = w_s[(kb+0)*64 + lane], w1 = w_s[(kb+1)*64 + lane],
                    w2 = w_s[(kb+2)*64 + lane], w3 = w_s[(kb+3)*64 + lane];
        #pragma unroll
        for (int i = 0; i < 32; ++i) {
          const float4 xv = *reinterpret_cast<const float4*>(
              &zlds[(ndbase + i) * 64 + c * 16 + kb]);
          float a = xla[i];
          a = fmaf(xv.x, w0, a); a = fmaf(xv.y, w1, a);
          a = fmaf(xv.z, w2, a); a = fmaf(xv.w, w3, a);
          xla[i] = a;
        }
      }
    }
    #pragma unroll
    for (int i = 0; i < 32; ++i)
      xout[(size_t)(gbase + ndbase + i) * 64 + lane] = xla[i];  // park
  }
  // ---- pass B: zacc = X@Wr, overwrite own rows ----
  {
    float zacc[32];
    #pragma unroll
    for (int i = 0; i < 32; ++i) zacc[i] = 0.f;
    #pragma unroll 1
    for (int c = 0; c < 4; ++c) {
      __syncthreads();                             // WAR on w_s
      w_s[t] = Wr[c * 1024 + t];
      __syncthreads();
      #pragma unroll 1
      for (int k4 = 0; k4 < 4; ++k4) {
        const int kb = k4 * 4;
        const float w0 = w_s[(kb+0)*64 + lane], w1 = w_s[(kb+1)*64 + lane],
                    w2 = w_s[(kb+2)*64 + lane], w3 = w_s[(kb+3)*64 + lane];
        #pragma unroll
        for (int i = 0; i < 32; ++i) {
          const float4 xv = *reinterpret_cast<const float4*>(
              &zlds[(ndbase + i) * 64 + c * 16 + kb]);
          float a = zacc[i];
          a = fmaf(xv.x, w0, a); a = fmaf(xv.y, w1, a);
          a = fmaf(xv.z, w2, a); a = fmaf(xv.w, w3, a);
          zacc[i] = a;
        }
      }
    }
    #pragma unroll
    for (int i = 0; i < 32; ++i)
      zlds[(ndbase + i) * 64 + lane] = zacc[i];    // own rows only: safe
  }
  __syncthreads();                                 // all z written
  // ---- gather + epilogue ----
  const float bv = bias[lane];
  float psum = 0.f;
  #pragma unroll 1
  for (int i = 0; i < 32; ++i) {
    const int nd = ndbase + i;
    const unsigned int s = start[nd], d = hist[nd];
    float a0 = 0.f, a1 = 0.f, a2 = 0.f, a3 = 0.f;
    unsigned int j = 0;
    for (; j + 4 <= d; j += 4) {
      const int i0 = csr[s+j], i1 = csr[s+j+1], i2 = csr[s+j+2], i3 = csr[s+j+3];
      a0 += zlds[i0*64 + lane]; a1 += zlds[i1*64 + lane];
      a2 += zlds[i2*64 + lane]; a3 += zlds[i3*64 + lane];
    }
    for (; j < d; ++j) a0 += zlds[csr[s+j]*64 + lane];
    const float xla_v = xout[(size_t)(gbase + nd)*64 + lane];   // reload park
    float v = ((a0 + a1) + (a2 + a3)) / (float)(d > 0 ? d : 1) + xla_v + bv;
    v = fmaxf(v, 0.f);
    xout[(size_t)(gbase + nd)*64 + lane] = v;
    psum += v;
  }
  red[w][lane] = psum;
  __syncthreads();
  if (t < 64) {
    float s = 0.f;
    #pragma unroll
    for (int ww = 0; ww < 16; ++ww) s += red[ww][t];
    g_xs[g*384 + xs_off + t] = s * (1.f/512.f);
  }
}

// ============================================================================
// SAG pool 0 (512 -> 57): CSR-based scalar aggregation (no LDS atomics).
// ============================================================================
__global__ __launch_bounds__(512)
void sag_pool0(int in_idx,
               const int* __restrict__ esrc, const int* __restrict__ edst,
               const float* __restrict__ wr, const float* __restrict__ wl,
               const float* __restrict__ pb,
               int xnew_idx, int out_stage)
{
  constexpr int NPER = 512, NPOW2 = 512, KSEL = 57;
  __shared__ float zs[NPER], swl[NPER], sscore[NPER];
  __shared__ unsigned long long keys[NPOW2];
  __shared__ unsigned short pcsr[EPG];
  __shared__ short newpos[NPER];
  __shared__ int scnt;
  const float* __restrict__ xin = g_feat[in_idx];
  float* __restrict__ xnew = g_feat[xnew_idx];
  int* __restrict__ eosrc = g_esrc[out_stage];
  int* __restrict__ eodst = g_edst[out_stage];
  const int g = blockIdx.x, t = threadIdx.x;
  const int gbase = g * NPER, ebase = g * EPG;
  const int lane = t & 63, w = t >> 6;            // 8 waves
  const float wrv = wr[lane], wlv = wl[lane];
  for (int nd = w; nd < NPER; nd += 8) {
    const float v = xin[(size_t)(gbase + nd)*64 + lane];
    float a = v * wrv, b = v * wlv;
    #pragma unroll
    for (int off = 32; off > 0; off >>= 1) {
      a += __shfl_xor(a, off);
      b += __shfl_xor(b, off);
    }
    if (lane == 0) { zs[nd] = a; swl[nd] = b; }
  }
  {
    const unsigned int* gcsr32 = reinterpret_cast<const unsigned int*>(&g_csr[ebase]);
    unsigned int* lcsr32 = reinterpret_cast<unsigned int*>(pcsr);
    for (int i = t; i < EPG/2; i += 512) lcsr32[i] = gcsr32[i];
  }
  if (t == 0) scnt = 0;
  __syncthreads();
  if (t < NPER) {
    const unsigned int s = g_start[gbase + t], d = g_deg[gbase + t];
    float a = 0.f;
    for (unsigned int j = 0; j < d; ++j) a += zs[pcsr[s + j]];
    sscore[t] = a / fmaxf((float)d, 1.f) + pb[0] + swl[t];
  }
  __syncthreads();
  if (t < NPOW2) {
    unsigned long long key = 0ull;
    if (t < NPER) {
      unsigned int u = __float_as_uint(sscore[t]);
      u = (u & 0x80000000u) ? ~u : (u | 0x80000000u);
      key = ((unsigned long long)u << 32) | (unsigned int)(~(unsigned int)t);
    }
    keys[t] = key;
  }
  __syncthreads();
  for (int kk = 2; kk <= NPOW2; kk <<= 1) {
    for (int j = kk >> 1; j > 0; j >>= 1) {
      if (t < NPOW2) {
        const int ixj = t ^ j;
        if (ixj > t) {
          const unsigned long long a = keys[t], bk = keys[ixj];
          const bool up = ((t & kk) == 0);
          if (up ? (a < bk) : (a > bk)) { keys[t] = bk; keys[ixj] = a; }
        }
      }
      __syncthreads();
    }
  }
  if (t < NPER) newpos[t] = -1;
  __syncthreads();
  if (t < KSEL)
    newpos[(int)(~(unsigned int)(keys[t] & 0xffffffffull))] = (short)t;
  __syncthreads();
  for (int r = w; r < KSEL; r += 8) {
    const int old = (int)(~(unsigned int)(keys[r] & 0xffffffffull));
    const float sc = tanhf(sscore[old]);
    xnew[(size_t)(g*KSEL + r)*64 + lane] =
        xin[(size_t)(gbase + old)*64 + lane] * sc;
  }
  for (int e = t; e < EPG; e += 512) {
    const int sl = esrc[ebase + e] - gbase;
    const int dl = edst[ebase + e] - gbase;
    const int ns = newpos[sl], nd2 = newpos[dl];
    if (ns >= 0 && nd2 >= 0) {
      const int slot = atomicAdd(&scnt, 1);
      eosrc[ebase + slot] = g*KSEL + ns;
      eodst[ebase + slot] = g*KSEL + nd2;
    }
  }
  __syncthreads();
  if (t == 0) g_ecnt[out_stage][g] = scnt;
}

// ============================================================================
// Fused tail: per graph, everything after pool0 (convs[1..4], pool1, gmp's).
// ============================================================================
__device__ __forceinline__ void conv_small(
    float* X, float* Z, float* ACC, float* w_s, const float* deg,
    const float* Wr, const float* Wl, const float* bias,
    int n, const int* esrc, const int* edst, int m, int gb, int ebase,
    int xs_off, int g, int t, int lane, int w)
{
  for (int i = t; i < n*64; i += 512) { Z[i] = 0.f; ACC[i] = 0.f; }
  __syncthreads();
  for (int kc = 0; kc < 4; ++kc) {
    for (int i = t; i < 1024; i += 512) w_s[i] = Wr[kc*1024 + i];
    __syncthreads();
    for (int r = w; r < n; r += 8) {
      float zacc = 0.f;
      #pragma unroll
      for (int k = 0; k < 16; ++k)
        zacc = fmaf(X[r*64 + kc*16 + k], w_s[k*64 + lane], zacc);
      Z[r*64 + lane] += zacc;
    }
    __syncthreads();
  }
  for (int e = w; e < m; e += 8) {
    const int sl = esrc[ebase + e] - gb;
    const int dl = edst[ebase + e] - gb;
    atomicAdd(&ACC[dl*64 + lane], Z[sl*64 + lane]);
  }
  __syncthreads();
  for (int i = t; i < n*64; i += 512) {
    const int r = i >> 6, f = i & 63;
    Z[i] = ACC[i] / fmaxf(deg[r], 1.f) + bias[f];
  }
  __syncthreads();
  for (int kc = 0; kc < 4; ++kc) {
    for (int i = t; i < 1024; i += 512) w_s[i] = Wl[kc*1024 + i];
    __syncthreads();
    for (int r = w; r < n; r += 8) {
      float zacc = 0.f;
      #pragma unroll
      for (int k = 0; k < 16; ++k)
        zacc = fmaf(X[r*64 + kc*16 + k], w_s[k*64 + lane], zacc);
      Z[r*64 + lane] += zacc;
    }
    __syncthreads();
  }
  for (int i = t; i < n*64; i += 512) X[i] = fmaxf(Z[i], 0.f);
  __syncthreads();
  if (t < 64) {
    float s = 0.f;
    for (int r = 0; r < n; ++r) s += X[r*64 + t];
    g_xs[g*384 + xs_off + t] = s / (float)n;
  }
  __syncthreads();
}

__global__ __launch_bounds__(512)
void tail(const float* __restrict__ cWr, const float* __restrict__ cWl,
          const float* __restrict__ cb,
          const float* __restrict__ pWr, const float* __restrict__ pWl,
          const float* __restrict__ pb)
{
  __shared__ float X[57*64], Z[57*64], ACC[57*64];   // 42.75 KB
  __shared__ float w_s[16*64];                       // 4 KB
  __shared__ float deg[64];
  __shared__ float zs[64], swl[64], sagg[64], sscore[64];
  __shared__ unsigned long long keys[64];
  __shared__ short newpos[64];
  __shared__ int scnt;
  const int g = blockIdx.x, t = threadIdx.x;
  const int lane = t & 63, w = t >> 6;
  const int ebase = g * EPG;

  for (int i = t; i < 57*64; i += 512) X[i] = g_feat[0][(size_t)(g*57)*64 + i];
  const int m0 = g_ecnt[0][g];
  if (t < 64) deg[t] = 0.f;
  __syncthreads();
  for (int e = t; e < m0; e += 512)
    atomicAdd(&deg[g_edst[0][ebase + e] - g*57], 1.f);
  __syncthreads();

  conv_small(X, Z, ACC, w_s, deg, cWr + 4096,  cWl + 4096,  cb + 64,
             57, g_esrc[0], g_edst[0], m0, g*57, ebase, 128, g, t, lane, w);
  conv_small(X, Z, ACC, w_s, deg, cWr + 8192,  cWl + 8192,  cb + 128,
             57, g_esrc[0], g_edst[0], m0, g*57, ebase, 192, g, t, lane, w);

  // ---- pool1: 57 -> 7 ----
  {
    const float pwrv = pWr[64 + lane], pwlv = pWl[64 + lane];
    for (int r = w; r < 57; r += 8) {
      float a = X[r*64 + lane] * pwrv, b = X[r*64 + lane] * pwlv;
      #pragma unroll
      for (int off = 32; off > 0; off >>= 1) {
        a += __shfl_xor(a, off);
        b += __shfl_xor(b, off);
      }
      if (lane == 0) { zs[r] = a; swl[r] = b; }
    }
    if (t < 64) sagg[t] = 0.f;
    if (t == 0) scnt = 0;
    __syncthreads();
    for (int e = t; e < m0; e += 512)
      atomicAdd(&sagg[g_edst[0][ebase + e] - g*57],
                zs[g_esrc[0][ebase + e] - g*57]);
    __syncthreads();
    if (t < 57) sscore[t] = sagg[t] / fmaxf(deg[t], 1.f) + pb[1] + swl[t];
    __syncthreads();
    if (t < 64) {
      unsigned long long key = 0ull;
      if (t < 57) {
        unsigned int u = __float_as_uint(sscore[t]);
        u = (u & 0x80000000u) ? ~u : (u | 0x80000000u);
        key = ((unsigned long long)u << 32) | (unsigned int)(~(unsigned int)t);
      }
      keys[t] = key;
    }
    __syncthreads();
    for (int kk = 2; kk <= 64; kk <<= 1) {
      for (int j = kk >> 1; j > 0; j >>= 1) {
        if (t < 64) {
          const int ixj = t ^ j;
          if (ixj > t) {
            const unsigned long long a = keys[t], bk = keys[ixj];
            const bool up = ((t & kk) == 0);
            if (up ? (a < bk) : (a > bk)) { keys[t] = bk; keys[ixj] = a; }
          }
        }
        __syncthreads();
      }
    }
    if (t < 64) newpos[t] = -1;
    __syncthreads();
    if (t < 7)
      newpos[(int)(~(unsigned int)(keys[t] & 0xffffffffull))] = (short)t;
    __syncthreads();
    for (int r = w; r < 7; r += 8) {
      const int old = (int)(~(unsigned int)(keys[r] & 0xffffffffull));
      const float sc = tanhf(sscore[old]);
      Z[r*64 + lane] = X[old*64 + lane] * sc;
    }
    for (int e = t; e < m0; e += 512) {
      const int sl = g_esrc[0][ebase + e] - g*57;
      const int dl = g_edst[0][ebase + e] - g*57;
      const int ns = newpos[sl], nd2 = newpos[dl];
      if (ns >= 0 && nd2 >= 0) {
        const int slot = atomicAdd(&scnt, 1);
        g_esrc[1][ebase + slot] = g*7 + ns;
        g_edst[1][ebase + slot] = g*7 + nd2;
      }
    }
    __syncthreads();
    for (int i = t; i < 7*64; i += 512) X[i] = Z[i];
    if (t < 64) deg[t] = 0.f;
    __syncthreads();
  }
  const int m1 = scnt;
  for (int e = t; e < m1; e += 512)
    atomicAdd(&deg[g_edst[1][ebase + e] - g*7], 1.f);
  __syncthreads();

  conv_small(X, Z, ACC, w_s, deg, cWr + 12288, cWl + 12288, cb + 192,
             7, g_esrc[1], g_edst[1], m1, g*7, ebase, 256, g, t, lane, w);
  conv_small(X, Z, ACC, w_s, deg, cWr + 16384, cWl + 16384, cb + 256,
             7, g_esrc[1], g_edst[1], m1, g*7, ebase, 320, g, t, lane, w);
}

// ============================================================================
// MLP head: h=[B,384] -> relu(h@W1+b1) -> @W2+b2 -> log_softmax
// ============================================================================
__global__ __launch_bounds__(64)
void head(const float* __restrict__ W1, const float* __restrict__ b1,
          const float* __restrict__ W2, const float* __restrict__ b2,
          float* __restrict__ out)
{
  __shared__ float h[384], o1[64], lg[2];
  const int g = blockIdx.x, t = threadIdx.x;
  for (int i = t; i < 384; i += 64) h[i] = g_xs[g*384 + i];
  __syncthreads();
  float acc = b1[t];
  for (int j = 0; j < 384; ++j) acc = fmaf(h[j], W1[j*64 + t], acc);
  o1[t] = fmaxf(acc, 0.f);
  __syncthreads();
  if (t < 2) {
    float a2 = b2[t];
    for (int f2 = 0; f2 < 64; ++f2) a2 = fmaf(o1[f2], W2[f2*2 + t], a2);
    lg[t] = a2;
  }
  __syncthreads();
  if (t < 2) {
    const float mx = fmaxf(lg[0], lg[1]);
    const float lse = mx + logf(expf(lg[0]-mx) + expf(lg[1]-mx));
    out[g*2 + t] = lg[t] - lse;
  }
}

// ============================================================================
extern "C" void kernel_launch(void* const* d_in, const int* in_sizes, int n_in,
                              void* d_out, int out_size, void* d_ws, size_t ws_size,
                              hipStream_t stream)
{
  (void)in_sizes; (void)n_in; (void)d_ws; (void)ws_size; (void)out_size;
  const float* x    = (const float*)d_in[0];
  const int*   ei   = (const int*)d_in[1];
  const float* c1Wr = (const float*)d_in[2];
  const float* c1Wl = (const float*)d_in[3];
  const float* c1b  = (const float*)d_in[4];
  const float* cWr  = (const float*)d_in[5];
  const float* cWl  = (const float*)d_in[6];
  const float* cb   = (const float*)d_in[7];
  const float* pWr  = (const float*)d_in[8];
  const float* pWl  = (const float*)d_in[9];
  const float* pb   = (const float*)d_in[10];
  const float* l1W  = (const float*)d_in[11];
  const float* l1b  = (const float*)d_in[12];
  const float* l2W  = (const float*)d_in[13];
  const float* l2b  = (const float*)d_in[14];
  float* out = (float*)d_out;
  const int* esrc = ei;
  const int* edst = ei + ETOT;

  // conv1 (160->64) + relu, xs[0]  (builds the shared CSR)
  mm_dual<160><<<NN0/64, 256, 0, stream>>>(x, -1, c1Wr, c1Wl, c1b, 0, 1);
  agg_full_build<<<NB, 1024, 0, stream>>>(0, 1, esrc, edst, 1, 0);
  // convs[0] + relu, xs[1]  (fused GEMM + aggregation, reuses CSR)
  conv_agg_fused<<<NB, 1024, 0, stream>>>(1, cWr, cWl, cb, 2, 64);
  // pool0: 512 -> 57  (reuses CSR)
  sag_pool0<<<NB, 512, 0, stream>>>(2, esrc, edst, pWr, pWl, pb, 0, 0);
  // fused tail: convs[1..4] + pool1 + gmp's
  tail<<<NB, 512, 0, stream>>>(cWr, cWl, cb, pWr, pWl, pb);
  // head
  head<<<NB, 64, 0, stream>>>(l1W, l1b, l2W, l2b, out);
}

// Round 18
// 365.552 us; speedup vs baseline: 1.0313x; 1.0216x over previous
//
#include <hip/hip_runtime.h>
#include <math.h>

namespace {
constexpr int NB   = 256;          // graphs
constexpr int EPG  = 8192;         // edges per graph
constexpr int ETOT = NB * EPG;     // 2,097,152
constexpr int FH   = 64;           // hidden dim
constexpr int NN0  = NB * 512;     // 131072 nodes at full size
}

// ---- scratch (device globals: write-before-read each call, deterministic) ----
__device__ float g_feat[3][(size_t)NN0 * FH];   // rotating node-feature buffers
__device__ float g_xs[NB * 6 * FH];             // jumping-knowledge concat
__device__ int   g_esrc[2][ETOT];               // compacted edges (stage 0/1)
__device__ int   g_edst[2][ETOT];
__device__ int   g_ecnt[2][NB];
__device__ unsigned short g_csr[ETOT];          // shared CSR (built once/call)
__device__ unsigned int   g_deg[NN0], g_start[NN0];

// ============================================================================
// Dual matmul (v6, RPB=64 — proven 87us; K-independent wall, do not iterate).
// ============================================================================
template<int K>
__global__ __launch_bounds__(256)
void mm_dual(const float* __restrict__ xext, int in_idx,
             const float* __restrict__ Wr, const float* __restrict__ Wl,
             const float* __restrict__ bias, int zr_idx, int xl_idx)
{
  constexpr int RPB = 64;           // rows per block
  constexpr int KC  = 32;           // k-chunk staged in LDS
  __shared__ float xs[RPB][KC];     // 8 KB
  __shared__ float wrT[KC/4][64][4];// 8 KB
  __shared__ float wlT[KC/4][64][4];// 8 KB
  const float* __restrict__ x = (in_idx < 0) ? xext : g_feat[in_idx];
  float* __restrict__ zr = g_feat[zr_idx];
  float* __restrict__ xl = g_feat[xl_idx];
  const int t = threadIdx.x;
  const int rowbase = blockIdx.x * RPB;
  const int f  = t & 31;
  const int rg = t >> 5;
  const int wv = t >> 6;
  const int wc = t & 63;
  const int wq = t >> 6;
  float ar0[8], ar1[8], al0[8], al1[8];
  #pragma unroll
  for (int r = 0; r < 8; ++r) { ar0[r]=0.f; ar1[r]=0.f; al0[r]=0.f; al1[r]=0.f; }

  for (int c = 0; c < K / KC; ++c) {
    __syncthreads();
    #pragma unroll
    for (int i = 0; i < 2; ++i) {
      const int idx = t + i * 256;
      const int r = idx >> 3, q = idx & 7;
      const float* gp = &x[(size_t)(rowbase + r) * K + c * KC + q * 4];
      float* lp = &xs[0][0] + (size_t)(i * 256 + wv * 64) * 4;
      __builtin_amdgcn_global_load_lds(
          (const __attribute__((address_space(1))) unsigned int*)gp,
          (__attribute__((address_space(3))) unsigned int*)lp, 16, 0, 0);
    }
    #pragma unroll
    for (int h = 0; h < 2; ++h) {
      const int kq = wq * 2 + h;
      #pragma unroll
      for (int i = 0; i < 4; ++i) {
        const int krow = c * KC + kq * 4 + i;
        wrT[kq][wc][i] = Wr[(size_t)krow * 64 + wc];
        wlT[kq][wc][i] = Wl[(size_t)krow * 64 + wc];
      }
    }
    __syncthreads();
    #pragma unroll 1
    for (int k4 = 0; k4 < KC / 4; ++k4) {
      const float4 wr0 = *reinterpret_cast<const float4*>(&wrT[k4][f][0]);
      const float4 wr1 = *reinterpret_cast<const float4*>(&wrT[k4][f+32][0]);
      const float4 wl0 = *reinterpret_cast<const float4*>(&wlT[k4][f][0]);
      const float4 wl1 = *reinterpret_cast<const float4*>(&wlT[k4][f+32][0]);
      #pragma unroll
      for (int r = 0; r < 8; ++r) {
        const float4 xv = *reinterpret_cast<const float4*>(&xs[rg*8 + r][k4*4]);
        float a0 = ar0[r], a1 = ar1[r], b0 = al0[r], b1 = al1[r];
        a0 = fmaf(xv.x, wr0.x, a0); a0 = fmaf(xv.y, wr0.y, a0);
        a0 = fmaf(xv.z, wr0.z, a0); a0 = fmaf(xv.w, wr0.w, a0);
        a1 = fmaf(xv.x, wr1.x, a1); a1 = fmaf(xv.y, wr1.y, a1);
        a1 = fmaf(xv.z, wr1.z, a1); a1 = fmaf(xv.w, wr1.w, a1);
        b0 = fmaf(xv.x, wl0.x, b0); b0 = fmaf(xv.y, wl0.y, b0);
        b0 = fmaf(xv.z, wl0.z, b0); b0 = fmaf(xv.w, wl0.w, b0);
        b1 = fmaf(xv.x, wl1.x, b1); b1 = fmaf(xv.y, wl1.y, b1);
        b1 = fmaf(xv.z, wl1.z, b1); b1 = fmaf(xv.w, wl1.w, b1);
        ar0[r] = a0; ar1[r] = a1; al0[r] = b0; al1[r] = b1;
      }
    }
  }
  const float bv0 = bias[f], bv1 = bias[f + 32];
  #pragma unroll
  for (int r = 0; r < 8; ++r) {
    const size_t row = (size_t)(rowbase + rg * 8 + r);
    zr[row * 64 + f]      = ar0[r];
    zr[row * 64 + f + 32] = ar1[r];
    xl[row * 64 + f]      = al0[r] + bv0;
    xl[row * 64 + f + 32] = al1[r] + bv1;
  }
}

// ============================================================================
// agg_full_build: CSR build + zr staged in LDS (128 KB); gather LDS-local.
// ============================================================================
__global__ __launch_bounds__(1024)
void agg_full_build(int zr_idx, int xl_idx,
                    const int* __restrict__ esrc, const int* __restrict__ edst,
                    int out_idx, int xs_off)
{
  __shared__ float zlds[512 * 64];                 // 128 KB
  __shared__ unsigned short csr[EPG];              // 16 KB
  __shared__ unsigned int hist[512], bufA[512], bufB[512];  // 6 KB
  __shared__ float red[16][64];                    // 4 KB
  const float* __restrict__ zr  = g_feat[zr_idx];
  const float* __restrict__ xlb = g_feat[xl_idx];
  float* __restrict__ xout = g_feat[out_idx];
  const int g = blockIdx.x, t = threadIdx.x;
  const int gbase = g * 512, ebase = g * EPG;
  if (t < 512) hist[t] = 0;
  __syncthreads();
  {
    const float4* zsrc = reinterpret_cast<const float4*>(zr + (size_t)gbase * 64);
    float4* zdst = reinterpret_cast<float4*>(zlds);
    #pragma unroll
    for (int i = 0; i < 8; ++i) zdst[t + i * 1024] = zsrc[t + i * 1024];
  }
  for (int e = t; e < EPG; e += 1024)
    atomicAdd(&hist[edst[ebase + e] - gbase], 1u);
  __syncthreads();
  if (t < 512) bufA[t] = hist[t];
  __syncthreads();
  unsigned int *pa = bufA, *pb = bufB;
  for (int off = 1; off < 512; off <<= 1) {
    if (t < 512) {
      unsigned int v = pa[t];
      if (t >= off) v += pa[t - off];
      pb[t] = v;
    }
    __syncthreads();
    unsigned int* tmp = pa; pa = pb; pb = tmp;
  }
  unsigned int excl = 0;
  if (t < 512) excl = pa[t] - hist[t];
  __syncthreads();
  if (t < 512) { bufA[t] = excl; bufB[t] = excl; }
  __syncthreads();
  for (int e = t; e < EPG; e += 1024) {
    const int sl = esrc[ebase + e] - gbase;
    const int dl = edst[ebase + e] - gbase;
    const unsigned int pos = atomicAdd(&bufB[dl], 1u);
    csr[pos] = (unsigned short)sl;
  }
  __syncthreads();
  if (t < 512) { g_deg[gbase + t] = hist[t]; g_start[gbase + t] = bufA[t]; }
  {
    unsigned int* gcsr32 = reinterpret_cast<unsigned int*>(&g_csr[ebase]);
    const unsigned int* lcsr32 = reinterpret_cast<const unsigned int*>(csr);
    for (int i = t; i < EPG/2; i += 1024) gcsr32[i] = lcsr32[i];
  }
  const int lane = t & 63, w = t >> 6;
  float psum = 0.f;
  for (int nd = w; nd < 512; nd += 16) {
    const unsigned int s = bufA[nd], d = hist[nd];
    float a0 = 0.f, a1 = 0.f, a2 = 0.f, a3 = 0.f;
    unsigned int j = 0;
    for (; j + 4 <= d; j += 4) {
      const int i0 = csr[s+j], i1 = csr[s+j+1], i2 = csr[s+j+2], i3 = csr[s+j+3];
      a0 += zlds[i0*64 + lane]; a1 += zlds[i1*64 + lane];
      a2 += zlds[i2*64 + lane]; a3 += zlds[i3*64 + lane];
    }
    for (; j < d; ++j) a0 += zlds[csr[s+j]*64 + lane];
    const float acc = (a0 + a1) + (a2 + a3);
    float v = acc / (float)(d > 0 ? d : 1) + xlb[(size_t)(gbase + nd)*64 + lane];
    v = fmaxf(v, 0.f);
    xout[(size_t)(gbase + nd)*64 + lane] = v;
    psum += v;
  }
  red[w][lane] = psum;
  __syncthreads();
  if (t < 64) {
    float s = 0.f;
    #pragma unroll
    for (int ww = 0; ww < 16; ++ww) s += red[ww][t];
    g_xs[g*384 + xs_off + t] = s * (1.f/512.f);
  }
}

// ============================================================================
// conv_agg_fused (v1, restored): replaces mm_dual<64>(full) + agg_full_use.
// Per graph: stage X1 (128KB) + CSR; z2/xl2 = X1@{Wr,Wl} in registers (wave
// owns 32 contiguous rows); write z2 back in place; LDS-local gather;
// relu+bias+gmp. 159.7 KB LDS. (v2 two-pass refuted: +19us from park/reload.)
// ============================================================================
__global__ __launch_bounds__(1024)
void conv_agg_fused(int x_idx, const float* __restrict__ Wr,
                    const float* __restrict__ Wl, const float* __restrict__ bias,
                    int out_idx, int xs_off)
{
  __shared__ float zlds[512 * 64];                 // 128 KB: X1, then z2
  __shared__ unsigned short csr[EPG];              // 16 KB
  __shared__ unsigned int hist[512], start[512];   // 4 KB
  __shared__ float w_r[1024], w_l[1024];           // 8 KB
  const float* __restrict__ X1 = g_feat[x_idx];
  float* __restrict__ xout = g_feat[out_idx];
  const int g = blockIdx.x, t = threadIdx.x;
  const int gbase = g * 512, ebase = g * EPG;
  const int lane = t & 63, w = t >> 6;             // 16 waves
  // stage X1 slice + CSR + deg/start
  {
    const float4* src = reinterpret_cast<const float4*>(X1 + (size_t)gbase * 64);
    float4* dst = reinterpret_cast<float4*>(zlds);
    #pragma unroll
    for (int i = 0; i < 8; ++i) dst[t + i * 1024] = src[t + i * 1024];
  }
  if (t < 512) { hist[t] = g_deg[gbase + t]; start[t] = g_start[gbase + t]; }
  {
    const uint4* c4 = reinterpret_cast<const uint4*>(&g_csr[ebase]);
    uint4* l4 = reinterpret_cast<uint4*>(csr);
    l4[t] = c4[t];
  }
  // GEMM: wave w owns rows [w*32, w*32+32)
  const int ndbase = w * 32;
  float zacc[32], xla[32];
  #pragma unroll
  for (int i = 0; i < 32; ++i) { zacc[i] = 0.f; xla[i] = 0.f; }
  #pragma unroll 1
  for (int c = 0; c < 4; ++c) {                    // 16-wide k chunks
    __syncthreads();                               // (1st iter: staging done)
    w_r[t] = Wr[c * 1024 + t];
    w_l[t] = Wl[c * 1024 + t];
    __syncthreads();
    #pragma unroll 1
    for (int k4 = 0; k4 < 4; ++k4) {
      const int kb = k4 * 4;
      const float wr0 = w_r[(kb+0)*64 + lane], wr1 = w_r[(kb+1)*64 + lane],
                  wr2 = w_r[(kb+2)*64 + lane], wr3 = w_r[(kb+3)*64 + lane];
      const float wl0 = w_l[(kb+0)*64 + lane], wl1 = w_l[(kb+1)*64 + lane],
                  wl2 = w_l[(kb+2)*64 + lane], wl3 = w_l[(kb+3)*64 + lane];
      #pragma unroll
      for (int i = 0; i < 32; ++i) {
        const float4 xv = *reinterpret_cast<const float4*>(
            &zlds[(ndbase + i) * 64 + c * 16 + kb]);
        float za = zacc[i], xa = xla[i];
        za = fmaf(xv.x, wr0, za); za = fmaf(xv.y, wr1, za);
        za = fmaf(xv.z, wr2, za); za = fmaf(xv.w, wr3, za);
        xa = fmaf(xv.x, wl0, xa); xa = fmaf(xv.y, wl1, xa);
        xa = fmaf(xv.z, wl2, xa); xa = fmaf(xv.w, wl3, xa);
        zacc[i] = za; xla[i] = xa;
      }
    }
  }
  __syncthreads();                                 // all X1 reads complete
  #pragma unroll
  for (int i = 0; i < 32; ++i)
    zlds[(ndbase + i) * 64 + lane] = zacc[i];      // z2 in place
  __syncthreads();
  // gather + epilogue
  const float bv = bias[lane];
  float psum = 0.f;
  #pragma unroll 1
  for (int i = 0; i < 32; ++i) {
    const int nd = ndbase + i;
    const unsigned int s = start[nd], d = hist[nd];
    float a0 = 0.f, a1 = 0.f, a2 = 0.f, a3 = 0.f;
    unsigned int j = 0;
    for (; j + 4 <= d; j += 4) {
      const int i0 = csr[s+j], i1 = csr[s+j+1], i2 = csr[s+j+2], i3 = csr[s+j+3];
      a0 += zlds[i0*64 + lane]; a1 += zlds[i1*64 + lane];
      a2 += zlds[i2*64 + lane]; a3 += zlds[i3*64 + lane];
    }
    for (; j < d; ++j) a0 += zlds[csr[s+j]*64 + lane];
    float v = ((a0 + a1) + (a2 + a3)) / (float)(d > 0 ? d : 1) + xla[i] + bv;
    v = fmaxf(v, 0.f);
    xout[(size_t)(gbase + nd)*64 + lane] = v;
    psum += v;
  }
  __syncthreads();                                 // zlds free now
  zlds[w * 64 + lane] = psum;
  __syncthreads();
  if (t < 64) {
    float s = 0.f;
    #pragma unroll
    for (int ww = 0; ww < 16; ++ww) s += zlds[ww*64 + t];
    g_xs[g*384 + xs_off + t] = s * (1.f/512.f);
  }
}

// ============================================================================
// SAG pool 0 (512 -> 57): CSR-based scalar aggregation (no LDS atomics).
// ============================================================================
__global__ __launch_bounds__(512)
void sag_pool0(int in_idx,
               const int* __restrict__ esrc, const int* __restrict__ edst,
               const float* __restrict__ wr, const float* __restrict__ wl,
               const float* __restrict__ pb,
               int xnew_idx, int out_stage)
{
  constexpr int NPER = 512, NPOW2 = 512, KSEL = 57;
  __shared__ float zs[NPER], swl[NPER], sscore[NPER];
  __shared__ unsigned long long keys[NPOW2];
  __shared__ unsigned short pcsr[EPG];
  __shared__ short newpos[NPER];
  __shared__ int scnt;
  const float* __restrict__ xin = g_feat[in_idx];
  float* __restrict__ xnew = g_feat[xnew_idx];
  int* __restrict__ eosrc = g_esrc[out_stage];
  int* __restrict__ eodst = g_edst[out_stage];
  const int g = blockIdx.x, t = threadIdx.x;
  const int gbase = g * NPER, ebase = g * EPG;
  const int lane = t & 63, w = t >> 6;            // 8 waves
  const float wrv = wr[lane], wlv = wl[lane];
  for (int nd = w; nd < NPER; nd += 8) {
    const float v = xin[(size_t)(gbase + nd)*64 + lane];
    float a = v * wrv, b = v * wlv;
    #pragma unroll
    for (int off = 32; off > 0; off >>= 1) {
      a += __shfl_xor(a, off);
      b += __shfl_xor(b, off);
    }
    if (lane == 0) { zs[nd] = a; swl[nd] = b; }
  }
  {
    const unsigned int* gcsr32 = reinterpret_cast<const unsigned int*>(&g_csr[ebase]);
    unsigned int* lcsr32 = reinterpret_cast<unsigned int*>(pcsr);
    for (int i = t; i < EPG/2; i += 512) lcsr32[i] = gcsr32[i];
  }
  if (t == 0) scnt = 0;
  __syncthreads();
  if (t < NPER) {
    const unsigned int s = g_start[gbase + t], d = g_deg[gbase + t];
    float a = 0.f;
    for (unsigned int j = 0; j < d; ++j) a += zs[pcsr[s + j]];
    sscore[t] = a / fmaxf((float)d, 1.f) + pb[0] + swl[t];
  }
  __syncthreads();
  if (t < NPOW2) {
    unsigned long long key = 0ull;
    if (t < NPER) {
      unsigned int u = __float_as_uint(sscore[t]);
      u = (u & 0x80000000u) ? ~u : (u | 0x80000000u);
      key = ((unsigned long long)u << 32) | (unsigned int)(~(unsigned int)t);
    }
    keys[t] = key;
  }
  __syncthreads();
  for (int kk = 2; kk <= NPOW2; kk <<= 1) {
    for (int j = kk >> 1; j > 0; j >>= 1) {
      if (t < NPOW2) {
        const int ixj = t ^ j;
        if (ixj > t) {
          const unsigned long long a = keys[t], bk = keys[ixj];
          const bool up = ((t & kk) == 0);
          if (up ? (a < bk) : (a > bk)) { keys[t] = bk; keys[ixj] = a; }
        }
      }
      __syncthreads();
    }
  }
  if (t < NPER) newpos[t] = -1;
  __syncthreads();
  if (t < KSEL)
    newpos[(int)(~(unsigned int)(keys[t] & 0xffffffffull))] = (short)t;
  __syncthreads();
  for (int r = w; r < KSEL; r += 8) {
    const int old = (int)(~(unsigned int)(keys[r] & 0xffffffffull));
    const float sc = tanhf(sscore[old]);
    xnew[(size_t)(g*KSEL + r)*64 + lane] =
        xin[(size_t)(gbase + old)*64 + lane] * sc;
  }
  for (int e = t; e < EPG; e += 512) {
    const int sl = esrc[ebase + e] - gbase;
    const int dl = edst[ebase + e] - gbase;
    const int ns = newpos[sl], nd2 = newpos[dl];
    if (ns >= 0 && nd2 >= 0) {
      const int slot = atomicAdd(&scnt, 1);
      eosrc[ebase + slot] = g*KSEL + ns;
      eodst[ebase + slot] = g*KSEL + nd2;
    }
  }
  __syncthreads();
  if (t == 0) g_ecnt[out_stage][g] = scnt;
}

// ============================================================================
// Fused tail: per graph, everything after pool0 (convs[1..4], pool1, gmp's).
// ============================================================================
__device__ __forceinline__ void conv_small(
    float* X, float* Z, float* ACC, float* w_s, const float* deg,
    const float* Wr, const float* Wl, const float* bias,
    int n, const int* esrc, const int* edst, int m, int gb, int ebase,
    int xs_off, int g, int t, int lane, int w)
{
  for (int i = t; i < n*64; i += 512) { Z[i] = 0.f; ACC[i] = 0.f; }
  __syncthreads();
  for (int kc = 0; kc < 4; ++kc) {
    for (int i = t; i < 1024; i += 512) w_s[i] = Wr[kc*1024 + i];
    __syncthreads();
    for (int r = w; r < n; r += 8) {
      float zacc = 0.f;
      #pragma unroll
      for (int k = 0; k < 16; ++k)
        zacc = fmaf(X[r*64 + kc*16 + k], w_s[k*64 + lane], zacc);
      Z[r*64 + lane] += zacc;
    }
    __syncthreads();
  }
  for (int e = w; e < m; e += 8) {
    const int sl = esrc[ebase + e] - gb;
    const int dl = edst[ebase + e] - gb;
    atomicAdd(&ACC[dl*64 + lane], Z[sl*64 + lane]);
  }
  __syncthreads();
  for (int i = t; i < n*64; i += 512) {
    const int r = i >> 6, f = i & 63;
    Z[i] = ACC[i] / fmaxf(deg[r], 1.f) + bias[f];
  }
  __syncthreads();
  for (int kc = 0; kc < 4; ++kc) {
    for (int i = t; i < 1024; i += 512) w_s[i] = Wl[kc*1024 + i];
    __syncthreads();
    for (int r = w; r < n; r += 8) {
      float zacc = 0.f;
      #pragma unroll
      for (int k = 0; k < 16; ++k)
        zacc = fmaf(X[r*64 + kc*16 + k], w_s[k*64 + lane], zacc);
      Z[r*64 + lane] += zacc;
    }
    __syncthreads();
  }
  for (int i = t; i < n*64; i += 512) X[i] = fmaxf(Z[i], 0.f);
  __syncthreads();
  if (t < 64) {
    float s = 0.f;
    for (int r = 0; r < n; ++r) s += X[r*64 + t];
    g_xs[g*384 + xs_off + t] = s / (float)n;
  }
  __syncthreads();
}

__global__ __launch_bounds__(512)
void tail(const float* __restrict__ cWr, const float* __restrict__ cWl,
          const float* __restrict__ cb,
          const float* __restrict__ pWr, const float* __restrict__ pWl,
          const float* __restrict__ pb)
{
  __shared__ float X[57*64], Z[57*64], ACC[57*64];   // 42.75 KB
  __shared__ float w_s[16*64];                       // 4 KB
  __shared__ float deg[64];
  __shared__ float zs[64], swl[64], sagg[64], sscore[64];
  __shared__ unsigned long long keys[64];
  __shared__ short newpos[64];
  __shared__ int scnt;
  const int g = blockIdx.x, t = threadIdx.x;
  const int lane = t & 63, w = t >> 6;
  const int ebase = g * EPG;

  for (int i = t; i < 57*64; i += 512) X[i] = g_feat[0][(size_t)(g*57)*64 + i];
  const int m0 = g_ecnt[0][g];
  if (t < 64) deg[t] = 0.f;
  __syncthreads();
  for (int e = t; e < m0; e += 512)
    atomicAdd(&deg[g_edst[0][ebase + e] - g*57], 1.f);
  __syncthreads();

  conv_small(X, Z, ACC, w_s, deg, cWr + 4096,  cWl + 4096,  cb + 64,
             57, g_esrc[0], g_edst[0], m0, g*57, ebase, 128, g, t, lane, w);
  conv_small(X, Z, ACC, w_s, deg, cWr + 8192,  cWl + 8192,  cb + 128,
             57, g_esrc[0], g_edst[0], m0, g*57, ebase, 192, g, t, lane, w);

  // ---- pool1: 57 -> 7 ----
  {
    const float pwrv = pWr[64 + lane], pwlv = pWl[64 + lane];
    for (int r = w; r < 57; r += 8) {
      float a = X[r*64 + lane] * pwrv, b = X[r*64 + lane] * pwlv;
      #pragma unroll
      for (int off = 32; off > 0; off >>= 1) {
        a += __shfl_xor(a, off);
        b += __shfl_xor(b, off);
      }
      if (lane == 0) { zs[r] = a; swl[r] = b; }
    }
    if (t < 64) sagg[t] = 0.f;
    if (t == 0) scnt = 0;
    __syncthreads();
    for (int e = t; e < m0; e += 512)
      atomicAdd(&sagg[g_edst[0][ebase + e] - g*57],
                zs[g_esrc[0][ebase + e] - g*57]);
    __syncthreads();
    if (t < 57) sscore[t] = sagg[t] / fmaxf(deg[t], 1.f) + pb[1] + swl[t];
    __syncthreads();
    if (t < 64) {
      unsigned long long key = 0ull;
      if (t < 57) {
        unsigned int u = __float_as_uint(sscore[t]);
        u = (u & 0x80000000u) ? ~u : (u | 0x80000000u);
        key = ((unsigned long long)u << 32) | (unsigned int)(~(unsigned int)t);
      }
      keys[t] = key;
    }
    __syncthreads();
    for (int kk = 2; kk <= 64; kk <<= 1) {
      for (int j = kk >> 1; j > 0; j >>= 1) {
        if (t < 64) {
          const int ixj = t ^ j;
          if (ixj > t) {
            const unsigned long long a = keys[t], bk = keys[ixj];
            const bool up = ((t & kk) == 0);
            if (up ? (a < bk) : (a > bk)) { keys[t] = bk; keys[ixj] = a; }
          }
        }
        __syncthreads();
      }
    }
    if (t < 64) newpos[t] = -1;
    __syncthreads();
    if (t < 7)
      newpos[(int)(~(unsigned int)(keys[t] & 0xffffffffull))] = (short)t;
    __syncthreads();
    for (int r = w; r < 7; r += 8) {
      const int old = (int)(~(unsigned int)(keys[r] & 0xffffffffull));
      const float sc = tanhf(sscore[old]);
      Z[r*64 + lane] = X[old*64 + lane] * sc;
    }
    for (int e = t; e < m0; e += 512) {
      const int sl = g_esrc[0][ebase + e] - g*57;
      const int dl = g_edst[0][ebase + e] - g*57;
      const int ns = newpos[sl], nd2 = newpos[dl];
      if (ns >= 0 && nd2 >= 0) {
        const int slot = atomicAdd(&scnt, 1);
        g_esrc[1][ebase + slot] = g*7 + ns;
        g_edst[1][ebase + slot] = g*7 + nd2;
      }
    }
    __syncthreads();
    for (int i = t; i < 7*64; i += 512) X[i] = Z[i];
    if (t < 64) deg[t] = 0.f;
    __syncthreads();
  }
  const int m1 = scnt;
  for (int e = t; e < m1; e += 512)
    atomicAdd(&deg[g_edst[1][ebase + e] - g*7], 1.f);
  __syncthreads();

  conv_small(X, Z, ACC, w_s, deg, cWr + 12288, cWl + 12288, cb + 192,
             7, g_esrc[1], g_edst[1], m1, g*7, ebase, 256, g, t, lane, w);
  conv_small(X, Z, ACC, w_s, deg, cWr + 16384, cWl + 16384, cb + 256,
             7, g_esrc[1], g_edst[1], m1, g*7, ebase, 320, g, t, lane, w);
}

// ============================================================================
// MLP head: h=[B,384] -> relu(h@W1+b1) -> @W2+b2 -> log_softmax
// ============================================================================
__global__ __launch_bounds__(64)
void head(const float* __restrict__ W1, const float* __restrict__ b1,
          const float* __restrict__ W2, const float* __restrict__ b2,
          float* __restrict__ out)
{
  __shared__ float h[384], o1[64], lg[2];
  const int g = blockIdx.x, t = threadIdx.x;
  for (int i = t; i < 384; i += 64) h[i] = g_xs[g*384 + i];
  __syncthreads();
  float acc = b1[t];
  for (int j = 0; j < 384; ++j) acc = fmaf(h[j], W1[j*64 + t], acc);
  o1[t] = fmaxf(acc, 0.f);
  __syncthreads();
  if (t < 2) {
    float a2 = b2[t];
    for (int f2 = 0; f2 < 64; ++f2) a2 = fmaf(o1[f2], W2[f2*2 + t], a2);
    lg[t] = a2;
  }
  __syncthreads();
  if (t < 2) {
    const float mx = fmaxf(lg[0], lg[1]);
    const float lse = mx + logf(expf(lg[0]-mx) + expf(lg[1]-mx));
    out[g*2 + t] = lg[t] - lse;
  }
}

// ============================================================================
extern "C" void kernel_launch(void* const* d_in, const int* in_sizes, int n_in,
                              void* d_out, int out_size, void* d_ws, size_t ws_size,
                              hipStream_t stream)
{
  (void)in_sizes; (void)n_in; (void)d_ws; (void)ws_size; (void)out_size;
  const float* x    = (const float*)d_in[0];
  const int*   ei   = (const int*)d_in[1];
  const float* c1Wr = (const float*)d_in[2];
  const float* c1Wl = (const float*)d_in[3];
  const float* c1b  = (const float*)d_in[4];
  const float* cWr  = (const float*)d_in[5];
  const float* cWl  = (const float*)d_in[6];
  const float* cb   = (const float*)d_in[7];
  const float* pWr  = (const float*)d_in[8];
  const float* pWl  = (const float*)d_in[9];
  const float* pb   = (const float*)d_in[10];
  const float* l1W  = (const float*)d_in[11];
  const float* l1b  = (const float*)d_in[12];
  const float* l2W  = (const float*)d_in[13];
  const float* l2b  = (const float*)d_in[14];
  float* out = (float*)d_out;
  const int* esrc = ei;
  const int* edst = ei + ETOT;

  // conv1 (160->64) + relu, xs[0]  (builds the shared CSR)
  mm_dual<160><<<NN0/64, 256, 0, stream>>>(x, -1, c1Wr, c1Wl, c1b, 0, 1);
  agg_full_build<<<NB, 1024, 0, stream>>>(0, 1, esrc, edst, 1, 0);
  // convs[0] + relu, xs[1]  (fused GEMM + aggregation, reuses CSR)
  conv_agg_fused<<<NB, 1024, 0, stream>>>(1, cWr, cWl, cb, 2, 64);
  // pool0: 512 -> 57  (reuses CSR)
  sag_pool0<<<NB, 512, 0, stream>>>(2, esrc, edst, pWr, pWl, pb, 0, 0);
  // fused tail: convs[1..4] + pool1 + gmp's
  tail<<<NB, 512, 0, stream>>>(cWr, cWl, cb, pWr, pWl, pb);
  // head
  head<<<NB, 64, 0, stream>>>(l1W, l1b, l2W, l2b, out);
}

// Round 19
// 341.219 us; speedup vs baseline: 1.1049x; 1.0713x over previous
//
#include <hip/hip_runtime.h>
#include <math.h>

namespace {
constexpr int NB   = 256;          // graphs
constexpr int EPG  = 8192;         // edges per graph
constexpr int ETOT = NB * EPG;     // 2,097,152
constexpr int FH   = 64;           // hidden dim
constexpr int NN0  = NB * 512;     // 131072 nodes at full size
}

// ---- scratch (device globals: write-before-read each call, deterministic) ----
__device__ float g_feat[3][(size_t)NN0 * FH];   // rotating node-feature buffers
__device__ float g_xs[NB * 6 * FH];             // jumping-knowledge concat
__device__ int   g_esrc[2][ETOT];               // compacted edges (stage 0/1)
__device__ int   g_edst[2][ETOT];
__device__ int   g_ecnt[2][NB];
__device__ unsigned short g_csr[ETOT];          // shared CSR (built once/call)
__device__ unsigned int   g_deg[NN0], g_start[NN0];

// ============================================================================
// Dual matmul (v6, RPB=64 — proven 87us; K-independent wall, do not iterate).
// ============================================================================
template<int K>
__global__ __launch_bounds__(256)
void mm_dual(const float* __restrict__ xext, int in_idx,
             const float* __restrict__ Wr, const float* __restrict__ Wl,
             const float* __restrict__ bias, int zr_idx, int xl_idx)
{
  constexpr int RPB = 64;           // rows per block
  constexpr int KC  = 32;           // k-chunk staged in LDS
  __shared__ float xs[RPB][KC];     // 8 KB
  __shared__ float wrT[KC/4][64][4];// 8 KB
  __shared__ float wlT[KC/4][64][4];// 8 KB
  const float* __restrict__ x = (in_idx < 0) ? xext : g_feat[in_idx];
  float* __restrict__ zr = g_feat[zr_idx];
  float* __restrict__ xl = g_feat[xl_idx];
  const int t = threadIdx.x;
  const int rowbase = blockIdx.x * RPB;
  const int f  = t & 31;
  const int rg = t >> 5;
  const int wv = t >> 6;
  const int wc = t & 63;
  const int wq = t >> 6;
  float ar0[8], ar1[8], al0[8], al1[8];
  #pragma unroll
  for (int r = 0; r < 8; ++r) { ar0[r]=0.f; ar1[r]=0.f; al0[r]=0.f; al1[r]=0.f; }

  for (int c = 0; c < K / KC; ++c) {
    __syncthreads();
    #pragma unroll
    for (int i = 0; i < 2; ++i) {
      const int idx = t + i * 256;
      const int r = idx >> 3, q = idx & 7;
      const float* gp = &x[(size_t)(rowbase + r) * K + c * KC + q * 4];
      float* lp = &xs[0][0] + (size_t)(i * 256 + wv * 64) * 4;
      __builtin_amdgcn_global_load_lds(
          (const __attribute__((address_space(1))) unsigned int*)gp,
          (__attribute__((address_space(3))) unsigned int*)lp, 16, 0, 0);
    }
    #pragma unroll
    for (int h = 0; h < 2; ++h) {
      const int kq = wq * 2 + h;
      #pragma unroll
      for (int i = 0; i < 4; ++i) {
        const int krow = c * KC + kq * 4 + i;
        wrT[kq][wc][i] = Wr[(size_t)krow * 64 + wc];
        wlT[kq][wc][i] = Wl[(size_t)krow * 64 + wc];
      }
    }
    __syncthreads();
    #pragma unroll 1
    for (int k4 = 0; k4 < KC / 4; ++k4) {
      const float4 wr0 = *reinterpret_cast<const float4*>(&wrT[k4][f][0]);
      const float4 wr1 = *reinterpret_cast<const float4*>(&wrT[k4][f+32][0]);
      const float4 wl0 = *reinterpret_cast<const float4*>(&wlT[k4][f][0]);
      const float4 wl1 = *reinterpret_cast<const float4*>(&wlT[k4][f+32][0]);
      #pragma unroll
      for (int r = 0; r < 8; ++r) {
        const float4 xv = *reinterpret_cast<const float4*>(&xs[rg*8 + r][k4*4]);
        float a0 = ar0[r], a1 = ar1[r], b0 = al0[r], b1 = al1[r];
        a0 = fmaf(xv.x, wr0.x, a0); a0 = fmaf(xv.y, wr0.y, a0);
        a0 = fmaf(xv.z, wr0.z, a0); a0 = fmaf(xv.w, wr0.w, a0);
        a1 = fmaf(xv.x, wr1.x, a1); a1 = fmaf(xv.y, wr1.y, a1);
        a1 = fmaf(xv.z, wr1.z, a1); a1 = fmaf(xv.w, wr1.w, a1);
        b0 = fmaf(xv.x, wl0.x, b0); b0 = fmaf(xv.y, wl0.y, b0);
        b0 = fmaf(xv.z, wl0.z, b0); b0 = fmaf(xv.w, wl0.w, b0);
        b1 = fmaf(xv.x, wl1.x, b1); b1 = fmaf(xv.y, wl1.y, b1);
        b1 = fmaf(xv.z, wl1.z, b1); b1 = fmaf(xv.w, wl1.w, b1);
        ar0[r] = a0; ar1[r] = a1; al0[r] = b0; al1[r] = b1;
      }
    }
  }
  const float bv0 = bias[f], bv1 = bias[f + 32];
  #pragma unroll
  for (int r = 0; r < 8; ++r) {
    const size_t row = (size_t)(rowbase + rg * 8 + r);
    zr[row * 64 + f]      = ar0[r];
    zr[row * 64 + f + 32] = ar1[r];
    xl[row * 64 + f]      = al0[r] + bv0;
    xl[row * 64 + f + 32] = al1[r] + bv1;
  }
}

// ============================================================================
// agg_full_build: CSR build + zr staged in LDS (128 KB); gather LDS-local.
// ============================================================================
__global__ __launch_bounds__(1024)
void agg_full_build(int zr_idx, int xl_idx,
                    const int* __restrict__ esrc, const int* __restrict__ edst,
                    int out_idx, int xs_off)
{
  __shared__ float zlds[512 * 64];                 // 128 KB
  __shared__ unsigned short csr[EPG];              // 16 KB
  __shared__ unsigned int hist[512], bufA[512], bufB[512];  // 6 KB
  __shared__ float red[16][64];                    // 4 KB
  const float* __restrict__ zr  = g_feat[zr_idx];
  const float* __restrict__ xlb = g_feat[xl_idx];
  float* __restrict__ xout = g_feat[out_idx];
  const int g = blockIdx.x, t = threadIdx.x;
  const int gbase = g * 512, ebase = g * EPG;
  if (t < 512) hist[t] = 0;
  __syncthreads();
  {
    const float4* zsrc = reinterpret_cast<const float4*>(zr + (size_t)gbase * 64);
    float4* zdst = reinterpret_cast<float4*>(zlds);
    #pragma unroll
    for (int i = 0; i < 8; ++i) zdst[t + i * 1024] = zsrc[t + i * 1024];
  }
  for (int e = t; e < EPG; e += 1024)
    atomicAdd(&hist[edst[ebase + e] - gbase], 1u);
  __syncthreads();
  if (t < 512) bufA[t] = hist[t];
  __syncthreads();
  unsigned int *pa = bufA, *pb = bufB;
  for (int off = 1; off < 512; off <<= 1) {
    if (t < 512) {
      unsigned int v = pa[t];
      if (t >= off) v += pa[t - off];
      pb[t] = v;
    }
    __syncthreads();
    unsigned int* tmp = pa; pa = pb; pb = tmp;
  }
  unsigned int excl = 0;
  if (t < 512) excl = pa[t] - hist[t];
  __syncthreads();
  if (t < 512) { bufA[t] = excl; bufB[t] = excl; }
  __syncthreads();
  for (int e = t; e < EPG; e += 1024) {
    const int sl = esrc[ebase + e] - gbase;
    const int dl = edst[ebase + e] - gbase;
    const unsigned int pos = atomicAdd(&bufB[dl], 1u);
    csr[pos] = (unsigned short)sl;
  }
  __syncthreads();
  if (t < 512) { g_deg[gbase + t] = hist[t]; g_start[gbase + t] = bufA[t]; }
  {
    unsigned int* gcsr32 = reinterpret_cast<unsigned int*>(&g_csr[ebase]);
    const unsigned int* lcsr32 = reinterpret_cast<const unsigned int*>(csr);
    for (int i = t; i < EPG/2; i += 1024) gcsr32[i] = lcsr32[i];
  }
  const int lane = t & 63, w = t >> 6;
  float psum = 0.f;
  for (int nd = w; nd < 512; nd += 16) {
    const unsigned int s = bufA[nd], d = hist[nd];
    float a0 = 0.f, a1 = 0.f, a2 = 0.f, a3 = 0.f;
    unsigned int j = 0;
    for (; j + 4 <= d; j += 4) {
      const int i0 = csr[s+j], i1 = csr[s+j+1], i2 = csr[s+j+2], i3 = csr[s+j+3];
      a0 += zlds[i0*64 + lane]; a1 += zlds[i1*64 + lane];
      a2 += zlds[i2*64 + lane]; a3 += zlds[i3*64 + lane];
    }
    for (; j < d; ++j) a0 += zlds[csr[s+j]*64 + lane];
    const float acc = (a0 + a1) + (a2 + a3);
    float v = acc / (float)(d > 0 ? d : 1) + xlb[(size_t)(gbase + nd)*64 + lane];
    v = fmaxf(v, 0.f);
    xout[(size_t)(gbase + nd)*64 + lane] = v;
    psum += v;
  }
  red[w][lane] = psum;
  __syncthreads();
  if (t < 64) {
    float s = 0.f;
    #pragma unroll
    for (int ww = 0; ww < 16; ++ww) s += red[ww][t];
    g_xs[g*384 + xs_off + t] = s * (1.f/512.f);
  }
}

// ============================================================================
// conv_agg_pool: fused convs[0]+agg (v1 structure) + sag_pool0, one kernel.
// x2 never leaves LDS (drops the 66 MB x2 HBM round-trip + a launch + CSR copy).
// LDS overlays (barrier-ordered): wpf = weights -> red -> zs/swl/sscore;
// u2 = hist/start -> keys; csrbuf = csr -> newpos. Total 159,748 B.
// ============================================================================
__global__ __launch_bounds__(1024)
void conv_agg_pool(int x_idx, const float* __restrict__ Wr,
                   const float* __restrict__ Wl, const float* __restrict__ bias,
                   const int* __restrict__ esrc, const int* __restrict__ edst,
                   const float* __restrict__ pwr, const float* __restrict__ pwl,
                   const float* __restrict__ pb,
                   int xnew_idx, int xs_off)
{
  __shared__ float zlds[512 * 64];                        // 128 KB: X1 -> z2 -> x2
  __shared__ unsigned short csrbuf[EPG];                  // 16 KB: csr -> newpos
  __shared__ __align__(16) unsigned long long u2[512];    // 4 KB: hist/start -> keys
  __shared__ float wpf[2048];                             // 8 KB: w_r/w_l -> red -> zs/swl/sscore
  __shared__ int scnt;
  unsigned int* hist  = reinterpret_cast<unsigned int*>(u2);        // [0..512)
  unsigned int* start = hist + 512;                                 // [512..1024)
  const float* __restrict__ X1 = g_feat[x_idx];
  float* __restrict__ xnew = g_feat[xnew_idx];
  const int g = blockIdx.x, t = threadIdx.x;
  const int gbase = g * 512, ebase = g * EPG;
  const int lane = t & 63, w = t >> 6;                    // 16 waves
  const int ndbase = w * 32;
  // ---- stage X1 + CSR + deg/start ----
  {
    const float4* src = reinterpret_cast<const float4*>(X1 + (size_t)gbase * 64);
    float4* dst = reinterpret_cast<float4*>(zlds);
    #pragma unroll
    for (int i = 0; i < 8; ++i) dst[t + i * 1024] = src[t + i * 1024];
  }
  if (t < 512) { hist[t] = g_deg[gbase + t]; start[t] = g_start[gbase + t]; }
  {
    const uint4* c4 = reinterpret_cast<const uint4*>(&g_csr[ebase]);
    uint4* l4 = reinterpret_cast<uint4*>(csrbuf);
    l4[t] = c4[t];
  }
  if (t == 0) scnt = 0;
  // ---- GEMM: z2/xl2, wave owns rows [ndbase, ndbase+32) ----
  float zacc[32], xla[32];
  #pragma unroll
  for (int i = 0; i < 32; ++i) { zacc[i] = 0.f; xla[i] = 0.f; }
  float* w_r = wpf;            // [0..1024)
  float* w_l = wpf + 1024;     // [1024..2048)
  #pragma unroll 1
  for (int c = 0; c < 4; ++c) {
    __syncthreads();                                     // staging done / WAR w
    w_r[t] = Wr[c * 1024 + t];
    w_l[t] = Wl[c * 1024 + t];
    __syncthreads();
    #pragma unroll 1
    for (int k4 = 0; k4 < 4; ++k4) {
      const int kb = k4 * 4;
      const float wr0 = w_r[(kb+0)*64 + lane], wr1 = w_r[(kb+1)*64 + lane],
                  wr2 = w_r[(kb+2)*64 + lane], wr3 = w_r[(kb+3)*64 + lane];
      const float wl0 = w_l[(kb+0)*64 + lane], wl1 = w_l[(kb+1)*64 + lane],
                  wl2 = w_l[(kb+2)*64 + lane], wl3 = w_l[(kb+3)*64 + lane];
      #pragma unroll
      for (int i = 0; i < 32; ++i) {
        const float4 xv = *reinterpret_cast<const float4*>(
            &zlds[(ndbase + i) * 64 + c * 16 + kb]);
        float za = zacc[i], xa = xla[i];
        za = fmaf(xv.x, wr0, za); za = fmaf(xv.y, wr1, za);
        za = fmaf(xv.z, wr2, za); za = fmaf(xv.w, wr3, za);
        xa = fmaf(xv.x, wl0, xa); xa = fmaf(xv.y, wl1, xa);
        xa = fmaf(xv.z, wl2, xa); xa = fmaf(xv.w, wl3, xa);
        zacc[i] = za; xla[i] = xa;
      }
    }
  }
  __syncthreads();                                       // all X1 reads complete
  #pragma unroll
  for (int i = 0; i < 32; ++i)
    zlds[(ndbase + i) * 64 + lane] = zacc[i];            // z2 in place
  __syncthreads();
  // ---- gather + epilogue: x2 = relu(agg/deg + xl + b) kept in zacc ----
  const float bv = bias[lane];
  float psum = 0.f;
  #pragma unroll 1
  for (int i = 0; i < 32; ++i) {
    const int nd = ndbase + i;
    const unsigned int s = start[nd], d = hist[nd];
    float a0 = 0.f, a1 = 0.f, a2 = 0.f, a3 = 0.f;
    unsigned int j = 0;
    for (; j + 4 <= d; j += 4) {
      const int i0 = csrbuf[s+j], i1 = csrbuf[s+j+1],
                i2 = csrbuf[s+j+2], i3 = csrbuf[s+j+3];
      a0 += zlds[i0*64 + lane]; a1 += zlds[i1*64 + lane];
      a2 += zlds[i2*64 + lane]; a3 += zlds[i3*64 + lane];
    }
    for (; j < d; ++j) a0 += zlds[csrbuf[s+j]*64 + lane];
    float v = ((a0 + a1) + (a2 + a3)) / (float)(d > 0 ? d : 1) + xla[i] + bv;
    v = fmaxf(v, 0.f);
    zacc[i] = v;                                         // x2 stays in regs
    psum += v;
  }
  __syncthreads();                                       // all z2 reads done
  #pragma unroll
  for (int i = 0; i < 32; ++i)
    zlds[(ndbase + i) * 64 + lane] = zacc[i];            // x2 into LDS
  wpf[w * 64 + lane] = psum;                             // red overlay (weights dead)
  __syncthreads();
  if (t < 64) {
    float s = 0.f;
    #pragma unroll
    for (int ww = 0; ww < 16; ++ww) s += wpf[ww*64 + t];
    g_xs[g*384 + xs_off + t] = s * (1.f/512.f);
  }
  __syncthreads();                                       // red dead
  // ---- pool0: dots ----
  float* zs     = wpf;                                   // [0..512)
  float* swl    = wpf + 512;                             // [512..1024)
  float* sscore = wpf + 1024;                            // [1024..1536)
  const float pwrv = pwr[lane], pwlv = pwl[lane];
  for (int nd = w; nd < 512; nd += 16) {
    const float v = zlds[nd*64 + lane];
    float a = v * pwrv, b = v * pwlv;
    #pragma unroll
    for (int off = 32; off > 0; off >>= 1) {
      a += __shfl_xor(a, off);
      b += __shfl_xor(b, off);
    }
    if (lane == 0) { zs[nd] = a; swl[nd] = b; }
  }
  __syncthreads();
  // ---- scores via CSR gather over zs ----
  if (t < 512) {
    const unsigned int s = start[t], d = hist[t];
    float a = 0.f;
    for (unsigned int j = 0; j < d; ++j) a += zs[csrbuf[s + j]];
    sscore[t] = a / fmaxf((float)d, 1.f) + pb[0] + swl[t];
  }
  __syncthreads();                                       // hist/start & csr dead
  // ---- pack keys (overlay u2) + bitonic sort ----
  unsigned long long* keys = u2;
  if (t < 512) {
    unsigned int u = __float_as_uint(sscore[t]);
    u = (u & 0x80000000u) ? ~u : (u | 0x80000000u);
    keys[t] = ((unsigned long long)u << 32) | (unsigned int)(~(unsigned int)t);
  }
  __syncthreads();
  for (int kk = 2; kk <= 512; kk <<= 1) {
    for (int j = kk >> 1; j > 0; j >>= 1) {
      if (t < 512) {
        const int ixj = t ^ j;
        if (ixj > t) {
          const unsigned long long a = keys[t], bk = keys[ixj];
          const bool up = ((t & kk) == 0);
          if (up ? (a < bk) : (a > bk)) { keys[t] = bk; keys[ixj] = a; }
        }
      }
      __syncthreads();
    }
  }
  // ---- newpos (overlay csrbuf) + xnew gather + edge compaction ----
  short* np = reinterpret_cast<short*>(csrbuf);
  if (t < 512) np[t] = -1;
  __syncthreads();
  if (t < 57)
    np[(int)(~(unsigned int)(keys[t] & 0xffffffffull))] = (short)t;
  __syncthreads();
  for (int r = w; r < 57; r += 16) {
    const int old = (int)(~(unsigned int)(keys[r] & 0xffffffffull));
    const float sc = tanhf(sscore[old]);
    xnew[(size_t)(g*57 + r)*64 + lane] = zlds[old*64 + lane] * sc;
  }
  for (int e = t; e < EPG; e += 1024) {
    const int sl = esrc[ebase + e] - gbase;
    const int dl = edst[ebase + e] - gbase;
    const int ns = np[sl], nd2 = np[dl];
    if (ns >= 0 && nd2 >= 0) {
      const int slot = atomicAdd(&scnt, 1);
      g_esrc[0][ebase + slot] = g*57 + ns;
      g_edst[0][ebase + slot] = g*57 + nd2;
    }
  }
  __syncthreads();
  if (t == 0) g_ecnt[0][g] = scnt;
}

// ============================================================================
// Fused tail: per graph, everything after pool0 (convs[1..4], pool1, gmp's).
// ============================================================================
__device__ __forceinline__ void conv_small(
    float* X, float* Z, float* ACC, float* w_s, const float* deg,
    const float* Wr, const float* Wl, const float* bias,
    int n, const int* esrc, const int* edst, int m, int gb, int ebase,
    int xs_off, int g, int t, int lane, int w)
{
  for (int i = t; i < n*64; i += 512) { Z[i] = 0.f; ACC[i] = 0.f; }
  __syncthreads();
  for (int kc = 0; kc < 4; ++kc) {
    for (int i = t; i < 1024; i += 512) w_s[i] = Wr[kc*1024 + i];
    __syncthreads();
    for (int r = w; r < n; r += 8) {
      float zacc = 0.f;
      #pragma unroll
      for (int k = 0; k < 16; ++k)
        zacc = fmaf(X[r*64 + kc*16 + k], w_s[k*64 + lane], zacc);
      Z[r*64 + lane] += zacc;
    }
    __syncthreads();
  }
  for (int e = w; e < m; e += 8) {
    const int sl = esrc[ebase + e] - gb;
    const int dl = edst[ebase + e] - gb;
    atomicAdd(&ACC[dl*64 + lane], Z[sl*64 + lane]);
  }
  __syncthreads();
  for (int i = t; i < n*64; i += 512) {
    const int r = i >> 6, f = i & 63;
    Z[i] = ACC[i] / fmaxf(deg[r], 1.f) + bias[f];
  }
  __syncthreads();
  for (int kc = 0; kc < 4; ++kc) {
    for (int i = t; i < 1024; i += 512) w_s[i] = Wl[kc*1024 + i];
    __syncthreads();
    for (int r = w; r < n; r += 8) {
      float zacc = 0.f;
      #pragma unroll
      for (int k = 0; k < 16; ++k)
        zacc = fmaf(X[r*64 + kc*16 + k], w_s[k*64 + lane], zacc);
      Z[r*64 + lane] += zacc;
    }
    __syncthreads();
  }
  for (int i = t; i < n*64; i += 512) X[i] = fmaxf(Z[i], 0.f);
  __syncthreads();
  if (t < 64) {
    float s = 0.f;
    for (int r = 0; r < n; ++r) s += X[r*64 + t];
    g_xs[g*384 + xs_off + t] = s / (float)n;
  }
  __syncthreads();
}

__global__ __launch_bounds__(512)
void tail(const float* __restrict__ cWr, const float* __restrict__ cWl,
          const float* __restrict__ cb,
          const float* __restrict__ pWr, const float* __restrict__ pWl,
          const float* __restrict__ pb)
{
  __shared__ float X[57*64], Z[57*64], ACC[57*64];   // 42.75 KB
  __shared__ float w_s[16*64];                       // 4 KB
  __shared__ float deg[64];
  __shared__ float zs[64], swl[64], sagg[64], sscore[64];
  __shared__ unsigned long long keys[64];
  __shared__ short newpos[64];
  __shared__ int scnt;
  const int g = blockIdx.x, t = threadIdx.x;
  const int lane = t & 63, w = t >> 6;
  const int ebase = g * EPG;

  for (int i = t; i < 57*64; i += 512) X[i] = g_feat[0][(size_t)(g*57)*64 + i];
  const int m0 = g_ecnt[0][g];
  if (t < 64) deg[t] = 0.f;
  __syncthreads();
  for (int e = t; e < m0; e += 512)
    atomicAdd(&deg[g_edst[0][ebase + e] - g*57], 1.f);
  __syncthreads();

  conv_small(X, Z, ACC, w_s, deg, cWr + 4096,  cWl + 4096,  cb + 64,
             57, g_esrc[0], g_edst[0], m0, g*57, ebase, 128, g, t, lane, w);
  conv_small(X, Z, ACC, w_s, deg, cWr + 8192,  cWl + 8192,  cb + 128,
             57, g_esrc[0], g_edst[0], m0, g*57, ebase, 192, g, t, lane, w);

  // ---- pool1: 57 -> 7 ----
  {
    const float pwrv = pWr[64 + lane], pwlv = pWl[64 + lane];
    for (int r = w; r < 57; r += 8) {
      float a = X[r*64 + lane] * pwrv, b = X[r*64 + lane] * pwlv;
      #pragma unroll
      for (int off = 32; off > 0; off >>= 1) {
        a += __shfl_xor(a, off);
        b += __shfl_xor(b, off);
      }
      if (lane == 0) { zs[r] = a; swl[r] = b; }
    }
    if (t < 64) sagg[t] = 0.f;
    if (t == 0) scnt = 0;
    __syncthreads();
    for (int e = t; e < m0; e += 512)
      atomicAdd(&sagg[g_edst[0][ebase + e] - g*57],
                zs[g_esrc[0][ebase + e] - g*57]);
    __syncthreads();
    if (t < 57) sscore[t] = sagg[t] / fmaxf(deg[t], 1.f) + pb[1] + swl[t];
    __syncthreads();
    if (t < 64) {
      unsigned long long key = 0ull;
      if (t < 57) {
        unsigned int u = __float_as_uint(sscore[t]);
        u = (u & 0x80000000u) ? ~u : (u | 0x80000000u);
        key = ((unsigned long long)u << 32) | (unsigned int)(~(unsigned int)t);
      }
      keys[t] = key;
    }
    __syncthreads();
    for (int kk = 2; kk <= 64; kk <<= 1) {
      for (int j = kk >> 1; j > 0; j >>= 1) {
        if (t < 64) {
          const int ixj = t ^ j;
          if (ixj > t) {
            const unsigned long long a = keys[t], bk = keys[ixj];
            const bool up = ((t & kk) == 0);
            if (up ? (a < bk) : (a > bk)) { keys[t] = bk; keys[ixj] = a; }
          }
        }
        __syncthreads();
      }
    }
    if (t < 64) newpos[t] = -1;
    __syncthreads();
    if (t < 7)
      newpos[(int)(~(unsigned int)(keys[t] & 0xffffffffull))] = (short)t;
    __syncthreads();
    for (int r = w; r < 7; r += 8) {
      const int old = (int)(~(unsigned int)(keys[r] & 0xffffffffull));
      const float sc = tanhf(sscore[old]);
      Z[r*64 + lane] = X[old*64 + lane] * sc;
    }
    for (int e = t; e < m0; e += 512) {
      const int sl = g_esrc[0][ebase + e] - g*57;
      const int dl = g_edst[0][ebase + e] - g*57;
      const int ns = newpos[sl], nd2 = newpos[dl];
      if (ns >= 0 && nd2 >= 0) {
        const int slot = atomicAdd(&scnt, 1);
        g_esrc[1][ebase + slot] = g*7 + ns;
        g_edst[1][ebase + slot] = g*7 + nd2;
      }
    }
    __syncthreads();
    for (int i = t; i < 7*64; i += 512) X[i] = Z[i];
    if (t < 64) deg[t] = 0.f;
    __syncthreads();
  }
  const int m1 = scnt;
  for (int e = t; e < m1; e += 512)
    atomicAdd(&deg[g_edst[1][ebase + e] - g*7], 1.f);
  __syncthreads();

  conv_small(X, Z, ACC, w_s, deg, cWr + 12288, cWl + 12288, cb + 192,
             7, g_esrc[1], g_edst[1], m1, g*7, ebase, 256, g, t, lane, w);
  conv_small(X, Z, ACC, w_s, deg, cWr + 16384, cWl + 16384, cb + 256,
             7, g_esrc[1], g_edst[1], m1, g*7, ebase, 320, g, t, lane, w);
}

// ============================================================================
// MLP head: h=[B,384] -> relu(h@W1+b1) -> @W2+b2 -> log_softmax
// ============================================================================
__global__ __launch_bounds__(64)
void head(const float* __restrict__ W1, const float* __restrict__ b1,
          const float* __restrict__ W2, const float* __restrict__ b2,
          float* __restrict__ out)
{
  __shared__ float h[384], o1[64], lg[2];
  const int g = blockIdx.x, t = threadIdx.x;
  for (int i = t; i < 384; i += 64) h[i] = g_xs[g*384 + i];
  __syncthreads();
  float acc = b1[t];
  for (int j = 0; j < 384; ++j) acc = fmaf(h[j], W1[j*64 + t], acc);
  o1[t] = fmaxf(acc, 0.f);
  __syncthreads();
  if (t < 2) {
    float a2 = b2[t];
    for (int f2 = 0; f2 < 64; ++f2) a2 = fmaf(o1[f2], W2[f2*2 + t], a2);
    lg[t] = a2;
  }
  __syncthreads();
  if (t < 2) {
    const float mx = fmaxf(lg[0], lg[1]);
    const float lse = mx + logf(expf(lg[0]-mx) + expf(lg[1]-mx));
    out[g*2 + t] = lg[t] - lse;
  }
}

// ============================================================================
extern "C" void kernel_launch(void* const* d_in, const int* in_sizes, int n_in,
                              void* d_out, int out_size, void* d_ws, size_t ws_size,
                              hipStream_t stream)
{
  (void)in_sizes; (void)n_in; (void)d_ws; (void)ws_size; (void)out_size;
  const float* x    = (const float*)d_in[0];
  const int*   ei   = (const int*)d_in[1];
  const float* c1Wr = (const float*)d_in[2];
  const float* c1Wl = (const float*)d_in[3];
  const float* c1b  = (const float*)d_in[4];
  const float* cWr  = (const float*)d_in[5];
  const float* cWl  = (const float*)d_in[6];
  const float* cb   = (const float*)d_in[7];
  const float* pWr  = (const float*)d_in[8];
  const float* pWl  = (const float*)d_in[9];
  const float* pb   = (const float*)d_in[10];
  const float* l1W  = (const float*)d_in[11];
  const float* l1b  = (const float*)d_in[12];
  const float* l2W  = (const float*)d_in[13];
  const float* l2b  = (const float*)d_in[14];
  float* out = (float*)d_out;
  const int* esrc = ei;
  const int* edst = ei + ETOT;

  // conv1 (160->64) + relu, xs[0]  (builds the shared CSR)
  mm_dual<160><<<NN0/64, 256, 0, stream>>>(x, -1, c1Wr, c1Wl, c1b, 0, 1);
  agg_full_build<<<NB, 1024, 0, stream>>>(0, 1, esrc, edst, 1, 0);
  // convs[0] + agg + pool0, fully fused (x2 never leaves LDS)
  conv_agg_pool<<<NB, 1024, 0, stream>>>(1, cWr, cWl, cb, esrc, edst,
                                         pWr, pWl, pb, 0, 64);
  // fused tail: convs[1..4] + pool1 + gmp's
  tail<<<NB, 512, 0, stream>>>(cWr, cWl, cb, pWr, pWl, pb);
  // head
  head<<<NB, 64, 0, stream>>>(l1W, l1b, l2W, l2b, out);
}

// Round 20
// 336.136 us; speedup vs baseline: 1.1216x; 1.0151x over previous
//
#include <hip/hip_runtime.h>
#include <math.h>

namespace {
constexpr int NB   = 256;          // graphs
constexpr int EPG  = 8192;         // edges per graph
constexpr int ETOT = NB * EPG;     // 2,097,152
constexpr int FH   = 64;           // hidden dim
constexpr int NN0  = NB * 512;     // 131072 nodes at full size
}

// ---- scratch (device globals: write-before-read each call, deterministic) ----
__device__ float g_feat[1][(size_t)NN0 * FH];   // pool0 output (57 rows/graph)
__device__ float g_xs[NB * 6 * FH];             // jumping-knowledge concat
__device__ int   g_esrc[2][ETOT];               // compacted edges (stage 0/1)
__device__ int   g_edst[2][ETOT];
__device__ int   g_ecnt[2][NB];

// ============================================================================
// front: EVERYTHING before the tail, one kernel per graph (1024 thr, ~156 KB).
//   phase 1: CSR build in LDS (hist+scan+scatter) — never persisted
//   phase 2: GEMM1 z1/xl1 = x@{c1Wr,c1Wl} (K=160): x chunk-staged into zlds
//            via global_load_lds; weights in zlds upper 16 KB (z not yet live)
//   phase 3: gather1 -> x1 = relu(agg/deg + xl1 + b) in regs -> zlds; gmp xs[0]
//   phase 4: GEMM2 z2/xl2 = x1@{cWr,cWl} (weights via wpf)
//   phase 5: gather2 -> x2 -> zlds; gmp xs[1]
//   phase 6: pool0 (dots, CSR score, bitonic top-57, xnew, edge compaction)
// LDS overlays (barrier-ordered): u2 = hist/start -> keys;
// csrbuf = csr -> newpos; wpf = scan -> W2 -> red -> zs/swl/sscore.
// z1/xl1/x1/x2 NEVER touch HBM.
// ============================================================================
__global__ __launch_bounds__(1024)
void front(const float* __restrict__ x,
           const int* __restrict__ esrc, const int* __restrict__ edst,
           const float* __restrict__ c1Wr, const float* __restrict__ c1Wl,
           const float* __restrict__ c1b,
           const float* __restrict__ cWr, const float* __restrict__ cWl,
           const float* __restrict__ cb,
           const float* __restrict__ pwr, const float* __restrict__ pwl,
           const float* __restrict__ pb)
{
  __shared__ float zlds[512 * 64];                        // 128 KB
  __shared__ unsigned short csrbuf[EPG];                  // 16 KB
  __shared__ __align__(16) unsigned long long u2[512];    // 4 KB
  __shared__ float wpf[2048];                             // 8 KB
  __shared__ int scnt;
  unsigned int* hist  = reinterpret_cast<unsigned int*>(u2);   // [0..512)
  unsigned int* start = hist + 512;                            // [512..1024)
  float* __restrict__ xnew = g_feat[0];
  const int g = blockIdx.x, t = threadIdx.x;
  const int gbase = g * 512, ebase = g * EPG;
  const int lane = t & 63, w = t >> 6;                    // 16 waves
  const int ndbase = w * 32;

  // ---- phase 1: CSR build ----
  if (t < 512) hist[t] = 0;
  if (t == 0) scnt = 0;
  __syncthreads();
  for (int e = t; e < EPG; e += 1024)
    atomicAdd(&hist[edst[ebase + e] - gbase], 1u);
  __syncthreads();
  {
    unsigned int* sA = reinterpret_cast<unsigned int*>(wpf);
    unsigned int* sB = sA + 512;
    if (t < 512) sA[t] = hist[t];
    __syncthreads();
    unsigned int *pa = sA, *pb = sB;
    for (int off = 1; off < 512; off <<= 1) {             // inclusive scan
      if (t < 512) {
        unsigned int v = pa[t];
        if (t >= off) v += pa[t - off];
        pb[t] = v;
      }
      __syncthreads();
      unsigned int* tmp = pa; pa = pb; pb = tmp;
    }
    if (t < 512) start[t] = pa[t] - hist[t];
    __syncthreads();
    unsigned int* cur = pb;                               // free half
    if (t < 512) cur[t] = start[t];
    __syncthreads();
    for (int e = t; e < EPG; e += 1024) {
      const int sl = esrc[ebase + e] - gbase;
      const int dl = edst[ebase + e] - gbase;
      const unsigned int pos = atomicAdd(&cur[dl], 1u);
      csrbuf[pos] = (unsigned short)sl;
    }
  }
  // ---- phase 2: GEMM1 (K=160, 5 chunks of 32) ----
  float zacc[32], xla[32];
  #pragma unroll
  for (int i = 0; i < 32; ++i) { zacc[i] = 0.f; xla[i] = 0.f; }
  constexpr int WRO = 16384;      // Wr chunk float-offset in zlds
  constexpr int WLO = 18432;      // Wl chunk
  #pragma unroll 1
  for (int c = 0; c < 5; ++c) {
    __syncthreads();              // prev chunk reads done / scatter done (c=0)
    #pragma unroll
    for (int i = 0; i < 4; ++i) { // x chunk: 512 rows x 32 k = 4096x16B
      const int slot = t + i * 1024;
      const int r = slot >> 3, q = slot & 7;
      const float* gp = &x[(size_t)(gbase + r) * 160 + c * 32 + q * 4];
      float* lp = zlds + (size_t)(i * 1024 + w * 64) * 4;
      __builtin_amdgcn_global_load_lds(
          (const __attribute__((address_space(1))) unsigned int*)gp,
          (__attribute__((address_space(3))) unsigned int*)lp, 16, 0, 0);
    }
    zlds[WRO + t]        = c1Wr[c * 2048 + t];
    zlds[WRO + 1024 + t] = c1Wr[c * 2048 + 1024 + t];
    zlds[WLO + t]        = c1Wl[c * 2048 + t];
    zlds[WLO + 1024 + t] = c1Wl[c * 2048 + 1024 + t];
    __syncthreads();
    #pragma unroll 1
    for (int k4 = 0; k4 < 8; ++k4) {
      const int kb = k4 * 4;
      const float wr0 = zlds[WRO + (kb+0)*64 + lane], wr1 = zlds[WRO + (kb+1)*64 + lane],
                  wr2 = zlds[WRO + (kb+2)*64 + lane], wr3 = zlds[WRO + (kb+3)*64 + lane];
      const float wl0 = zlds[WLO + (kb+0)*64 + lane], wl1 = zlds[WLO + (kb+1)*64 + lane],
                  wl2 = zlds[WLO + (kb+2)*64 + lane], wl3 = zlds[WLO + (kb+3)*64 + lane];
      #pragma unroll
      for (int i = 0; i < 32; ++i) {
        const float4 xv = *reinterpret_cast<const float4*>(
            &zlds[(ndbase + i) * 32 + kb]);
        float za = zacc[i], xa = xla[i];
        za = fmaf(xv.x, wr0, za); za = fmaf(xv.y, wr1, za);
        za = fmaf(xv.z, wr2, za); za = fmaf(xv.w, wr3, za);
        xa = fmaf(xv.x, wl0, xa); xa = fmaf(xv.y, wl1, xa);
        xa = fmaf(xv.z, wl2, xa); xa = fmaf(xv.w, wl3, xa);
        zacc[i] = za; xla[i] = xa;
      }
    }
  }
  __syncthreads();                // all x-chunk reads done
  #pragma unroll
  for (int i = 0; i < 32; ++i)
    zlds[(ndbase + i) * 64 + lane] = zacc[i];             // z1
  __syncthreads();
  // ---- phase 3: gather1 -> x1 ----
  {
    const float bv = c1b[lane];
    float psum = 0.f;
    #pragma unroll 1
    for (int i = 0; i < 32; ++i) {
      const int nd = ndbase + i;
      const unsigned int s = start[nd], d = hist[nd];
      float a0 = 0.f, a1 = 0.f, a2 = 0.f, a3 = 0.f;
      unsigned int j = 0;
      for (; j + 4 <= d; j += 4) {
        const int i0 = csrbuf[s+j], i1 = csrbuf[s+j+1],
                  i2 = csrbuf[s+j+2], i3 = csrbuf[s+j+3];
        a0 += zlds[i0*64 + lane]; a1 += zlds[i1*64 + lane];
        a2 += zlds[i2*64 + lane]; a3 += zlds[i3*64 + lane];
      }
      for (; j < d; ++j) a0 += zlds[csrbuf[s+j]*64 + lane];
      float v = ((a0 + a1) + (a2 + a3)) / (float)(d > 0 ? d : 1) + xla[i] + bv;
      v = fmaxf(v, 0.f);
      zacc[i] = v;
      psum += v;
    }
    __syncthreads();              // all z1 reads done
    #pragma unroll
    for (int i = 0; i < 32; ++i)
      zlds[(ndbase + i) * 64 + lane] = zacc[i];           // x1
    wpf[w * 64 + lane] = psum;    // red overlay (scan dead)
    __syncthreads();
    if (t < 64) {
      float s = 0.f;
      #pragma unroll
      for (int ww = 0; ww < 16; ++ww) s += wpf[ww*64 + t];
      g_xs[g*384 + 0 + t] = s * (1.f/512.f);
    }
  }
  // ---- phase 4: GEMM2 (K=64, 4 chunks of 16; weights via wpf) ----
  #pragma unroll
  for (int i = 0; i < 32; ++i) { zacc[i] = 0.f; xla[i] = 0.f; }
  {
    float* w_r = wpf;             // [0..1024)
    float* w_l = wpf + 1024;      // [1024..2048)
    #pragma unroll 1
    for (int c = 0; c < 4; ++c) {
      __syncthreads();            // c=0: red reads done; WAR on wpf
      w_r[t] = cWr[c * 1024 + t];
      w_l[t] = cWl[c * 1024 + t];
      __syncthreads();
      #pragma unroll 1
      for (int k4 = 0; k4 < 4; ++k4) {
        const int kb = k4 * 4;
        const float wr0 = w_r[(kb+0)*64 + lane], wr1 = w_r[(kb+1)*64 + lane],
                    wr2 = w_r[(kb+2)*64 + lane], wr3 = w_r[(kb+3)*64 + lane];
        const float wl0 = w_l[(kb+0)*64 + lane], wl1 = w_l[(kb+1)*64 + lane],
                    wl2 = w_l[(kb+2)*64 + lane], wl3 = w_l[(kb+3)*64 + lane];
        #pragma unroll
        for (int i = 0; i < 32; ++i) {
          const float4 xv = *reinterpret_cast<const float4*>(
              &zlds[(ndbase + i) * 64 + c * 16 + kb]);
          float za = zacc[i], xa = xla[i];
          za = fmaf(xv.x, wr0, za); za = fmaf(xv.y, wr1, za);
          za = fmaf(xv.z, wr2, za); za = fmaf(xv.w, wr3, za);
          xa = fmaf(xv.x, wl0, xa); xa = fmaf(xv.y, wl1, xa);
          xa = fmaf(xv.z, wl2, xa); xa = fmaf(xv.w, wl3, xa);
          zacc[i] = za; xla[i] = xa;
        }
      }
    }
  }
  __syncthreads();                // all x1 reads complete
  #pragma unroll
  for (int i = 0; i < 32; ++i)
    zlds[(ndbase + i) * 64 + lane] = zacc[i];             // z2
  __syncthreads();
  // ---- phase 5: gather2 -> x2 ----
  {
    const float bv = cb[lane];
    float psum = 0.f;
    #pragma unroll 1
    for (int i = 0; i < 32; ++i) {
      const int nd = ndbase + i;
      const unsigned int s = start[nd], d = hist[nd];
      float a0 = 0.f, a1 = 0.f, a2 = 0.f, a3 = 0.f;
      unsigned int j = 0;
      for (; j + 4 <= d; j += 4) {
        const int i0 = csrbuf[s+j], i1 = csrbuf[s+j+1],
                  i2 = csrbuf[s+j+2], i3 = csrbuf[s+j+3];
        a0 += zlds[i0*64 + lane]; a1 += zlds[i1*64 + lane];
        a2 += zlds[i2*64 + lane]; a3 += zlds[i3*64 + lane];
      }
      for (; j < d; ++j) a0 += zlds[csrbuf[s+j]*64 + lane];
      float v = ((a0 + a1) + (a2 + a3)) / (float)(d > 0 ? d : 1) + xla[i] + bv;
      v = fmaxf(v, 0.f);
      zacc[i] = v;
      psum += v;
    }
    __syncthreads();              // all z2 reads done
    #pragma unroll
    for (int i = 0; i < 32; ++i)
      zlds[(ndbase + i) * 64 + lane] = zacc[i];           // x2
    wpf[w * 64 + lane] = psum;    // red overlay (weights dead)
    __syncthreads();
    if (t < 64) {
      float s = 0.f;
      #pragma unroll
      for (int ww = 0; ww < 16; ++ww) s += wpf[ww*64 + t];
      g_xs[g*384 + 64 + t] = s * (1.f/512.f);
    }
    __syncthreads();              // red dead
  }
  // ---- phase 6: pool0 ----
  float* zs     = wpf;            // [0..512)
  float* swl    = wpf + 512;      // [512..1024)
  float* sscore = wpf + 1024;     // [1024..1536)
  const float pwrv = pwr[lane], pwlv = pwl[lane];
  for (int nd = w; nd < 512; nd += 16) {
    const float v = zlds[nd*64 + lane];
    float a = v * pwrv, b = v * pwlv;
    #pragma unroll
    for (int off = 32; off > 0; off >>= 1) {
      a += __shfl_xor(a, off);
      b += __shfl_xor(b, off);
    }
    if (lane == 0) { zs[nd] = a; swl[nd] = b; }
  }
  __syncthreads();
  if (t < 512) {
    const unsigned int s = start[t], d = hist[t];
    float a = 0.f;
    for (unsigned int j = 0; j < d; ++j) a += zs[csrbuf[s + j]];
    sscore[t] = a / fmaxf((float)d, 1.f) + pb[0] + swl[t];
  }
  __syncthreads();                // hist/start & csr dead
  unsigned long long* keys = u2;  // overlay
  if (t < 512) {
    unsigned int u = __float_as_uint(sscore[t]);
    u = (u & 0x80000000u) ? ~u : (u | 0x80000000u);
    keys[t] = ((unsigned long long)u << 32) | (unsigned int)(~(unsigned int)t);
  }
  __syncthreads();
  for (int kk = 2; kk <= 512; kk <<= 1) {
    for (int j = kk >> 1; j > 0; j >>= 1) {
      if (t < 512) {
        const int ixj = t ^ j;
        if (ixj > t) {
          const unsigned long long a = keys[t], bk = keys[ixj];
          const bool up = ((t & kk) == 0);
          if (up ? (a < bk) : (a > bk)) { keys[t] = bk; keys[ixj] = a; }
        }
      }
      __syncthreads();
    }
  }
  short* np = reinterpret_cast<short*>(csrbuf);           // overlay
  if (t < 512) np[t] = -1;
  __syncthreads();
  if (t < 57)
    np[(int)(~(unsigned int)(keys[t] & 0xffffffffull))] = (short)t;
  __syncthreads();
  for (int r = w; r < 57; r += 16) {
    const int old = (int)(~(unsigned int)(keys[r] & 0xffffffffull));
    const float sc = tanhf(sscore[old]);
    xnew[(size_t)(g*57 + r)*64 + lane] = zlds[old*64 + lane] * sc;
  }
  for (int e = t; e < EPG; e += 1024) {
    const int sl = esrc[ebase + e] - gbase;
    const int dl = edst[ebase + e] - gbase;
    const int ns = np[sl], nd2 = np[dl];
    if (ns >= 0 && nd2 >= 0) {
      const int slot = atomicAdd(&scnt, 1);
      g_esrc[0][ebase + slot] = g*57 + ns;
      g_edst[0][ebase + slot] = g*57 + nd2;
    }
  }
  __syncthreads();
  if (t == 0) g_ecnt[0][g] = scnt;
}

// ============================================================================
// Fused tail: per graph, everything after pool0 (convs[1..4], pool1, gmp's).
// ============================================================================
__device__ __forceinline__ void conv_small(
    float* X, float* Z, float* ACC, float* w_s, const float* deg,
    const float* Wr, const float* Wl, const float* bias,
    int n, const int* esrc, const int* edst, int m, int gb, int ebase,
    int xs_off, int g, int t, int lane, int w)
{
  for (int i = t; i < n*64; i += 512) { Z[i] = 0.f; ACC[i] = 0.f; }
  __syncthreads();
  for (int kc = 0; kc < 4; ++kc) {
    for (int i = t; i < 1024; i += 512) w_s[i] = Wr[kc*1024 + i];
    __syncthreads();
    for (int r = w; r < n; r += 8) {
      float zacc = 0.f;
      #pragma unroll
      for (int k = 0; k < 16; ++k)
        zacc = fmaf(X[r*64 + kc*16 + k], w_s[k*64 + lane], zacc);
      Z[r*64 + lane] += zacc;
    }
    __syncthreads();
  }
  for (int e = w; e < m; e += 8) {
    const int sl = esrc[ebase + e] - gb;
    const int dl = edst[ebase + e] - gb;
    atomicAdd(&ACC[dl*64 + lane], Z[sl*64 + lane]);
  }
  __syncthreads();
  for (int i = t; i < n*64; i += 512) {
    const int r = i >> 6, f = i & 63;
    Z[i] = ACC[i] / fmaxf(deg[r], 1.f) + bias[f];
  }
  __syncthreads();
  for (int kc = 0; kc < 4; ++kc) {
    for (int i = t; i < 1024; i += 512) w_s[i] = Wl[kc*1024 + i];
    __syncthreads();
    for (int r = w; r < n; r += 8) {
      float zacc = 0.f;
      #pragma unroll
      for (int k = 0; k < 16; ++k)
        zacc = fmaf(X[r*64 + kc*16 + k], w_s[k*64 + lane], zacc);
      Z[r*64 + lane] += zacc;
    }
    __syncthreads();
  }
  for (int i = t; i < n*64; i += 512) X[i] = fmaxf(Z[i], 0.f);
  __syncthreads();
  if (t < 64) {
    float s = 0.f;
    for (int r = 0; r < n; ++r) s += X[r*64 + t];
    g_xs[g*384 + xs_off + t] = s / (float)n;
  }
  __syncthreads();
}

__global__ __launch_bounds__(512)
void tail(const float* __restrict__ cWr, const float* __restrict__ cWl,
          const float* __restrict__ cb,
          const float* __restrict__ pWr, const float* __restrict__ pWl,
          const float* __restrict__ pb)
{
  __shared__ float X[57*64], Z[57*64], ACC[57*64];   // 42.75 KB
  __shared__ float w_s[16*64];                       // 4 KB
  __shared__ float deg[64];
  __shared__ float zs[64], swl[64], sagg[64], sscore[64];
  __shared__ unsigned long long keys[64];
  __shared__ short newpos[64];
  __shared__ int scnt;
  const int g = blockIdx.x, t = threadIdx.x;
  const int lane = t & 63, w = t >> 6;
  const int ebase = g * EPG;

  for (int i = t; i < 57*64; i += 512) X[i] = g_feat[0][(size_t)(g*57)*64 + i];
  const int m0 = g_ecnt[0][g];
  if (t < 64) deg[t] = 0.f;
  __syncthreads();
  for (int e = t; e < m0; e += 512)
    atomicAdd(&deg[g_edst[0][ebase + e] - g*57], 1.f);
  __syncthreads();

  conv_small(X, Z, ACC, w_s, deg, cWr + 4096,  cWl + 4096,  cb + 64,
             57, g_esrc[0], g_edst[0], m0, g*57, ebase, 128, g, t, lane, w);
  conv_small(X, Z, ACC, w_s, deg, cWr + 8192,  cWl + 8192,  cb + 128,
             57, g_esrc[0], g_edst[0], m0, g*57, ebase, 192, g, t, lane, w);

  // ---- pool1: 57 -> 7 ----
  {
    const float pwrv = pWr[64 + lane], pwlv = pWl[64 + lane];
    for (int r = w; r < 57; r += 8) {
      float a = X[r*64 + lane] * pwrv, b = X[r*64 + lane] * pwlv;
      #pragma unroll
      for (int off = 32; off > 0; off >>= 1) {
        a += __shfl_xor(a, off);
        b += __shfl_xor(b, off);
      }
      if (lane == 0) { zs[r] = a; swl[r] = b; }
    }
    if (t < 64) sagg[t] = 0.f;
    if (t == 0) scnt = 0;
    __syncthreads();
    for (int e = t; e < m0; e += 512)
      atomicAdd(&sagg[g_edst[0][ebase + e] - g*57],
                zs[g_esrc[0][ebase + e] - g*57]);
    __syncthreads();
    if (t < 57) sscore[t] = sagg[t] / fmaxf(deg[t], 1.f) + pb[1] + swl[t];
    __syncthreads();
    if (t < 64) {
      unsigned long long key = 0ull;
      if (t < 57) {
        unsigned int u = __float_as_uint(sscore[t]);
        u = (u & 0x80000000u) ? ~u : (u | 0x80000000u);
        key = ((unsigned long long)u << 32) | (unsigned int)(~(unsigned int)t);
      }
      keys[t] = key;
    }
    __syncthreads();
    for (int kk = 2; kk <= 64; kk <<= 1) {
      for (int j = kk >> 1; j > 0; j >>= 1) {
        if (t < 64) {
          const int ixj = t ^ j;
          if (ixj > t) {
            const unsigned long long a = keys[t], bk = keys[ixj];
            const bool up = ((t & kk) == 0);
            if (up ? (a < bk) : (a > bk)) { keys[t] = bk; keys[ixj] = a; }
          }
        }
        __syncthreads();
      }
    }
    if (t < 64) newpos[t] = -1;
    __syncthreads();
    if (t < 7)
      newpos[(int)(~(unsigned int)(keys[t] & 0xffffffffull))] = (short)t;
    __syncthreads();
    for (int r = w; r < 7; r += 8) {
      const int old = (int)(~(unsigned int)(keys[r] & 0xffffffffull));
      const float sc = tanhf(sscore[old]);
      Z[r*64 + lane] = X[old*64 + lane] * sc;
    }
    for (int e = t; e < m0; e += 512) {
      const int sl = g_esrc[0][ebase + e] - g*57;
      const int dl = g_edst[0][ebase + e] - g*57;
      const int ns = newpos[sl], nd2 = newpos[dl];
      if (ns >= 0 && nd2 >= 0) {
        const int slot = atomicAdd(&scnt, 1);
        g_esrc[1][ebase + slot] = g*7 + ns;
        g_edst[1][ebase + slot] = g*7 + nd2;
      }
    }
    __syncthreads();
    for (int i = t; i < 7*64; i += 512) X[i] = Z[i];
    if (t < 64) deg[t] = 0.f;
    __syncthreads();
  }
  const int m1 = scnt;
  for (int e = t; e < m1; e += 512)
    atomicAdd(&deg[g_edst[1][ebase + e] - g*7], 1.f);
  __syncthreads();

  conv_small(X, Z, ACC, w_s, deg, cWr + 12288, cWl + 12288, cb + 192,
             7, g_esrc[1], g_edst[1], m1, g*7, ebase, 256, g, t, lane, w);
  conv_small(X, Z, ACC, w_s, deg, cWr + 16384, cWl + 16384, cb + 256,
             7, g_esrc[1], g_edst[1], m1, g*7, ebase, 320, g, t, lane, w);
}

// ============================================================================
// MLP head: h=[B,384] -> relu(h@W1+b1) -> @W2+b2 -> log_softmax
// ============================================================================
__global__ __launch_bounds__(64)
void head(const float* __restrict__ W1, const float* __restrict__ b1,
          const float* __restrict__ W2, const float* __restrict__ b2,
          float* __restrict__ out)
{
  __shared__ float h[384], o1[64], lg[2];
  const int g = blockIdx.x, t = threadIdx.x;
  for (int i = t; i < 384; i += 64) h[i] = g_xs[g*384 + i];
  __syncthreads();
  float acc = b1[t];
  for (int j = 0; j < 384; ++j) acc = fmaf(h[j], W1[j*64 + t], acc);
  o1[t] = fmaxf(acc, 0.f);
  __syncthreads();
  if (t < 2) {
    float a2 = b2[t];
    for (int f2 = 0; f2 < 64; ++f2) a2 = fmaf(o1[f2], W2[f2*2 + t], a2);
    lg[t] = a2;
  }
  __syncthreads();
  if (t < 2) {
    const float mx = fmaxf(lg[0], lg[1]);
    const float lse = mx + logf(expf(lg[0]-mx) + expf(lg[1]-mx));
    out[g*2 + t] = lg[t] - lse;
  }
}

// ============================================================================
extern "C" void kernel_launch(void* const* d_in, const int* in_sizes, int n_in,
                              void* d_out, int out_size, void* d_ws, size_t ws_size,
                              hipStream_t stream)
{
  (void)in_sizes; (void)n_in; (void)d_ws; (void)ws_size; (void)out_size;
  const float* x    = (const float*)d_in[0];
  const int*   ei   = (const int*)d_in[1];
  const float* c1Wr = (const float*)d_in[2];
  const float* c1Wl = (const float*)d_in[3];
  const float* c1b  = (const float*)d_in[4];
  const float* cWr  = (const float*)d_in[5];
  const float* cWl  = (const float*)d_in[6];
  const float* cb   = (const float*)d_in[7];
  const float* pWr  = (const float*)d_in[8];
  const float* pWl  = (const float*)d_in[9];
  const float* pb   = (const float*)d_in[10];
  const float* l1W  = (const float*)d_in[11];
  const float* l1b  = (const float*)d_in[12];
  const float* l2W  = (const float*)d_in[13];
  const float* l2b  = (const float*)d_in[14];
  float* out = (float*)d_out;
  const int* esrc = ei;
  const int* edst = ei + ETOT;

  // conv1 + agg + conv0 + agg + pool0, fully fused per graph
  front<<<NB, 1024, 0, stream>>>(x, esrc, edst, c1Wr, c1Wl, c1b,
                                 cWr, cWl, cb, pWr, pWl, pb);
  // fused tail: convs[1..4] + pool1 + gmp's
  tail<<<NB, 512, 0, stream>>>(cWr, cWl, cb, pWr, pWl, pb);
  // head
  head<<<NB, 64, 0, stream>>>(l1W, l1b, l2W, l2b, out);
}

// Round 21
// 334.183 us; speedup vs baseline: 1.1281x; 1.0058x over previous
//
#include <hip/hip_runtime.h>
#include <math.h>

namespace {
constexpr int NB   = 256;          // graphs
constexpr int EPG  = 8192;         // edges per graph
constexpr int ETOT = NB * EPG;     // 2,097,152
constexpr int FH   = 64;           // hidden dim
constexpr int NN0  = NB * 512;     // 131072 nodes at full size
}

// ---- scratch (device globals: write-before-read each call, deterministic) ----
__device__ float g_feat[1][(size_t)NN0 * FH];   // pool0 output (57 rows/graph)
__device__ float g_xs[NB * 6 * FH];             // jumping-knowledge concat
__device__ int   g_esrc[2][ETOT];               // compacted edges (stage 0/1)
__device__ int   g_edst[2][ETOT];
__device__ int   g_ecnt[2][NB];

// ============================================================================
// front: EVERYTHING before the tail, one kernel per graph (1024 thr, ~156 KB).
//   phase 1: CSR build in LDS — chunk-0 x loads issued early, hidden under it
//   phase 2: GEMM1 (K=160, 10 chunks of 16) DOUBLE-BUFFERED in zlds
//            (z in regs during GEMM1, so zlds is free: x bufs @0/8192,
//             weight bufs @16384..24575; 2-phase schedule, T3 recipe)
//   phase 3: gather1 -> x1 = relu(agg/deg + xl1 + b) -> zlds; gmp xs[0]
//   phase 4: GEMM2 z2/xl2 = x1@{cWr,cWl} (weights via wpf)
//   phase 5: gather2 -> x2 -> zlds; gmp xs[1]
//   phase 6: pool0 (dots, CSR score, bitonic top-57, xnew, edge compaction)
// Overlays: u2 = hist/start -> keys; csrbuf = csr -> newpos;
// wpf = scan -> W2 -> red -> zs/swl/sscore. z1/xl1/x1/x2 never touch HBM.
// ============================================================================
__global__ __launch_bounds__(1024)
void front(const float* __restrict__ x,
           const int* __restrict__ esrc, const int* __restrict__ edst,
           const float* __restrict__ c1Wr, const float* __restrict__ c1Wl,
           const float* __restrict__ c1b,
           const float* __restrict__ cWr, const float* __restrict__ cWl,
           const float* __restrict__ cb,
           const float* __restrict__ pwr, const float* __restrict__ pwl,
           const float* __restrict__ pb)
{
  __shared__ float zlds[512 * 64];                        // 128 KB
  __shared__ unsigned short csrbuf[EPG];                  // 16 KB
  __shared__ __align__(16) unsigned long long u2[512];    // 4 KB
  __shared__ float wpf[2048];                             // 8 KB
  __shared__ int scnt;
  unsigned int* hist  = reinterpret_cast<unsigned int*>(u2);   // [0..512)
  unsigned int* start = hist + 512;                            // [512..1024)
  float* __restrict__ xnew = g_feat[0];
  const int g = blockIdx.x, t = threadIdx.x;
  const int gbase = g * 512, ebase = g * EPG;
  const int lane = t & 63, w = t >> 6;                    // 16 waves
  const int ndbase = w * 32;

  // GEMM1 double-buffer float offsets inside zlds
  auto stage_chunk = [&](int c, int p) {
    const int xb  = p ? 8192  : 0;
    const int wrO = p ? 18432 : 16384;
    const int wlO = p ? 22528 : 20480;
    #pragma unroll
    for (int i = 0; i < 2; ++i) {            // x: 512 rows x 16 k = 2048x16B
      const int slot = t + i * 1024;
      const int r = slot >> 2, q = slot & 3;
      const float* gp = &x[(size_t)(gbase + r) * 160 + c * 16 + q * 4];
      float* lp = zlds + xb + (size_t)(i * 1024 + w * 64) * 4;
      __builtin_amdgcn_global_load_lds(
          (const __attribute__((address_space(1))) unsigned int*)gp,
          (__attribute__((address_space(3))) unsigned int*)lp, 16, 0, 0);
    }
    {
      const float* gp = &c1Wr[c * 1024 + t];
      float* lp = zlds + wrO + (size_t)(w * 64);
      __builtin_amdgcn_global_load_lds(
          (const __attribute__((address_space(1))) unsigned int*)gp,
          (__attribute__((address_space(3))) unsigned int*)lp, 4, 0, 0);
    }
    {
      const float* gp = &c1Wl[c * 1024 + t];
      float* lp = zlds + wlO + (size_t)(w * 64);
      __builtin_amdgcn_global_load_lds(
          (const __attribute__((address_space(1))) unsigned int*)gp,
          (__attribute__((address_space(3))) unsigned int*)lp, 4, 0, 0);
    }
  };

  // ---- phase 1: CSR build (chunk-0 x loads in flight underneath) ----
  if (t < 512) hist[t] = 0;
  if (t == 0) scnt = 0;
  __syncthreads();
  stage_chunk(0, 0);                                      // hide under CSR build
  for (int e = t; e < EPG; e += 1024)
    atomicAdd(&hist[edst[ebase + e] - gbase], 1u);
  __syncthreads();
  {
    unsigned int* sA = reinterpret_cast<unsigned int*>(wpf);
    unsigned int* sB = sA + 512;
    if (t < 512) sA[t] = hist[t];
    __syncthreads();
    unsigned int *pa = sA, *pb = sB;
    for (int off = 1; off < 512; off <<= 1) {             // inclusive scan
      if (t < 512) {
        unsigned int v = pa[t];
        if (t >= off) v += pa[t - off];
        pb[t] = v;
      }
      __syncthreads();
      unsigned int* tmp = pa; pa = pb; pb = tmp;
    }
    if (t < 512) start[t] = pa[t] - hist[t];
    __syncthreads();
    unsigned int* cur = pb;                               // free half
    if (t < 512) cur[t] = start[t];
    __syncthreads();
    for (int e = t; e < EPG; e += 1024) {
      const int sl = esrc[ebase + e] - gbase;
      const int dl = edst[ebase + e] - gbase;
      const unsigned int pos = atomicAdd(&cur[dl], 1u);
      csrbuf[pos] = (unsigned short)sl;
    }
  }
  __syncthreads();                                        // CSR done; chunk0 ready
  // ---- phase 2: GEMM1, 2-phase pipelined ----
  float zacc[32], xla[32];
  #pragma unroll
  for (int i = 0; i < 32; ++i) { zacc[i] = 0.f; xla[i] = 0.f; }
  #pragma unroll 1
  for (int c = 0; c < 10; ++c) {
    if (c < 9) stage_chunk(c + 1, (c + 1) & 1);           // issue next chunk
    const int p   = c & 1;
    const int xb  = p ? 8192  : 0;
    const int wrO = p ? 18432 : 16384;
    const int wlO = p ? 22528 : 20480;
    #pragma unroll 1
    for (int k4 = 0; k4 < 4; ++k4) {
      const int kb = k4 * 4;
      const float wr0 = zlds[wrO + (kb+0)*64 + lane], wr1 = zlds[wrO + (kb+1)*64 + lane],
                  wr2 = zlds[wrO + (kb+2)*64 + lane], wr3 = zlds[wrO + (kb+3)*64 + lane];
      const float wl0 = zlds[wlO + (kb+0)*64 + lane], wl1 = zlds[wlO + (kb+1)*64 + lane],
                  wl2 = zlds[wlO + (kb+2)*64 + lane], wl3 = zlds[wlO + (kb+3)*64 + lane];
      #pragma unroll
      for (int i = 0; i < 32; ++i) {
        const float4 xv = *reinterpret_cast<const float4*>(
            &zlds[xb + (ndbase + i) * 16 + kb]);
        float za = zacc[i], xa = xla[i];
        za = fmaf(xv.x, wr0, za); za = fmaf(xv.y, wr1, za);
        za = fmaf(xv.z, wr2, za); za = fmaf(xv.w, wr3, za);
        xa = fmaf(xv.x, wl0, xa); xa = fmaf(xv.y, wl1, xa);
        xa = fmaf(xv.z, wl2, xa); xa = fmaf(xv.w, wl3, xa);
        zacc[i] = za; xla[i] = xa;
      }
    }
    __syncthreads();              // drains vmcnt: next chunk resident; WAR safe
  }
  #pragma unroll
  for (int i = 0; i < 32; ++i)
    zlds[(ndbase + i) * 64 + lane] = zacc[i];             // z1
  __syncthreads();
  // ---- phase 3: gather1 -> x1 ----
  {
    const float bv = c1b[lane];
    float psum = 0.f;
    #pragma unroll 1
    for (int i = 0; i < 32; ++i) {
      const int nd = ndbase + i;
      const unsigned int s = start[nd], d = hist[nd];
      float a0 = 0.f, a1 = 0.f, a2 = 0.f, a3 = 0.f;
      unsigned int j = 0;
      for (; j + 4 <= d; j += 4) {
        const int i0 = csrbuf[s+j], i1 = csrbuf[s+j+1],
                  i2 = csrbuf[s+j+2], i3 = csrbuf[s+j+3];
        a0 += zlds[i0*64 + lane]; a1 += zlds[i1*64 + lane];
        a2 += zlds[i2*64 + lane]; a3 += zlds[i3*64 + lane];
      }
      for (; j < d; ++j) a0 += zlds[csrbuf[s+j]*64 + lane];
      float v = ((a0 + a1) + (a2 + a3)) / (float)(d > 0 ? d : 1) + xla[i] + bv;
      v = fmaxf(v, 0.f);
      zacc[i] = v;
      psum += v;
    }
    __syncthreads();              // all z1 reads done
    #pragma unroll
    for (int i = 0; i < 32; ++i)
      zlds[(ndbase + i) * 64 + lane] = zacc[i];           // x1
    wpf[w * 64 + lane] = psum;    // red overlay (scan dead)
    __syncthreads();
    if (t < 64) {
      float s = 0.f;
      #pragma unroll
      for (int ww = 0; ww < 16; ++ww) s += wpf[ww*64 + t];
      g_xs[g*384 + 0 + t] = s * (1.f/512.f);
    }
  }
  // ---- phase 4: GEMM2 (K=64, 4 chunks of 16; weights via wpf) ----
  #pragma unroll
  for (int i = 0; i < 32; ++i) { zacc[i] = 0.f; xla[i] = 0.f; }
  {
    float* w_r = wpf;             // [0..1024)
    float* w_l = wpf + 1024;      // [1024..2048)
    #pragma unroll 1
    for (int c = 0; c < 4; ++c) {
      __syncthreads();            // c=0: red reads done; WAR on wpf
      w_r[t] = cWr[c * 1024 + t];
      w_l[t] = cWl[c * 1024 + t];
      __syncthreads();
      #pragma unroll 1
      for (int k4 = 0; k4 < 4; ++k4) {
        const int kb = k4 * 4;
        const float wr0 = w_r[(kb+0)*64 + lane], wr1 = w_r[(kb+1)*64 + lane],
                    wr2 = w_r[(kb+2)*64 + lane], wr3 = w_r[(kb+3)*64 + lane];
        const float wl0 = w_l[(kb+0)*64 + lane], wl1 = w_l[(kb+1)*64 + lane],
                    wl2 = w_l[(kb+2)*64 + lane], wl3 = w_l[(kb+3)*64 + lane];
        #pragma unroll
        for (int i = 0; i < 32; ++i) {
          const float4 xv = *reinterpret_cast<const float4*>(
              &zlds[(ndbase + i) * 64 + c * 16 + kb]);
          float za = zacc[i], xa = xla[i];
          za = fmaf(xv.x, wr0, za); za = fmaf(xv.y, wr1, za);
          za = fmaf(xv.z, wr2, za); za = fmaf(xv.w, wr3, za);
          xa = fmaf(xv.x, wl0, xa); xa = fmaf(xv.y, wl1, xa);
          xa = fmaf(xv.z, wl2, xa); xa = fmaf(xv.w, wl3, xa);
          zacc[i] = za; xla[i] = xa;
        }
      }
    }
  }
  __syncthreads();                // all x1 reads complete
  #pragma unroll
  for (int i = 0; i < 32; ++i)
    zlds[(ndbase + i) * 64 + lane] = zacc[i];             // z2
  __syncthreads();
  // ---- phase 5: gather2 -> x2 ----
  {
    const float bv = cb[lane];
    float psum = 0.f;
    #pragma unroll 1
    for (int i = 0; i < 32; ++i) {
      const int nd = ndbase + i;
      const unsigned int s = start[nd], d = hist[nd];
      float a0 = 0.f, a1 = 0.f, a2 = 0.f, a3 = 0.f;
      unsigned int j = 0;
      for (; j + 4 <= d; j += 4) {
        const int i0 = csrbuf[s+j], i1 = csrbuf[s+j+1],
                  i2 = csrbuf[s+j+2], i3 = csrbuf[s+j+3];
        a0 += zlds[i0*64 + lane]; a1 += zlds[i1*64 + lane];
        a2 += zlds[i2*64 + lane]; a3 += zlds[i3*64 + lane];
      }
      for (; j < d; ++j) a0 += zlds[csrbuf[s+j]*64 + lane];
      float v = ((a0 + a1) + (a2 + a3)) / (float)(d > 0 ? d : 1) + xla[i] + bv;
      v = fmaxf(v, 0.f);
      zacc[i] = v;
      psum += v;
    }
    __syncthreads();              // all z2 reads done
    #pragma unroll
    for (int i = 0; i < 32; ++i)
      zlds[(ndbase + i) * 64 + lane] = zacc[i];           // x2
    wpf[w * 64 + lane] = psum;    // red overlay (weights dead)
    __syncthreads();
    if (t < 64) {
      float s = 0.f;
      #pragma unroll
      for (int ww = 0; ww < 16; ++ww) s += wpf[ww*64 + t];
      g_xs[g*384 + 64 + t] = s * (1.f/512.f);
    }
    __syncthreads();              // red dead
  }
  // ---- phase 6: pool0 ----
  float* zs     = wpf;            // [0..512)
  float* swl    = wpf + 512;      // [512..1024)
  float* sscore = wpf + 1024;     // [1024..1536)
  const float pwrv = pwr[lane], pwlv = pwl[lane];
  for (int nd = w; nd < 512; nd += 16) {
    const float v = zlds[nd*64 + lane];
    float a = v * pwrv, b = v * pwlv;
    #pragma unroll
    for (int off = 32; off > 0; off >>= 1) {
      a += __shfl_xor(a, off);
      b += __shfl_xor(b, off);
    }
    if (lane == 0) { zs[nd] = a; swl[nd] = b; }
  }
  __syncthreads();
  if (t < 512) {
    const unsigned int s = start[t], d = hist[t];
    float a = 0.f;
    for (unsigned int j = 0; j < d; ++j) a += zs[csrbuf[s + j]];
    sscore[t] = a / fmaxf((float)d, 1.f) + pb[0] + swl[t];
  }
  __syncthreads();                // hist/start & csr dead
  unsigned long long* keys = u2;  // overlay
  if (t < 512) {
    unsigned int u = __float_as_uint(sscore[t]);
    u = (u & 0x80000000u) ? ~u : (u | 0x80000000u);
    keys[t] = ((unsigned long long)u << 32) | (unsigned int)(~(unsigned int)t);
  }
  __syncthreads();
  for (int kk = 2; kk <= 512; kk <<= 1) {
    for (int j = kk >> 1; j > 0; j >>= 1) {
      if (t < 512) {
        const int ixj = t ^ j;
        if (ixj > t) {
          const unsigned long long a = keys[t], bk = keys[ixj];
          const bool up = ((t & kk) == 0);
          if (up ? (a < bk) : (a > bk)) { keys[t] = bk; keys[ixj] = a; }
        }
      }
      __syncthreads();
    }
  }
  short* np = reinterpret_cast<short*>(csrbuf);           // overlay
  if (t < 512) np[t] = -1;
  __syncthreads();
  if (t < 57)
    np[(int)(~(unsigned int)(keys[t] & 0xffffffffull))] = (short)t;
  __syncthreads();
  for (int r = w; r < 57; r += 16) {
    const int old = (int)(~(unsigned int)(keys[r] & 0xffffffffull));
    const float sc = tanhf(sscore[old]);
    xnew[(size_t)(g*57 + r)*64 + lane] = zlds[old*64 + lane] * sc;
  }
  for (int e = t; e < EPG; e += 1024) {
    const int sl = esrc[ebase + e] - gbase;
    const int dl = edst[ebase + e] - gbase;
    const int ns = np[sl], nd2 = np[dl];
    if (ns >= 0 && nd2 >= 0) {
      const int slot = atomicAdd(&scnt, 1);
      g_esrc[0][ebase + slot] = g*57 + ns;
      g_edst[0][ebase + slot] = g*57 + nd2;
    }
  }
  __syncthreads();
  if (t == 0) g_ecnt[0][g] = scnt;
}

// ============================================================================
// Fused tail: per graph, everything after pool0 (convs[1..4], pool1, gmp's).
// ============================================================================
__device__ __forceinline__ void conv_small(
    float* X, float* Z, float* ACC, float* w_s, const float* deg,
    const float* Wr, const float* Wl, const float* bias,
    int n, const int* esrc, const int* edst, int m, int gb, int ebase,
    int xs_off, int g, int t, int lane, int w)
{
  for (int i = t; i < n*64; i += 512) { Z[i] = 0.f; ACC[i] = 0.f; }
  __syncthreads();
  for (int kc = 0; kc < 4; ++kc) {
    for (int i = t; i < 1024; i += 512) w_s[i] = Wr[kc*1024 + i];
    __syncthreads();
    for (int r = w; r < n; r += 8) {
      float zacc = 0.f;
      #pragma unroll
      for (int k = 0; k < 16; ++k)
        zacc = fmaf(X[r*64 + kc*16 + k], w_s[k*64 + lane], zacc);
      Z[r*64 + lane] += zacc;
    }
    __syncthreads();
  }
  for (int e = w; e < m; e += 8) {
    const int sl = esrc[ebase + e] - gb;
    const int dl = edst[ebase + e] - gb;
    atomicAdd(&ACC[dl*64 + lane], Z[sl*64 + lane]);
  }
  __syncthreads();
  for (int i = t; i < n*64; i += 512) {
    const int r = i >> 6, f = i & 63;
    Z[i] = ACC[i] / fmaxf(deg[r], 1.f) + bias[f];
  }
  __syncthreads();
  for (int kc = 0; kc < 4; ++kc) {
    for (int i = t; i < 1024; i += 512) w_s[i] = Wl[kc*1024 + i];
    __syncthreads();
    for (int r = w; r < n; r += 8) {
      float zacc = 0.f;
      #pragma unroll
      for (int k = 0; k < 16; ++k)
        zacc = fmaf(X[r*64 + kc*16 + k], w_s[k*64 + lane], zacc);
      Z[r*64 + lane] += zacc;
    }
    __syncthreads();
  }
  for (int i = t; i < n*64; i += 512) X[i] = fmaxf(Z[i], 0.f);
  __syncthreads();
  if (t < 64) {
    float s = 0.f;
    for (int r = 0; r < n; ++r) s += X[r*64 + t];
    g_xs[g*384 + xs_off + t] = s / (float)n;
  }
  __syncthreads();
}

__global__ __launch_bounds__(512)
void tail(const float* __restrict__ cWr, const float* __restrict__ cWl,
          const float* __restrict__ cb,
          const float* __restrict__ pWr, const float* __restrict__ pWl,
          const float* __restrict__ pb)
{
  __shared__ float X[57*64], Z[57*64], ACC[57*64];   // 42.75 KB
  __shared__ float w_s[16*64];                       // 4 KB
  __shared__ float deg[64];
  __shared__ float zs[64], swl[64], sagg[64], sscore[64];
  __shared__ unsigned long long keys[64];
  __shared__ short newpos[64];
  __shared__ int scnt;
  const int g = blockIdx.x, t = threadIdx.x;
  const int lane = t & 63, w = t >> 6;
  const int ebase = g * EPG;

  for (int i = t; i < 57*64; i += 512) X[i] = g_feat[0][(size_t)(g*57)*64 + i];
  const int m0 = g_ecnt[0][g];
  if (t < 64) deg[t] = 0.f;
  __syncthreads();
  for (int e = t; e < m0; e += 512)
    atomicAdd(&deg[g_edst[0][ebase + e] - g*57], 1.f);
  __syncthreads();

  conv_small(X, Z, ACC, w_s, deg, cWr + 4096,  cWl + 4096,  cb + 64,
             57, g_esrc[0], g_edst[0], m0, g*57, ebase, 128, g, t, lane, w);
  conv_small(X, Z, ACC, w_s, deg, cWr + 8192,  cWl + 8192,  cb + 128,
             57, g_esrc[0], g_edst[0], m0, g*57, ebase, 192, g, t, lane, w);

  // ---- pool1: 57 -> 7 ----
  {
    const float pwrv = pWr[64 + lane], pwlv = pWl[64 + lane];
    for (int r = w; r < 57; r += 8) {
      float a = X[r*64 + lane] * pwrv, b = X[r*64 + lane] * pwlv;
      #pragma unroll
      for (int off = 32; off > 0; off >>= 1) {
        a += __shfl_xor(a, off);
        b += __shfl_xor(b, off);
      }
      if (lane == 0) { zs[r] = a; swl[r] = b; }
    }
    if (t < 64) sagg[t] = 0.f;
    if (t == 0) scnt = 0;
    __syncthreads();
    for (int e = t; e < m0; e += 512)
      atomicAdd(&sagg[g_edst[0][ebase + e] - g*57],
                zs[g_esrc[0][ebase + e] - g*57]);
    __syncthreads();
    if (t < 57) sscore[t] = sagg[t] / fmaxf(deg[t], 1.f) + pb[1] + swl[t];
    __syncthreads();
    if (t < 64) {
      unsigned long long key = 0ull;
      if (t < 57) {
        unsigned int u = __float_as_uint(sscore[t]);
        u = (u & 0x80000000u) ? ~u : (u | 0x80000000u);
        key = ((unsigned long long)u << 32) | (unsigned int)(~(unsigned int)t);
      }
      keys[t] = key;
    }
    __syncthreads();
    for (int kk = 2; kk <= 64; kk <<= 1) {
      for (int j = kk >> 1; j > 0; j >>= 1) {
        if (t < 64) {
          const int ixj = t ^ j;
          if (ixj > t) {
            const unsigned long long a = keys[t], bk = keys[ixj];
            const bool up = ((t & kk) == 0);
            if (up ? (a < bk) : (a > bk)) { keys[t] = bk; keys[ixj] = a; }
          }
        }
        __syncthreads();
      }
    }
    if (t < 64) newpos[t] = -1;
    __syncthreads();
    if (t < 7)
      newpos[(int)(~(unsigned int)(keys[t] & 0xffffffffull))] = (short)t;
    __syncthreads();
    for (int r = w; r < 7; r += 8) {
      const int old = (int)(~(unsigned int)(keys[r] & 0xffffffffull));
      const float sc = tanhf(sscore[old]);
      Z[r*64 + lane] = X[old*64 + lane] * sc;
    }
    for (int e = t; e < m0; e += 512) {
      const int sl = g_esrc[0][ebase + e] - g*57;
      const int dl = g_edst[0][ebase + e] - g*57;
      const int ns = newpos[sl], nd2 = newpos[dl];
      if (ns >= 0 && nd2 >= 0) {
        const int slot = atomicAdd(&scnt, 1);
        g_esrc[1][ebase + slot] = g*7 + ns;
        g_edst[1][ebase + slot] = g*7 + nd2;
      }
    }
    __syncthreads();
    for (int i = t; i < 7*64; i += 512) X[i] = Z[i];
    if (t < 64) deg[t] = 0.f;
    __syncthreads();
  }
  const int m1 = scnt;
  for (int e = t; e < m1; e += 512)
    atomicAdd(&deg[g_edst[1][ebase + e] - g*7], 1.f);
  __syncthreads();

  conv_small(X, Z, ACC, w_s, deg, cWr + 12288, cWl + 12288, cb + 192,
             7, g_esrc[1], g_edst[1], m1, g*7, ebase, 256, g, t, lane, w);
  conv_small(X, Z, ACC, w_s, deg, cWr + 16384, cWl + 16384, cb + 256,
             7, g_esrc[1], g_edst[1], m1, g*7, ebase, 320, g, t, lane, w);
}

// ============================================================================
// MLP head: h=[B,384] -> relu(h@W1+b1) -> @W2+b2 -> log_softmax
// ============================================================================
__global__ __launch_bounds__(64)
void head(const float* __restrict__ W1, const float* __restrict__ b1,
          const float* __restrict__ W2, const float* __restrict__ b2,
          float* __restrict__ out)
{
  __shared__ float h[384], o1[64], lg[2];
  const int g = blockIdx.x, t = threadIdx.x;
  for (int i = t; i < 384; i += 64) h[i] = g_xs[g*384 + i];
  __syncthreads();
  float acc = b1[t];
  for (int j = 0; j < 384; ++j) acc = fmaf(h[j], W1[j*64 + t], acc);
  o1[t] = fmaxf(acc, 0.f);
  __syncthreads();
  if (t < 2) {
    float a2 = b2[t];
    for (int f2 = 0; f2 < 64; ++f2) a2 = fmaf(o1[f2], W2[f2*2 + t], a2);
    lg[t] = a2;
  }
  __syncthreads();
  if (t < 2) {
    const float mx = fmaxf(lg[0], lg[1]);
    const float lse = mx + logf(expf(lg[0]-mx) + expf(lg[1]-mx));
    out[g*2 + t] = lg[t] - lse;
  }
}

// ============================================================================
extern "C" void kernel_launch(void* const* d_in, const int* in_sizes, int n_in,
                              void* d_out, int out_size, void* d_ws, size_t ws_size,
                              hipStream_t stream)
{
  (void)in_sizes; (void)n_in; (void)d_ws; (void)ws_size; (void)out_size;
  const float* x    = (const float*)d_in[0];
  const int*   ei   = (const int*)d_in[1];
  const float* c1Wr = (const float*)d_in[2];
  const float* c1Wl = (const float*)d_in[3];
  const float* c1b  = (const float*)d_in[4];
  const float* cWr  = (const float*)d_in[5];
  const float* cWl  = (const float*)d_in[6];
  const float* cb   = (const float*)d_in[7];
  const float* pWr  = (const float*)d_in[8];
  const float* pWl  = (const float*)d_in[9];
  const float* pb   = (const float*)d_in[10];
  const float* l1W  = (const float*)d_in[11];
  const float* l1b  = (const float*)d_in[12];
  const float* l2W  = (const float*)d_in[13];
  const float* l2b  = (const float*)d_in[14];
  float* out = (float*)d_out;
  const int* esrc = ei;
  const int* edst = ei + ETOT;

  // conv1 + agg + conv0 + agg + pool0, fully fused per graph
  front<<<NB, 1024, 0, stream>>>(x, esrc, edst, c1Wr, c1Wl, c1b,
                                 cWr, cWl, cb, pWr, pWl, pb);
  // fused tail: convs[1..4] + pool1 + gmp's
  tail<<<NB, 512, 0, stream>>>(cWr, cWl, cb, pWr, pWl, pb);
  // head
  head<<<NB, 64, 0, stream>>>(l1W, l1b, l2W, l2b, out);
}

// Round 22
// 320.409 us; speedup vs baseline: 1.1766x; 1.0430x over previous
//
#include <hip/hip_runtime.h>
#include <math.h>

namespace {
constexpr int NB   = 256;          // graphs
constexpr int EPG  = 8192;         // edges per graph
constexpr int ETOT = NB * EPG;     // 2,097,152
}

// ============================================================================
// mono: the ENTIRE network, one block per graph (1024 thr, ~157.5 KB LDS).
//   ph1: CSR build in LDS (chunk-0 x loads in flight underneath)
//   ph2: GEMM1 (K=160, 10 chunks, double-buffered in zlds)
//   ph3: gather1 -> x1 -> zlds; gmp xs[0]
//   ph4: GEMM2 (weights via wpf)
//   ph5: gather2 -> x2 -> zlds; gmp xs[1]
//   ph6: pool0 (dots, score, bitonic top-57, X57 in place, edges -> LDS)
//   ph7: convs[1],[2] (n=57, LDS edges); pool1 (57->7); convs[3],[4] (n=7)
//   ph8: head (lin1+relu+lin2+log_softmax) -> out
// ONLY global write: out[g*2..g*2+2). No device-global scratch at all.
// Overlays: u2 = hist/start -> keys; csrbuf = csr -> newpos;
// wpf = scan -> W2 -> red -> zs/swl/sscore -> deg/w_s/pool1/head.
// ============================================================================
__global__ __launch_bounds__(1024)
void mono(const float* __restrict__ x,
          const int* __restrict__ esrc, const int* __restrict__ edst,
          const float* __restrict__ c1Wr, const float* __restrict__ c1Wl,
          const float* __restrict__ c1b,
          const float* __restrict__ cWr, const float* __restrict__ cWl,
          const float* __restrict__ cb,
          const float* __restrict__ pwr, const float* __restrict__ pwl,
          const float* __restrict__ pb,
          const float* __restrict__ l1W, const float* __restrict__ l1b,
          const float* __restrict__ l2W, const float* __restrict__ l2b,
          float* __restrict__ out)
{
  __shared__ float zlds[512 * 64];                        // 128 KB
  __shared__ unsigned short csrbuf[EPG];                  // 16 KB
  __shared__ __align__(16) unsigned long long u2[512];    // 4 KB
  __shared__ float wpf[2048];                             // 8 KB
  __shared__ float xsl[384];                              // 1.5 KB (JK concat)
  __shared__ int scnt;
  unsigned int* hist  = reinterpret_cast<unsigned int*>(u2);   // [0..512)
  unsigned int* start = hist + 512;                            // [512..1024)
  const int g = blockIdx.x, t = threadIdx.x;
  const int gbase = g * 512, ebase = g * EPG;
  const int lane = t & 63, w = t >> 6;                    // 16 waves
  const int ndbase = w * 32;

  auto stage_chunk = [&](int c, int p) {
    const int xb  = p ? 8192  : 0;
    const int wrO = p ? 18432 : 16384;
    const int wlO = p ? 22528 : 20480;
    #pragma unroll
    for (int i = 0; i < 2; ++i) {            // x: 512 rows x 16 k = 2048x16B
      const int slot = t + i * 1024;
      const int r = slot >> 2, q = slot & 3;
      const float* gp = &x[(size_t)(gbase + r) * 160 + c * 16 + q * 4];
      float* lp = zlds + xb + (size_t)(i * 1024 + w * 64) * 4;
      __builtin_amdgcn_global_load_lds(
          (const __attribute__((address_space(1))) unsigned int*)gp,
          (__attribute__((address_space(3))) unsigned int*)lp, 16, 0, 0);
    }
    {
      const float* gp = &c1Wr[c * 1024 + t];
      float* lp = zlds + wrO + (size_t)(w * 64);
      __builtin_amdgcn_global_load_lds(
          (const __attribute__((address_space(1))) unsigned int*)gp,
          (__attribute__((address_space(3))) unsigned int*)lp, 4, 0, 0);
    }
    {
      const float* gp = &c1Wl[c * 1024 + t];
      float* lp = zlds + wlO + (size_t)(w * 64);
      __builtin_amdgcn_global_load_lds(
          (const __attribute__((address_space(1))) unsigned int*)gp,
          (__attribute__((address_space(3))) unsigned int*)lp, 4, 0, 0);
    }
  };

  // ---- ph1: CSR build ----
  if (t < 512) hist[t] = 0;
  if (t == 0) scnt = 0;
  __syncthreads();
  stage_chunk(0, 0);
  for (int e = t; e < EPG; e += 1024)
    atomicAdd(&hist[edst[ebase + e] - gbase], 1u);
  __syncthreads();
  {
    unsigned int* sA = reinterpret_cast<unsigned int*>(wpf);
    unsigned int* sB = sA + 512;
    if (t < 512) sA[t] = hist[t];
    __syncthreads();
    unsigned int *pa = sA, *pb = sB;
    for (int off = 1; off < 512; off <<= 1) {
      if (t < 512) {
        unsigned int v = pa[t];
        if (t >= off) v += pa[t - off];
        pb[t] = v;
      }
      __syncthreads();
      unsigned int* tmp = pa; pa = pb; pb = tmp;
    }
    if (t < 512) start[t] = pa[t] - hist[t];
    __syncthreads();
    unsigned int* cur = pb;
    if (t < 512) cur[t] = start[t];
    __syncthreads();
    for (int e = t; e < EPG; e += 1024) {
      const int sl = esrc[ebase + e] - gbase;
      const int dl = edst[ebase + e] - gbase;
      const unsigned int pos = atomicAdd(&cur[dl], 1u);
      csrbuf[pos] = (unsigned short)sl;
    }
  }
  __syncthreads();
  // ---- ph2: GEMM1, 2-phase pipelined ----
  float zacc[32], xla[32];
  #pragma unroll
  for (int i = 0; i < 32; ++i) { zacc[i] = 0.f; xla[i] = 0.f; }
  #pragma unroll 1
  for (int c = 0; c < 10; ++c) {
    if (c < 9) stage_chunk(c + 1, (c + 1) & 1);
    const int p   = c & 1;
    const int xb  = p ? 8192  : 0;
    const int wrO = p ? 18432 : 16384;
    const int wlO = p ? 22528 : 20480;
    #pragma unroll 1
    for (int k4 = 0; k4 < 4; ++k4) {
      const int kb = k4 * 4;
      const float wr0 = zlds[wrO + (kb+0)*64 + lane], wr1 = zlds[wrO + (kb+1)*64 + lane],
                  wr2 = zlds[wrO + (kb+2)*64 + lane], wr3 = zlds[wrO + (kb+3)*64 + lane];
      const float wl0 = zlds[wlO + (kb+0)*64 + lane], wl1 = zlds[wlO + (kb+1)*64 + lane],
                  wl2 = zlds[wlO + (kb+2)*64 + lane], wl3 = zlds[wlO + (kb+3)*64 + lane];
      #pragma unroll
      for (int i = 0; i < 32; ++i) {
        const float4 xv = *reinterpret_cast<const float4*>(
            &zlds[xb + (ndbase + i) * 16 + kb]);
        float za = zacc[i], xa = xla[i];
        za = fmaf(xv.x, wr0, za); za = fmaf(xv.y, wr1, za);
        za = fmaf(xv.z, wr2, za); za = fmaf(xv.w, wr3, za);
        xa = fmaf(xv.x, wl0, xa); xa = fmaf(xv.y, wl1, xa);
        xa = fmaf(xv.z, wl2, xa); xa = fmaf(xv.w, wl3, xa);
        zacc[i] = za; xla[i] = xa;
      }
    }
    __syncthreads();
  }
  #pragma unroll
  for (int i = 0; i < 32; ++i)
    zlds[(ndbase + i) * 64 + lane] = zacc[i];             // z1
  __syncthreads();
  // ---- ph3: gather1 -> x1 ----
  {
    const float bv = c1b[lane];
    float psum = 0.f;
    #pragma unroll 1
    for (int i = 0; i < 32; ++i) {
      const int nd = ndbase + i;
      const unsigned int s = start[nd], d = hist[nd];
      float a0 = 0.f, a1 = 0.f, a2 = 0.f, a3 = 0.f;
      unsigned int j = 0;
      for (; j + 4 <= d; j += 4) {
        const int i0 = csrbuf[s+j], i1 = csrbuf[s+j+1],
                  i2 = csrbuf[s+j+2], i3 = csrbuf[s+j+3];
        a0 += zlds[i0*64 + lane]; a1 += zlds[i1*64 + lane];
        a2 += zlds[i2*64 + lane]; a3 += zlds[i3*64 + lane];
      }
      for (; j < d; ++j) a0 += zlds[csrbuf[s+j]*64 + lane];
      float v = ((a0 + a1) + (a2 + a3)) / (float)(d > 0 ? d : 1) + xla[i] + bv;
      v = fmaxf(v, 0.f);
      zacc[i] = v;
      psum += v;
    }
    __syncthreads();
    #pragma unroll
    for (int i = 0; i < 32; ++i)
      zlds[(ndbase + i) * 64 + lane] = zacc[i];           // x1
    wpf[w * 64 + lane] = psum;
    __syncthreads();
    if (t < 64) {
      float s = 0.f;
      #pragma unroll
      for (int ww = 0; ww < 16; ++ww) s += wpf[ww*64 + t];
      xsl[0 + t] = s * (1.f/512.f);
    }
  }
  // ---- ph4: GEMM2 ----
  #pragma unroll
  for (int i = 0; i < 32; ++i) { zacc[i] = 0.f; xla[i] = 0.f; }
  {
    float* w_r = wpf;
    float* w_l = wpf + 1024;
    #pragma unroll 1
    for (int c = 0; c < 4; ++c) {
      __syncthreads();
      w_r[t] = cWr[c * 1024 + t];
      w_l[t] = cWl[c * 1024 + t];
      __syncthreads();
      #pragma unroll 1
      for (int k4 = 0; k4 < 4; ++k4) {
        const int kb = k4 * 4;
        const float wr0 = w_r[(kb+0)*64 + lane], wr1 = w_r[(kb+1)*64 + lane],
                    wr2 = w_r[(kb+2)*64 + lane], wr3 = w_r[(kb+3)*64 + lane];
        const float wl0 = w_l[(kb+0)*64 + lane], wl1 = w_l[(kb+1)*64 + lane],
                    wl2 = w_l[(kb+2)*64 + lane], wl3 = w_l[(kb+3)*64 + lane];
        #pragma unroll
        for (int i = 0; i < 32; ++i) {
          const float4 xv = *reinterpret_cast<const float4*>(
              &zlds[(ndbase + i) * 64 + c * 16 + kb]);
          float za = zacc[i], xa = xla[i];
          za = fmaf(xv.x, wr0, za); za = fmaf(xv.y, wr1, za);
          za = fmaf(xv.z, wr2, za); za = fmaf(xv.w, wr3, za);
          xa = fmaf(xv.x, wl0, xa); xa = fmaf(xv.y, wl1, xa);
          xa = fmaf(xv.z, wl2, xa); xa = fmaf(xv.w, wl3, xa);
          zacc[i] = za; xla[i] = xa;
        }
      }
    }
  }
  __syncthreads();
  #pragma unroll
  for (int i = 0; i < 32; ++i)
    zlds[(ndbase + i) * 64 + lane] = zacc[i];             // z2
  __syncthreads();
  // ---- ph5: gather2 -> x2 ----
  {
    const float bv = cb[lane];
    float psum = 0.f;
    #pragma unroll 1
    for (int i = 0; i < 32; ++i) {
      const int nd = ndbase + i;
      const unsigned int s = start[nd], d = hist[nd];
      float a0 = 0.f, a1 = 0.f, a2 = 0.f, a3 = 0.f;
      unsigned int j = 0;
      for (; j + 4 <= d; j += 4) {
        const int i0 = csrbuf[s+j], i1 = csrbuf[s+j+1],
                  i2 = csrbuf[s+j+2], i3 = csrbuf[s+j+3];
        a0 += zlds[i0*64 + lane]; a1 += zlds[i1*64 + lane];
        a2 += zlds[i2*64 + lane]; a3 += zlds[i3*64 + lane];
      }
      for (; j < d; ++j) a0 += zlds[csrbuf[s+j]*64 + lane];
      float v = ((a0 + a1) + (a2 + a3)) / (float)(d > 0 ? d : 1) + xla[i] + bv;
      v = fmaxf(v, 0.f);
      zacc[i] = v;
      psum += v;
    }
    __syncthreads();
    #pragma unroll
    for (int i = 0; i < 32; ++i)
      zlds[(ndbase + i) * 64 + lane] = zacc[i];           // x2
    wpf[w * 64 + lane] = psum;
    __syncthreads();
    if (t < 64) {
      float s = 0.f;
      #pragma unroll
      for (int ww = 0; ww < 16; ++ww) s += wpf[ww*64 + t];
      xsl[64 + t] = s * (1.f/512.f);
    }
    __syncthreads();
  }
  // ---- ph6: pool0 ----
  {
    float* zs     = wpf;
    float* swl    = wpf + 512;
    float* sscore = wpf + 1024;
    const float pwrv = pwr[lane], pwlv = pwl[lane];
    for (int nd = w; nd < 512; nd += 16) {
      const float v = zlds[nd*64 + lane];
      float a = v * pwrv, b = v * pwlv;
      #pragma unroll
      for (int off = 32; off > 0; off >>= 1) {
        a += __shfl_xor(a, off);
        b += __shfl_xor(b, off);
      }
      if (lane == 0) { zs[nd] = a; swl[nd] = b; }
    }
    __syncthreads();
    if (t < 512) {
      const unsigned int s = start[t], d = hist[t];
      float a = 0.f;
      for (unsigned int j = 0; j < d; ++j) a += zs[csrbuf[s + j]];
      sscore[t] = a / fmaxf((float)d, 1.f) + pb[0] + swl[t];
    }
    __syncthreads();                 // hist/start & csr dead
    unsigned long long* keys = u2;
    if (t < 512) {
      unsigned int u = __float_as_uint(sscore[t]);
      u = (u & 0x80000000u) ? ~u : (u | 0x80000000u);
      keys[t] = ((unsigned long long)u << 32) | (unsigned int)(~(unsigned int)t);
    }
    __syncthreads();
    for (int kk = 2; kk <= 512; kk <<= 1) {
      for (int j = kk >> 1; j > 0; j >>= 1) {
        if (t < 512) {
          const int ixj = t ^ j;
          if (ixj > t) {
            const unsigned long long a = keys[t], bk = keys[ixj];
            const bool up = ((t & kk) == 0);
            if (up ? (a < bk) : (a > bk)) { keys[t] = bk; keys[ixj] = a; }
          }
        }
        __syncthreads();
      }
    }
    short* np = reinterpret_cast<short*>(csrbuf);
    if (t < 512) np[t] = -1;
    __syncthreads();
    if (t < 57)
      np[(int)(~(unsigned int)(keys[t] & 0xffffffffull))] = (short)t;
    __syncthreads();
    // extract X57 (read-all -> barrier -> write-all); zero deg; reset scnt
    float xr[4];
    int nr = 0;
    for (int r = w * 4; r < w * 4 + 4 && r < 57; ++r) {
      const int old = (int)(~(unsigned int)(keys[r] & 0xffffffffull));
      xr[nr++] = zlds[old*64 + lane] * tanhf(sscore[old]);
    }
    if (t < 64) wpf[t] = 0.f;        // deg (zs region dead)
    if (t == 0) scnt = 0;
    __syncthreads();
    nr = 0;
    for (int r = w * 4; r < w * 4 + 4 && r < 57; ++r)
      zlds[r*64 + lane] = xr[nr++];  // X57 rows [0..57)
    // compact edges into LDS (u16 pair) + deg atomics
    unsigned int* eb = reinterpret_cast<unsigned int*>(zlds + 16384);
    for (int e = t; e < EPG; e += 1024) {
      const int sl = esrc[ebase + e] - gbase;
      const int dl = edst[ebase + e] - gbase;
      const int ns = np[sl], nd2 = np[dl];
      if (ns >= 0 && nd2 >= 0) {
        const int slot = atomicAdd(&scnt, 1);
        eb[slot] = (unsigned int)ns | ((unsigned int)nd2 << 16);
        atomicAdd(&wpf[nd2], 1.f);
      }
    }
    __syncthreads();
  }
  const int m0 = scnt;
  // ---- ph7: tail (X/Z/ACC in zlds; edges in LDS) ----
  float* X   = zlds;          // [0..3648)
  float* Z   = zlds + 4096;
  float* ACC = zlds + 8192;
  float* deg = wpf;           // [0..64)
  float* w_s = wpf + 512;     // [512..1536)
  unsigned int* eb  = reinterpret_cast<unsigned int*>(zlds + 16384);
  unsigned int* eb1 = reinterpret_cast<unsigned int*>(zlds + 24576);

  auto conv57 = [&](int n, const unsigned int* edges, int m,
                    const float* Wr, const float* Wl, const float* bias,
                    int xs_off) {
    for (int i = t; i < n*64; i += 1024) { Z[i] = 0.f; ACC[i] = 0.f; }
    __syncthreads();
    for (int kc = 0; kc < 4; ++kc) {
      w_s[t] = Wr[kc*1024 + t];
      __syncthreads();
      for (int r = w; r < n; r += 16) {
        float za = 0.f;
        #pragma unroll
        for (int k = 0; k < 16; ++k)
          za = fmaf(X[r*64 + kc*16 + k], w_s[k*64 + lane], za);
        Z[r*64 + lane] += za;
      }
      __syncthreads();
    }
    for (int e = w; e < m; e += 16) {
      const unsigned int pr = edges[e];
      const int sl = pr & 0xffff, dl = pr >> 16;
      atomicAdd(&ACC[dl*64 + lane], Z[sl*64 + lane]);
    }
    __syncthreads();
    for (int i = t; i < n*64; i += 1024) {
      const int r = i >> 6, f = i & 63;
      Z[i] = ACC[i] / fmaxf(deg[r], 1.f) + bias[f];
    }
    __syncthreads();
    for (int kc = 0; kc < 4; ++kc) {
      w_s[t] = Wl[kc*1024 + t];
      __syncthreads();
      for (int r = w; r < n; r += 16) {
        float za = 0.f;
        #pragma unroll
        for (int k = 0; k < 16; ++k)
          za = fmaf(X[r*64 + kc*16 + k], w_s[k*64 + lane], za);
        Z[r*64 + lane] += za;
      }
      __syncthreads();
    }
    for (int i = t; i < n*64; i += 1024) X[i] = fmaxf(Z[i], 0.f);
    __syncthreads();
    float psum = 0.f;
    for (int r = w; r < n; r += 16) psum += X[r*64 + lane];
    Z[w*64 + lane] = psum;           // Z dead: reuse as red
    __syncthreads();
    if (t < 64) {
      float s = 0.f;
      #pragma unroll
      for (int ww = 0; ww < 16; ++ww) s += Z[ww*64 + t];
      xsl[xs_off + t] = s / (float)n;
    }
    __syncthreads();
  };

  conv57(57, eb, m0, cWr + 4096, cWl + 4096, cb + 64, 128);
  conv57(57, eb, m0, cWr + 8192, cWl + 8192, cb + 128, 192);

  // ---- pool1: 57 -> 7 ----
  {
    float* zs1 = wpf + 1536;   // 57
    float* sw1 = wpf + 1600;   // 57
    float* ss1 = wpf + 1664;   // 57
    const float pwrv = pwr[64 + lane], pwlv = pwl[64 + lane];
    for (int r = w; r < 57; r += 16) {
      float a = X[r*64 + lane] * pwrv, b = X[r*64 + lane] * pwlv;
      #pragma unroll
      for (int off = 32; off > 0; off >>= 1) {
        a += __shfl_xor(a, off);
        b += __shfl_xor(b, off);
      }
      if (lane == 0) { zs1[r] = a; sw1[r] = b; }
    }
    if (t >= 64 && t < 128) ACC[t - 64] = 0.f;   // sagg in ACC[0..57)
    __syncthreads();
    for (int e = t; e < m0; e += 1024) {
      const unsigned int pr = eb[e];
      atomicAdd(&ACC[pr >> 16], zs1[pr & 0xffff]);
    }
    __syncthreads();
    if (t < 57) ss1[t] = ACC[t] / fmaxf(deg[t], 1.f) + pb[1] + sw1[t];
    __syncthreads();
    unsigned long long* keys = u2;
    if (t < 64) {
      unsigned long long key = 0ull;
      if (t < 57) {
        unsigned int u = __float_as_uint(ss1[t]);
        u = (u & 0x80000000u) ? ~u : (u | 0x80000000u);
        key = ((unsigned long long)u << 32) | (unsigned int)(~(unsigned int)t);
      }
      keys[t] = key;
    }
    __syncthreads();
    for (int kk = 2; kk <= 64; kk <<= 1) {
      for (int j = kk >> 1; j > 0; j >>= 1) {
        if (t < 64) {
          const int ixj = t ^ j;
          if (ixj > t) {
            const unsigned long long a = keys[t], bk = keys[ixj];
            const bool up = ((t & kk) == 0);
            if (up ? (a < bk) : (a > bk)) { keys[t] = bk; keys[ixj] = a; }
          }
        }
        __syncthreads();
      }
    }
    short* np1 = reinterpret_cast<short*>(csrbuf);
    if (t < 64) np1[t] = -1;
    __syncthreads();
    if (t < 7)
      np1[(int)(~(unsigned int)(keys[t] & 0xffffffffull))] = (short)t;
    __syncthreads();
    // extract X7 (read -> barrier -> write); zero deg; reset scnt
    float xv7 = 0.f;
    int old7 = -1;
    if (w < 7 && w * 4 == w * 4) {   // wave w handles row w
      old7 = (int)(~(unsigned int)(keys[w] & 0xffffffffull));
      xv7 = X[old7*64 + lane] * tanhf(ss1[old7]);
    }
    if (t < 64) deg[t] = 0.f;
    if (t == 0) scnt = 0;
    __syncthreads();
    if (w < 7) X[w*64 + lane] = xv7;
    for (int e = t; e < m0; e += 1024) {
      const unsigned int pr = eb[e];
      const int ns = np1[pr & 0xffff], nd2 = np1[pr >> 16];
      if (ns >= 0 && nd2 >= 0) {
        const int slot = atomicAdd(&scnt, 1);
        eb1[slot] = (unsigned int)ns | ((unsigned int)nd2 << 16);
        atomicAdd(&deg[nd2], 1.f);
      }
    }
    __syncthreads();
  }
  const int m1 = scnt;

  conv57(7, eb1, m1, cWr + 12288, cWl + 12288, cb + 192, 256);
  conv57(7, eb1, m1, cWr + 16384, cWl + 16384, cb + 256, 320);

  // ---- ph8: head ----
  if (t < 64) {
    float acc = l1b[t];
    for (int j = 0; j < 384; ++j) acc = fmaf(xsl[j], l1W[j*64 + t], acc);
    wpf[t] = fmaxf(acc, 0.f);
  }
  __syncthreads();
  if (t < 2) {
    float a2 = l2b[t];
    for (int f2 = 0; f2 < 64; ++f2) a2 = fmaf(wpf[f2], l2W[f2*2 + t], a2);
    wpf[64 + t] = a2;
  }
  __syncthreads();
  if (t < 2) {
    const float mx = fmaxf(wpf[64], wpf[65]);
    const float lse = mx + logf(expf(wpf[64]-mx) + expf(wpf[65]-mx));
    out[g*2 + t] = wpf[64 + t] - lse;
  }
}

// ============================================================================
extern "C" void kernel_launch(void* const* d_in, const int* in_sizes, int n_in,
                              void* d_out, int out_size, void* d_ws, size_t ws_size,
                              hipStream_t stream)
{
  (void)in_sizes; (void)n_in; (void)d_ws; (void)ws_size; (void)out_size;
  const float* x    = (const float*)d_in[0];
  const int*   ei   = (const int*)d_in[1];
  const float* c1Wr = (const float*)d_in[2];
  const float* c1Wl = (const float*)d_in[3];
  const float* c1b  = (const float*)d_in[4];
  const float* cWr  = (const float*)d_in[5];
  const float* cWl  = (const float*)d_in[6];
  const float* cb   = (const float*)d_in[7];
  const float* pWr  = (const float*)d_in[8];
  const float* pWl  = (const float*)d_in[9];
  const float* pb   = (const float*)d_in[10];
  const float* l1W  = (const float*)d_in[11];
  const float* l1b  = (const float*)d_in[12];
  const float* l2W  = (const float*)d_in[13];
  const float* l2b  = (const float*)d_in[14];
  float* out = (float*)d_out;
  const int* esrc = ei;
  const int* edst = ei + ETOT;

  mono<<<NB, 1024, 0, stream>>>(x, esrc, edst, c1Wr, c1Wl, c1b,
                                cWr, cWl, cb, pWr, pWl, pb,
                                l1W, l1b, l2W, l2b, out);
}

// Round 23
// 317.099 us; speedup vs baseline: 1.1889x; 1.0104x over previous
//
#include <hip/hip_runtime.h>
#include <math.h>

namespace {
constexpr int NB   = 256;          // graphs
constexpr int EPG  = 8192;         // edges per graph
constexpr int ETOT = NB * EPG;     // 2,097,152
}

// ============================================================================
// mono: the ENTIRE network, one block per graph (1024 thr, ~157.5 KB LDS).
// v2: barrier-count surgery (150 -> ~60):
//   - pool0 512-key bitonic in REGISTERS (shfl for j<64; LDS only j>=64)
//   - pool1 64-key sort entirely in wave 0 via shuffles
//   - CSR scan via in-wave shuffle scan (no Hillis-Steele barriers)
//   - conv57 stages full 64x64 W in free zlds (no per-chunk barriers)
// All compare-exchange networks identical -> bitwise-same results.
// ============================================================================
__global__ __launch_bounds__(1024)
void mono(const float* __restrict__ x,
          const int* __restrict__ esrc, const int* __restrict__ edst,
          const float* __restrict__ c1Wr, const float* __restrict__ c1Wl,
          const float* __restrict__ c1b,
          const float* __restrict__ cWr, const float* __restrict__ cWl,
          const float* __restrict__ cb,
          const float* __restrict__ pwr, const float* __restrict__ pwl,
          const float* __restrict__ pb,
          const float* __restrict__ l1W, const float* __restrict__ l1b,
          const float* __restrict__ l2W, const float* __restrict__ l2b,
          float* __restrict__ out)
{
  __shared__ float zlds[512 * 64];                        // 128 KB
  __shared__ unsigned short csrbuf[EPG];                  // 16 KB
  __shared__ __align__(16) unsigned long long u2[512];    // 4 KB
  __shared__ float wpf[2048];                             // 8 KB
  __shared__ float xsl[384];                              // 1.5 KB (JK concat)
  __shared__ int scnt;
  unsigned int* hist  = reinterpret_cast<unsigned int*>(u2);   // [0..512)
  unsigned int* start = hist + 512;                            // [512..1024)
  unsigned int* curp  = reinterpret_cast<unsigned int*>(wpf);  // scatter cursor
  const int g = blockIdx.x, t = threadIdx.x;
  const int gbase = g * 512, ebase = g * EPG;
  const int lane = t & 63, w = t >> 6;                    // 16 waves
  const int ndbase = w * 32;

  auto stage_chunk = [&](int c, int p) {
    const int xb  = p ? 8192  : 0;
    const int wrO = p ? 18432 : 16384;
    const int wlO = p ? 22528 : 20480;
    #pragma unroll
    for (int i = 0; i < 2; ++i) {            // x: 512 rows x 16 k = 2048x16B
      const int slot = t + i * 1024;
      const int r = slot >> 2, q = slot & 3;
      const float* gp = &x[(size_t)(gbase + r) * 160 + c * 16 + q * 4];
      float* lp = zlds + xb + (size_t)(i * 1024 + w * 64) * 4;
      __builtin_amdgcn_global_load_lds(
          (const __attribute__((address_space(1))) unsigned int*)gp,
          (__attribute__((address_space(3))) unsigned int*)lp, 16, 0, 0);
    }
    {
      const float* gp = &c1Wr[c * 1024 + t];
      float* lp = zlds + wrO + (size_t)(w * 64);
      __builtin_amdgcn_global_load_lds(
          (const __attribute__((address_space(1))) unsigned int*)gp,
          (__attribute__((address_space(3))) unsigned int*)lp, 4, 0, 0);
    }
    {
      const float* gp = &c1Wl[c * 1024 + t];
      float* lp = zlds + wlO + (size_t)(w * 64);
      __builtin_amdgcn_global_load_lds(
          (const __attribute__((address_space(1))) unsigned int*)gp,
          (__attribute__((address_space(3))) unsigned int*)lp, 4, 0, 0);
    }
  };

  // ---- ph1: CSR build (shuffle scan) ----
  if (t < 512) hist[t] = 0;
  if (t == 0) scnt = 0;
  __syncthreads();
  stage_chunk(0, 0);
  for (int e = t; e < EPG; e += 1024)
    atomicAdd(&hist[edst[ebase + e] - gbase], 1u);
  __syncthreads();
  {
    unsigned int v = 0;
    if (t < 512) {                       // waves 0-7 fully active
      v = hist[t];
      #pragma unroll
      for (int off = 1; off < 64; off <<= 1) {
        const unsigned int up = __shfl_up(v, off);
        if (lane >= off) v += up;
      }
      if (lane == 63)
        reinterpret_cast<unsigned int*>(wpf)[1024 + w] = v;  // wave totals
    }
    __syncthreads();
    if (t < 512) {
      unsigned int off = 0;
      for (int i = 0; i < w; ++i)
        off += reinterpret_cast<unsigned int*>(wpf)[1024 + i];
      const unsigned int st = off + v - hist[t];
      start[t] = st;
      curp[t]  = st;
    }
    __syncthreads();
    for (int e = t; e < EPG; e += 1024) {
      const int sl = esrc[ebase + e] - gbase;
      const int dl = edst[ebase + e] - gbase;
      const unsigned int pos = atomicAdd(&curp[dl], 1u);
      csrbuf[pos] = (unsigned short)sl;
    }
  }
  __syncthreads();
  // ---- ph2: GEMM1, 2-phase pipelined ----
  float zacc[32], xla[32];
  #pragma unroll
  for (int i = 0; i < 32; ++i) { zacc[i] = 0.f; xla[i] = 0.f; }
  #pragma unroll 1
  for (int c = 0; c < 10; ++c) {
    if (c < 9) stage_chunk(c + 1, (c + 1) & 1);
    const int p   = c & 1;
    const int xb  = p ? 8192  : 0;
    const int wrO = p ? 18432 : 16384;
    const int wlO = p ? 22528 : 20480;
    #pragma unroll 1
    for (int k4 = 0; k4 < 4; ++k4) {
      const int kb = k4 * 4;
      const float wr0 = zlds[wrO + (kb+0)*64 + lane], wr1 = zlds[wrO + (kb+1)*64 + lane],
                  wr2 = zlds[wrO + (kb+2)*64 + lane], wr3 = zlds[wrO + (kb+3)*64 + lane];
      const float wl0 = zlds[wlO + (kb+0)*64 + lane], wl1 = zlds[wlO + (kb+1)*64 + lane],
                  wl2 = zlds[wlO + (kb+2)*64 + lane], wl3 = zlds[wlO + (kb+3)*64 + lane];
      #pragma unroll
      for (int i = 0; i < 32; ++i) {
        const float4 xv = *reinterpret_cast<const float4*>(
            &zlds[xb + (ndbase + i) * 16 + kb]);
        float za = zacc[i], xa = xla[i];
        za = fmaf(xv.x, wr0, za); za = fmaf(xv.y, wr1, za);
        za = fmaf(xv.z, wr2, za); za = fmaf(xv.w, wr3, za);
        xa = fmaf(xv.x, wl0, xa); xa = fmaf(xv.y, wl1, xa);
        xa = fmaf(xv.z, wl2, xa); xa = fmaf(xv.w, wl3, xa);
        zacc[i] = za; xla[i] = xa;
      }
    }
    __syncthreads();
  }
  #pragma unroll
  for (int i = 0; i < 32; ++i)
    zlds[(ndbase + i) * 64 + lane] = zacc[i];             // z1
  __syncthreads();
  // ---- ph3: gather1 -> x1 ----
  {
    const float bv = c1b[lane];
    float psum = 0.f;
    #pragma unroll 1
    for (int i = 0; i < 32; ++i) {
      const int nd = ndbase + i;
      const unsigned int s = start[nd], d = hist[nd];
      float a0 = 0.f, a1 = 0.f, a2 = 0.f, a3 = 0.f;
      unsigned int j = 0;
      for (; j + 4 <= d; j += 4) {
        const int i0 = csrbuf[s+j], i1 = csrbuf[s+j+1],
                  i2 = csrbuf[s+j+2], i3 = csrbuf[s+j+3];
        a0 += zlds[i0*64 + lane]; a1 += zlds[i1*64 + lane];
        a2 += zlds[i2*64 + lane]; a3 += zlds[i3*64 + lane];
      }
      for (; j < d; ++j) a0 += zlds[csrbuf[s+j]*64 + lane];
      float v = ((a0 + a1) + (a2 + a3)) / (float)(d > 0 ? d : 1) + xla[i] + bv;
      v = fmaxf(v, 0.f);
      zacc[i] = v;
      psum += v;
    }
    __syncthreads();
    #pragma unroll
    for (int i = 0; i < 32; ++i)
      zlds[(ndbase + i) * 64 + lane] = zacc[i];           // x1
    wpf[w * 64 + lane] = psum;
    __syncthreads();
    if (t < 64) {
      float s = 0.f;
      #pragma unroll
      for (int ww = 0; ww < 16; ++ww) s += wpf[ww*64 + t];
      xsl[0 + t] = s * (1.f/512.f);
    }
  }
  // ---- ph4: GEMM2 ----
  #pragma unroll
  for (int i = 0; i < 32; ++i) { zacc[i] = 0.f; xla[i] = 0.f; }
  {
    float* w_r = wpf;
    float* w_l = wpf + 1024;
    #pragma unroll 1
    for (int c = 0; c < 4; ++c) {
      __syncthreads();
      w_r[t] = cWr[c * 1024 + t];
      w_l[t] = cWl[c * 1024 + t];
      __syncthreads();
      #pragma unroll 1
      for (int k4 = 0; k4 < 4; ++k4) {
        const int kb = k4 * 4;
        const float wr0 = w_r[(kb+0)*64 + lane], wr1 = w_r[(kb+1)*64 + lane],
                    wr2 = w_r[(kb+2)*64 + lane], wr3 = w_r[(kb+3)*64 + lane];
        const float wl0 = w_l[(kb+0)*64 + lane], wl1 = w_l[(kb+1)*64 + lane],
                    wl2 = w_l[(kb+2)*64 + lane], wl3 = w_l[(kb+3)*64 + lane];
        #pragma unroll
        for (int i = 0; i < 32; ++i) {
          const float4 xv = *reinterpret_cast<const float4*>(
              &zlds[(ndbase + i) * 64 + c * 16 + kb]);
          float za = zacc[i], xa = xla[i];
          za = fmaf(xv.x, wr0, za); za = fmaf(xv.y, wr1, za);
          za = fmaf(xv.z, wr2, za); za = fmaf(xv.w, wr3, za);
          xa = fmaf(xv.x, wl0, xa); xa = fmaf(xv.y, wl1, xa);
          xa = fmaf(xv.z, wl2, xa); xa = fmaf(xv.w, wl3, xa);
          zacc[i] = za; xla[i] = xa;
        }
      }
    }
  }
  __syncthreads();
  #pragma unroll
  for (int i = 0; i < 32; ++i)
    zlds[(ndbase + i) * 64 + lane] = zacc[i];             // z2
  __syncthreads();
  // ---- ph5: gather2 -> x2 ----
  {
    const float bv = cb[lane];
    float psum = 0.f;
    #pragma unroll 1
    for (int i = 0; i < 32; ++i) {
      const int nd = ndbase + i;
      const unsigned int s = start[nd], d = hist[nd];
      float a0 = 0.f, a1 = 0.f, a2 = 0.f, a3 = 0.f;
      unsigned int j = 0;
      for (; j + 4 <= d; j += 4) {
        const int i0 = csrbuf[s+j], i1 = csrbuf[s+j+1],
                  i2 = csrbuf[s+j+2], i3 = csrbuf[s+j+3];
        a0 += zlds[i0*64 + lane]; a1 += zlds[i1*64 + lane];
        a2 += zlds[i2*64 + lane]; a3 += zlds[i3*64 + lane];
      }
      for (; j < d; ++j) a0 += zlds[csrbuf[s+j]*64 + lane];
      float v = ((a0 + a1) + (a2 + a3)) / (float)(d > 0 ? d : 1) + xla[i] + bv;
      v = fmaxf(v, 0.f);
      zacc[i] = v;
      psum += v;
    }
    __syncthreads();
    #pragma unroll
    for (int i = 0; i < 32; ++i)
      zlds[(ndbase + i) * 64 + lane] = zacc[i];           // x2
    wpf[w * 64 + lane] = psum;
    __syncthreads();
    if (t < 64) {
      float s = 0.f;
      #pragma unroll
      for (int ww = 0; ww < 16; ++ww) s += wpf[ww*64 + t];
      xsl[64 + t] = s * (1.f/512.f);
    }
    __syncthreads();
  }
  // ---- ph6: pool0 ----
  {
    float* zs     = wpf;
    float* swl    = wpf + 512;
    float* sscore = wpf + 1024;
    const float pwrv = pwr[lane], pwlv = pwl[lane];
    for (int nd = w; nd < 512; nd += 16) {
      const float v = zlds[nd*64 + lane];
      float a = v * pwrv, b = v * pwlv;
      #pragma unroll
      for (int off = 32; off > 0; off >>= 1) {
        a += __shfl_xor(a, off);
        b += __shfl_xor(b, off);
      }
      if (lane == 0) { zs[nd] = a; swl[nd] = b; }
    }
    __syncthreads();
    if (t < 512) {
      const unsigned int s = start[t], d = hist[t];
      float a = 0.f;
      for (unsigned int j = 0; j < d; ++j) a += zs[csrbuf[s + j]];
      sscore[t] = a / fmaxf((float)d, 1.f) + pb[0] + swl[t];
    }
    __syncthreads();                 // hist/start & csr dead
    // register-resident bitonic sort (shfl for j<64; LDS for j>=64)
    unsigned long long k = 0ull;
    if (t < 512) {
      unsigned int u = __float_as_uint(sscore[t]);
      u = (u & 0x80000000u) ? ~u : (u | 0x80000000u);
      k = ((unsigned long long)u << 32) | (unsigned int)(~(unsigned int)t);
    }
    for (int kk = 2; kk <= 512; kk <<= 1) {
      for (int j = kk >> 1; j > 0; j >>= 1) {
        if (j >= 64) {
          if (t < 512) u2[t] = k;
          __syncthreads();
          unsigned long long kp = 0ull;
          if (t < 512) kp = u2[t ^ j];
          __syncthreads();
          if (t < 512) {
            const bool keep_max = (((t & kk) == 0) == ((t & j) == 0));
            k = keep_max ? (k >= kp ? k : kp) : (k >= kp ? kp : k);
          }
        } else if (t < 512) {        // waves 0-7 fully active
          const unsigned int lo = __shfl_xor((unsigned int)k, j);
          const unsigned int hi = __shfl_xor((unsigned int)(k >> 32), j);
          const unsigned long long kp = ((unsigned long long)hi << 32) | lo;
          const bool keep_max = (((t & kk) == 0) == ((t & j) == 0));
          k = keep_max ? (k >= kp ? k : kp) : (k >= kp ? kp : k);
        }
      }
    }
    if (t < 512) u2[t] = k;
    __syncthreads();
    unsigned long long* keys = u2;
    short* np = reinterpret_cast<short*>(csrbuf);
    if (t < 512) np[t] = -1;
    __syncthreads();
    if (t < 57)
      np[(int)(~(unsigned int)(keys[t] & 0xffffffffull))] = (short)t;
    __syncthreads();
    // extract X57 (read-all -> barrier -> write-all); zero deg; reset scnt
    float xr[4];
    int nr = 0;
    for (int r = w * 4; r < w * 4 + 4 && r < 57; ++r) {
      const int old = (int)(~(unsigned int)(keys[r] & 0xffffffffull));
      xr[nr++] = zlds[old*64 + lane] * tanhf(sscore[old]);
    }
    if (t < 64) wpf[t] = 0.f;        // deg (zs region dead)
    if (t == 0) scnt = 0;
    __syncthreads();
    nr = 0;
    for (int r = w * 4; r < w * 4 + 4 && r < 57; ++r)
      zlds[r*64 + lane] = xr[nr++];  // X57 rows [0..57)
    unsigned int* eb = reinterpret_cast<unsigned int*>(zlds + 16384);
    for (int e = t; e < EPG; e += 1024) {
      const int sl = esrc[ebase + e] - gbase;
      const int dl = edst[ebase + e] - gbase;
      const int ns = np[sl], nd2 = np[dl];
      if (ns >= 0 && nd2 >= 0) {
        const int slot = atomicAdd(&scnt, 1);
        eb[slot] = (unsigned int)ns | ((unsigned int)nd2 << 16);
        atomicAdd(&wpf[nd2], 1.f);
      }
    }
    __syncthreads();
  }
  const int m0 = scnt;
  // ---- ph7: tail (X/Z/ACC in zlds; edges in LDS; full-W staging) ----
  float* X   = zlds;          // [0..3648)
  float* Z   = zlds + 4096;
  float* ACC = zlds + 8192;
  float* deg = wpf;           // [0..64)
  unsigned int* eb  = reinterpret_cast<unsigned int*>(zlds + 16384);
  unsigned int* eb1 = reinterpret_cast<unsigned int*>(zlds + 24576);

  auto conv57 = [&](int n, const unsigned int* edges, int m,
                    const float* Wr, const float* Wl, const float* bias,
                    int xs_off) {
    float* Wfull = zlds + 12288;     // 16 KB free: [12288..16384)
    for (int i = t; i < n*64; i += 1024) ACC[i] = 0.f;
    #pragma unroll
    for (int i = 0; i < 4; ++i) Wfull[t + i*1024] = Wr[t + i*1024];
    __syncthreads();
    for (int r = w; r < n; r += 16) {        // Z = X @ Wr (own rows)
      float za = 0.f;
      for (int k = 0; k < 64; ++k)
        za = fmaf(X[r*64 + k], Wfull[k*64 + lane], za);
      Z[r*64 + lane] = za;
    }
    __syncthreads();                          // Z done; Wr dead
    for (int e = w; e < m; e += 16) {         // agg (+ Wl load below)
      const unsigned int pr = edges[e];
      atomicAdd(&ACC[(pr >> 16)*64 + lane], Z[(pr & 0xffff)*64 + lane]);
    }
    #pragma unroll
    for (int i = 0; i < 4; ++i) Wfull[t + i*1024] = Wl[t + i*1024];
    __syncthreads();
    for (int i = t; i < n*64; i += 1024) {    // T = ACC/deg + bias -> Z
      const int r = i >> 6, f = i & 63;
      Z[i] = ACC[i] / fmaxf(deg[r], 1.f) + bias[f];
    }
    __syncthreads();
    float psum = 0.f;
    for (int r = w; r < n; r += 16) {         // X = relu(T + X@Wl), own rows
      float za = Z[r*64 + lane];
      for (int k = 0; k < 64; ++k)
        za = fmaf(X[r*64 + k], Wfull[k*64 + lane], za);
      za = fmaxf(za, 0.f);
      X[r*64 + lane] = za;
      psum += za;
    }
    ACC[w*64 + lane] = psum;                  // red (ACC dead)
    __syncthreads();
    if (t < 64) {
      float s = 0.f;
      #pragma unroll
      for (int ww = 0; ww < 16; ++ww) s += ACC[ww*64 + t];
      xsl[xs_off + t] = s / (float)n;
    }
    __syncthreads();
  };

  conv57(57, eb, m0, cWr + 4096, cWl + 4096, cb + 64, 128);
  conv57(57, eb, m0, cWr + 8192, cWl + 8192, cb + 128, 192);

  // ---- pool1: 57 -> 7 (sort in wave 0 only) ----
  {
    float* zs1 = wpf + 1536;   // 57
    float* sw1 = wpf + 1600;   // 57
    float* ss1 = wpf + 1664;   // 57
    const float pwrv = pwr[64 + lane], pwlv = pwl[64 + lane];
    for (int r = w; r < 57; r += 16) {
      float a = X[r*64 + lane] * pwrv, b = X[r*64 + lane] * pwlv;
      #pragma unroll
      for (int off = 32; off > 0; off >>= 1) {
        a += __shfl_xor(a, off);
        b += __shfl_xor(b, off);
      }
      if (lane == 0) { zs1[r] = a; sw1[r] = b; }
    }
    if (t >= 64 && t < 128) ACC[t - 64] = 0.f;   // sagg in ACC[0..57)
    __syncthreads();
    for (int e = t; e < m0; e += 1024) {
      const unsigned int pr = eb[e];
      atomicAdd(&ACC[pr >> 16], zs1[pr & 0xffff]);
    }
    __syncthreads();
    if (t < 57) ss1[t] = ACC[t] / fmaxf(deg[t], 1.f) + pb[1] + sw1[t];
    __syncthreads();
    if (w == 0) {                              // in-wave 64-key bitonic
      unsigned long long k1 = 0ull;
      if (lane < 57) {
        unsigned int u = __float_as_uint(ss1[lane]);
        u = (u & 0x80000000u) ? ~u : (u | 0x80000000u);
        k1 = ((unsigned long long)u << 32) | (unsigned int)(~(unsigned int)lane);
      }
      for (int kk = 2; kk <= 64; kk <<= 1) {
        for (int j = kk >> 1; j > 0; j >>= 1) {
          const unsigned int lo = __shfl_xor((unsigned int)k1, j);
          const unsigned int hi = __shfl_xor((unsigned int)(k1 >> 32), j);
          const unsigned long long kp = ((unsigned long long)hi << 32) | lo;
          const bool keep_max = (((lane & kk) == 0) == ((lane & j) == 0));
          k1 = keep_max ? (k1 >= kp ? k1 : kp) : (k1 >= kp ? kp : k1);
        }
      }
      u2[lane] = k1;
    }
    __syncthreads();
    unsigned long long* keys = u2;
    short* np1 = reinterpret_cast<short*>(csrbuf);
    if (t < 64) np1[t] = -1;
    __syncthreads();
    if (t < 7)
      np1[(int)(~(unsigned int)(keys[t] & 0xffffffffull))] = (short)t;
    __syncthreads();
    float xv7 = 0.f;
    if (w < 7) {
      const int old7 = (int)(~(unsigned int)(keys[w] & 0xffffffffull));
      xv7 = X[old7*64 + lane] * tanhf(ss1[old7]);
    }
    if (t < 64) deg[t] = 0.f;
    if (t == 0) scnt = 0;
    __syncthreads();
    if (w < 7) X[w*64 + lane] = xv7;
    for (int e = t; e < m0; e += 1024) {
      const unsigned int pr = eb[e];
      const int ns = np1[pr & 0xffff], nd2 = np1[pr >> 16];
      if (ns >= 0 && nd2 >= 0) {
        const int slot = atomicAdd(&scnt, 1);
        eb1[slot] = (unsigned int)ns | ((unsigned int)nd2 << 16);
        atomicAdd(&deg[nd2], 1.f);
      }
    }
    __syncthreads();
  }
  const int m1 = scnt;

  conv57(7, eb1, m1, cWr + 12288, cWl + 12288, cb + 192, 256);
  conv57(7, eb1, m1, cWr + 16384, cWl + 16384, cb + 256, 320);

  // ---- ph8: head ----
  if (t < 64) {
    float acc = l1b[t];
    for (int j = 0; j < 384; ++j) acc = fmaf(xsl[j], l1W[j*64 + t], acc);
    wpf[t] = fmaxf(acc, 0.f);
  }
  __syncthreads();
  if (t < 2) {
    float a2 = l2b[t];
    for (int f2 = 0; f2 < 64; ++f2) a2 = fmaf(wpf[f2], l2W[f2*2 + t], a2);
    wpf[64 + t] = a2;
  }
  __syncthreads();
  if (t < 2) {
    const float mx = fmaxf(wpf[64], wpf[65]);
    const float lse = mx + logf(expf(wpf[64]-mx) + expf(wpf[65]-mx));
    out[g*2 + t] = wpf[64 + t] - lse;
  }
}

// ============================================================================
extern "C" void kernel_launch(void* const* d_in, const int* in_sizes, int n_in,
                              void* d_out, int out_size, void* d_ws, size_t ws_size,
                              hipStream_t stream)
{
  (void)in_sizes; (void)n_in; (void)d_ws; (void)ws_size; (void)out_size;
  const float* x    = (const float*)d_in[0];
  const int*   ei   = (const int*)d_in[1];
  const float* c1Wr = (const float*)d_in[2];
  const float* c1Wl = (const float*)d_in[3];
  const float* c1b  = (const float*)d_in[4];
  const float* cWr  = (const float*)d_in[5];
  const float* cWl  = (const float*)d_in[6];
  const float* cb   = (const float*)d_in[7];
  const float* pWr  = (const float*)d_in[8];
  const float* pWl  = (const float*)d_in[9];
  const float* pb   = (const float*)d_in[10];
  const float* l1W  = (const float*)d_in[11];
  const float* l1b  = (const float*)d_in[12];
  const float* l2W  = (const float*)d_in[13];
  const float* l2b  = (const float*)d_in[14];
  float* out = (float*)d_out;
  const int* esrc = ei;
  const int* edst = ei + ETOT;

  mono<<<NB, 1024, 0, stream>>>(x, esrc, edst, c1Wr, c1Wl, c1b,
                                cWr, cWl, cb, pWr, pWl, pb,
                                l1W, l1b, l2W, l2b, out);
}

// Round 24
// 315.760 us; speedup vs baseline: 1.1939x; 1.0042x over previous
//
#include <hip/hip_runtime.h>
#include <math.h>

namespace {
constexpr int NB   = 256;          // graphs
constexpr int EPG  = 8192;         // edges per graph
constexpr int ETOT = NB * EPG;     // 2,097,152
}

// ============================================================================
// mono v3: round-23 kernel + dual-node 8-deep CSR gathers (ph3/ph5) and
// 4-unrolled pool0 score gather. Per-node summation order unchanged.
// ============================================================================
__global__ __launch_bounds__(1024)
void mono(const float* __restrict__ x,
          const int* __restrict__ esrc, const int* __restrict__ edst,
          const float* __restrict__ c1Wr, const float* __restrict__ c1Wl,
          const float* __restrict__ c1b,
          const float* __restrict__ cWr, const float* __restrict__ cWl,
          const float* __restrict__ cb,
          const float* __restrict__ pwr, const float* __restrict__ pwl,
          const float* __restrict__ pb,
          const float* __restrict__ l1W, const float* __restrict__ l1b,
          const float* __restrict__ l2W, const float* __restrict__ l2b,
          float* __restrict__ out)
{
  __shared__ float zlds[512 * 64];                        // 128 KB
  __shared__ unsigned short csrbuf[EPG];                  // 16 KB
  __shared__ __align__(16) unsigned long long u2[512];    // 4 KB
  __shared__ float wpf[2048];                             // 8 KB
  __shared__ float xsl[384];                              // 1.5 KB (JK concat)
  __shared__ int scnt;
  unsigned int* hist  = reinterpret_cast<unsigned int*>(u2);   // [0..512)
  unsigned int* start = hist + 512;                            // [512..1024)
  unsigned int* curp  = reinterpret_cast<unsigned int*>(wpf);  // scatter cursor
  const int g = blockIdx.x, t = threadIdx.x;
  const int gbase = g * 512, ebase = g * EPG;
  const int lane = t & 63, w = t >> 6;                    // 16 waves
  const int ndbase = w * 32;

  auto stage_chunk = [&](int c, int p) {
    const int xb  = p ? 8192  : 0;
    const int wrO = p ? 18432 : 16384;
    const int wlO = p ? 22528 : 20480;
    #pragma unroll
    for (int i = 0; i < 2; ++i) {            // x: 512 rows x 16 k = 2048x16B
      const int slot = t + i * 1024;
      const int r = slot >> 2, q = slot & 3;
      const float* gp = &x[(size_t)(gbase + r) * 160 + c * 16 + q * 4];
      float* lp = zlds + xb + (size_t)(i * 1024 + w * 64) * 4;
      __builtin_amdgcn_global_load_lds(
          (const __attribute__((address_space(1))) unsigned int*)gp,
          (__attribute__((address_space(3))) unsigned int*)lp, 16, 0, 0);
    }
    {
      const float* gp = &c1Wr[c * 1024 + t];
      float* lp = zlds + wrO + (size_t)(w * 64);
      __builtin_amdgcn_global_load_lds(
          (const __attribute__((address_space(1))) unsigned int*)gp,
          (__attribute__((address_space(3))) unsigned int*)lp, 4, 0, 0);
    }
    {
      const float* gp = &c1Wl[c * 1024 + t];
      float* lp = zlds + wlO + (size_t)(w * 64);
      __builtin_amdgcn_global_load_lds(
          (const __attribute__((address_space(1))) unsigned int*)gp,
          (__attribute__((address_space(3))) unsigned int*)lp, 4, 0, 0);
    }
  };

  // ---- ph1: CSR build (shuffle scan) ----
  if (t < 512) hist[t] = 0;
  if (t == 0) scnt = 0;
  __syncthreads();
  stage_chunk(0, 0);
  for (int e = t; e < EPG; e += 1024)
    atomicAdd(&hist[edst[ebase + e] - gbase], 1u);
  __syncthreads();
  {
    unsigned int v = 0;
    if (t < 512) {
      v = hist[t];
      #pragma unroll
      for (int off = 1; off < 64; off <<= 1) {
        const unsigned int up = __shfl_up(v, off);
        if (lane >= off) v += up;
      }
      if (lane == 63)
        reinterpret_cast<unsigned int*>(wpf)[1024 + w] = v;
    }
    __syncthreads();
    if (t < 512) {
      unsigned int off = 0;
      for (int i = 0; i < w; ++i)
        off += reinterpret_cast<unsigned int*>(wpf)[1024 + i];
      const unsigned int st = off + v - hist[t];
      start[t] = st;
      curp[t]  = st;
    }
    __syncthreads();
    for (int e = t; e < EPG; e += 1024) {
      const int sl = esrc[ebase + e] - gbase;
      const int dl = edst[ebase + e] - gbase;
      const unsigned int pos = atomicAdd(&curp[dl], 1u);
      csrbuf[pos] = (unsigned short)sl;
    }
  }
  __syncthreads();
  // ---- ph2: GEMM1, 2-phase pipelined ----
  float zacc[32], xla[32];
  #pragma unroll
  for (int i = 0; i < 32; ++i) { zacc[i] = 0.f; xla[i] = 0.f; }
  #pragma unroll 1
  for (int c = 0; c < 10; ++c) {
    if (c < 9) stage_chunk(c + 1, (c + 1) & 1);
    const int p   = c & 1;
    const int xb  = p ? 8192  : 0;
    const int wrO = p ? 18432 : 16384;
    const int wlO = p ? 22528 : 20480;
    #pragma unroll 1
    for (int k4 = 0; k4 < 4; ++k4) {
      const int kb = k4 * 4;
      const float wr0 = zlds[wrO + (kb+0)*64 + lane], wr1 = zlds[wrO + (kb+1)*64 + lane],
                  wr2 = zlds[wrO + (kb+2)*64 + lane], wr3 = zlds[wrO + (kb+3)*64 + lane];
      const float wl0 = zlds[wlO + (kb+0)*64 + lane], wl1 = zlds[wlO + (kb+1)*64 + lane],
                  wl2 = zlds[wlO + (kb+2)*64 + lane], wl3 = zlds[wlO + (kb+3)*64 + lane];
      #pragma unroll
      for (int i = 0; i < 32; ++i) {
        const float4 xv = *reinterpret_cast<const float4*>(
            &zlds[xb + (ndbase + i) * 16 + kb]);
        float za = zacc[i], xa = xla[i];
        za = fmaf(xv.x, wr0, za); za = fmaf(xv.y, wr1, za);
        za = fmaf(xv.z, wr2, za); za = fmaf(xv.w, wr3, za);
        xa = fmaf(xv.x, wl0, xa); xa = fmaf(xv.y, wl1, xa);
        xa = fmaf(xv.z, wl2, xa); xa = fmaf(xv.w, wl3, xa);
        zacc[i] = za; xla[i] = xa;
      }
    }
    __syncthreads();
  }
  #pragma unroll
  for (int i = 0; i < 32; ++i)
    zlds[(ndbase + i) * 64 + lane] = zacc[i];             // z1
  __syncthreads();
  // dual-node 8-deep CSR gather over LDS (per-node order = 4-chunks + tail)
  auto gather_pair = [&](float* dstacc, const float* bias_p, float& psum) {
    const float bv = bias_p[lane];
    #pragma unroll 1
    for (int i = 0; i < 16; ++i) {
      const int ndA = ndbase + i, ndB = ndbase + 16 + i;
      const unsigned int sA = start[ndA], dA = hist[ndA];
      const unsigned int sB = start[ndB], dB = hist[ndB];
      float aA0=0.f,aA1=0.f,aA2=0.f,aA3=0.f;
      float aB0=0.f,aB1=0.f,aB2=0.f,aB3=0.f;
      unsigned int jA = 0, jB = 0;
      while (jA + 4 <= dA && jB + 4 <= dB) {
        const int iA0 = csrbuf[sA+jA],   iA1 = csrbuf[sA+jA+1],
                  iA2 = csrbuf[sA+jA+2], iA3 = csrbuf[sA+jA+3];
        const int iB0 = csrbuf[sB+jB],   iB1 = csrbuf[sB+jB+1],
                  iB2 = csrbuf[sB+jB+2], iB3 = csrbuf[sB+jB+3];
        const float vA0 = zlds[iA0*64+lane], vA1 = zlds[iA1*64+lane];
        const float vA2 = zlds[iA2*64+lane], vA3 = zlds[iA3*64+lane];
        const float vB0 = zlds[iB0*64+lane], vB1 = zlds[iB1*64+lane];
        const float vB2 = zlds[iB2*64+lane], vB3 = zlds[iB3*64+lane];
        aA0 += vA0; aA1 += vA1; aA2 += vA2; aA3 += vA3;
        aB0 += vB0; aB1 += vB1; aB2 += vB2; aB3 += vB3;
        jA += 4; jB += 4;
      }
      for (; jA + 4 <= dA; jA += 4) {
        aA0 += zlds[csrbuf[sA+jA]*64+lane];   aA1 += zlds[csrbuf[sA+jA+1]*64+lane];
        aA2 += zlds[csrbuf[sA+jA+2]*64+lane]; aA3 += zlds[csrbuf[sA+jA+3]*64+lane];
      }
      for (; jB + 4 <= dB; jB += 4) {
        aB0 += zlds[csrbuf[sB+jB]*64+lane];   aB1 += zlds[csrbuf[sB+jB+1]*64+lane];
        aB2 += zlds[csrbuf[sB+jB+2]*64+lane]; aB3 += zlds[csrbuf[sB+jB+3]*64+lane];
      }
      for (; jA < dA; ++jA) aA0 += zlds[csrbuf[sA+jA]*64+lane];
      for (; jB < dB; ++jB) aB0 += zlds[csrbuf[sB+jB]*64+lane];
      float vA = ((aA0+aA1)+(aA2+aA3)) / (float)(dA > 0 ? dA : 1) + xla[i] + bv;
      float vB = ((aB0+aB1)+(aB2+aB3)) / (float)(dB > 0 ? dB : 1) + xla[16+i] + bv;
      vA = fmaxf(vA, 0.f);
      vB = fmaxf(vB, 0.f);
      dstacc[i] = vA; dstacc[16+i] = vB;
      psum += vA + vB;
    }
  };
  // ---- ph3: gather1 -> x1 ----
  {
    float psum = 0.f;
    gather_pair(zacc, c1b, psum);
    __syncthreads();
    #pragma unroll
    for (int i = 0; i < 32; ++i)
      zlds[(ndbase + i) * 64 + lane] = zacc[i];           // x1
    wpf[w * 64 + lane] = psum;
    __syncthreads();
    if (t < 64) {
      float s = 0.f;
      #pragma unroll
      for (int ww = 0; ww < 16; ++ww) s += wpf[ww*64 + t];
      xsl[0 + t] = s * (1.f/512.f);
    }
  }
  // ---- ph4: GEMM2 ----
  #pragma unroll
  for (int i = 0; i < 32; ++i) { zacc[i] = 0.f; xla[i] = 0.f; }
  {
    float* w_r = wpf;
    float* w_l = wpf + 1024;
    #pragma unroll 1
    for (int c = 0; c < 4; ++c) {
      __syncthreads();
      w_r[t] = cWr[c * 1024 + t];
      w_l[t] = cWl[c * 1024 + t];
      __syncthreads();
      #pragma unroll 1
      for (int k4 = 0; k4 < 4; ++k4) {
        const int kb = k4 * 4;
        const float wr0 = w_r[(kb+0)*64 + lane], wr1 = w_r[(kb+1)*64 + lane],
                    wr2 = w_r[(kb+2)*64 + lane], wr3 = w_r[(kb+3)*64 + lane];
        const float wl0 = w_l[(kb+0)*64 + lane], wl1 = w_l[(kb+1)*64 + lane],
                    wl2 = w_l[(kb+2)*64 + lane], wl3 = w_l[(kb+3)*64 + lane];
        #pragma unroll
        for (int i = 0; i < 32; ++i) {
          const float4 xv = *reinterpret_cast<const float4*>(
              &zlds[(ndbase + i) * 64 + c * 16 + kb]);
          float za = zacc[i], xa = xla[i];
          za = fmaf(xv.x, wr0, za); za = fmaf(xv.y, wr1, za);
          za = fmaf(xv.z, wr2, za); za = fmaf(xv.w, wr3, za);
          xa = fmaf(xv.x, wl0, xa); xa = fmaf(xv.y, wl1, xa);
          xa = fmaf(xv.z, wl2, xa); xa = fmaf(xv.w, wl3, xa);
          zacc[i] = za; xla[i] = xa;
        }
      }
    }
  }
  __syncthreads();
  #pragma unroll
  for (int i = 0; i < 32; ++i)
    zlds[(ndbase + i) * 64 + lane] = zacc[i];             // z2
  __syncthreads();
  // ---- ph5: gather2 -> x2 ----
  {
    float psum = 0.f;
    gather_pair(zacc, cb, psum);
    __syncthreads();
    #pragma unroll
    for (int i = 0; i < 32; ++i)
      zlds[(ndbase + i) * 64 + lane] = zacc[i];           // x2
    wpf[w * 64 + lane] = psum;
    __syncthreads();
    if (t < 64) {
      float s = 0.f;
      #pragma unroll
      for (int ww = 0; ww < 16; ++ww) s += wpf[ww*64 + t];
      xsl[64 + t] = s * (1.f/512.f);
    }
    __syncthreads();
  }
  // ---- ph6: pool0 ----
  {
    float* zs     = wpf;
    float* swl    = wpf + 512;
    float* sscore = wpf + 1024;
    const float pwrv = pwr[lane], pwlv = pwl[lane];
    for (int nd = w; nd < 512; nd += 16) {
      const float v = zlds[nd*64 + lane];
      float a = v * pwrv, b = v * pwlv;
      #pragma unroll
      for (int off = 32; off > 0; off >>= 1) {
        a += __shfl_xor(a, off);
        b += __shfl_xor(b, off);
      }
      if (lane == 0) { zs[nd] = a; swl[nd] = b; }
    }
    __syncthreads();
    if (t < 512) {
      const unsigned int s = start[t], d = hist[t];
      float a0 = 0.f, a1 = 0.f, a2 = 0.f, a3 = 0.f;
      unsigned int j = 0;
      for (; j + 4 <= d; j += 4) {
        a0 += zs[csrbuf[s+j]];   a1 += zs[csrbuf[s+j+1]];
        a2 += zs[csrbuf[s+j+2]]; a3 += zs[csrbuf[s+j+3]];
      }
      for (; j < d; ++j) a0 += zs[csrbuf[s+j]];
      sscore[t] = ((a0+a1)+(a2+a3)) / fmaxf((float)d, 1.f) + pb[0] + swl[t];
    }
    __syncthreads();                 // hist/start & csr dead
    unsigned long long k = 0ull;
    if (t < 512) {
      unsigned int u = __float_as_uint(sscore[t]);
      u = (u & 0x80000000u) ? ~u : (u | 0x80000000u);
      k = ((unsigned long long)u << 32) | (unsigned int)(~(unsigned int)t);
    }
    for (int kk = 2; kk <= 512; kk <<= 1) {
      for (int j = kk >> 1; j > 0; j >>= 1) {
        if (j >= 64) {
          if (t < 512) u2[t] = k;
          __syncthreads();
          unsigned long long kp = 0ull;
          if (t < 512) kp = u2[t ^ j];
          __syncthreads();
          if (t < 512) {
            const bool keep_max = (((t & kk) == 0) == ((t & j) == 0));
            k = keep_max ? (k >= kp ? k : kp) : (k >= kp ? kp : k);
          }
        } else if (t < 512) {
          const unsigned int lo = __shfl_xor((unsigned int)k, j);
          const unsigned int hi = __shfl_xor((unsigned int)(k >> 32), j);
          const unsigned long long kp = ((unsigned long long)hi << 32) | lo;
          const bool keep_max = (((t & kk) == 0) == ((t & j) == 0));
          k = keep_max ? (k >= kp ? k : kp) : (k >= kp ? kp : k);
        }
      }
    }
    if (t < 512) u2[t] = k;
    __syncthreads();
    unsigned long long* keys = u2;
    short* np = reinterpret_cast<short*>(csrbuf);
    if (t < 512) np[t] = -1;
    __syncthreads();
    if (t < 57)
      np[(int)(~(unsigned int)(keys[t] & 0xffffffffull))] = (short)t;
    __syncthreads();
    float xr[4];
    int nr = 0;
    for (int r = w * 4; r < w * 4 + 4 && r < 57; ++r) {
      const int old = (int)(~(unsigned int)(keys[r] & 0xffffffffull));
      xr[nr++] = zlds[old*64 + lane] * tanhf(sscore[old]);
    }
    if (t < 64) wpf[t] = 0.f;        // deg
    if (t == 0) scnt = 0;
    __syncthreads();
    nr = 0;
    for (int r = w * 4; r < w * 4 + 4 && r < 57; ++r)
      zlds[r*64 + lane] = xr[nr++];  // X57
    unsigned int* eb = reinterpret_cast<unsigned int*>(zlds + 16384);
    for (int e = t; e < EPG; e += 1024) {
      const int sl = esrc[ebase + e] - gbase;
      const int dl = edst[ebase + e] - gbase;
      const int ns = np[sl], nd2 = np[dl];
      if (ns >= 0 && nd2 >= 0) {
        const int slot = atomicAdd(&scnt, 1);
        eb[slot] = (unsigned int)ns | ((unsigned int)nd2 << 16);
        atomicAdd(&wpf[nd2], 1.f);
      }
    }
    __syncthreads();
  }
  const int m0 = scnt;
  // ---- ph7: tail ----
  float* X   = zlds;
  float* Z   = zlds + 4096;
  float* ACC = zlds + 8192;
  float* deg = wpf;
  unsigned int* eb  = reinterpret_cast<unsigned int*>(zlds + 16384);
  unsigned int* eb1 = reinterpret_cast<unsigned int*>(zlds + 24576);

  auto conv57 = [&](int n, const unsigned int* edges, int m,
                    const float* Wr, const float* Wl, const float* bias,
                    int xs_off) {
    float* Wfull = zlds + 12288;
    for (int i = t; i < n*64; i += 1024) ACC[i] = 0.f;
    #pragma unroll
    for (int i = 0; i < 4; ++i) Wfull[t + i*1024] = Wr[t + i*1024];
    __syncthreads();
    for (int r = w; r < n; r += 16) {
      float za = 0.f;
      for (int k = 0; k < 64; ++k)
        za = fmaf(X[r*64 + k], Wfull[k*64 + lane], za);
      Z[r*64 + lane] = za;
    }
    __syncthreads();
    for (int e = w; e < m; e += 16) {
      const unsigned int pr = edges[e];
      atomicAdd(&ACC[(pr >> 16)*64 + lane], Z[(pr & 0xffff)*64 + lane]);
    }
    #pragma unroll
    for (int i = 0; i < 4; ++i) Wfull[t + i*1024] = Wl[t + i*1024];
    __syncthreads();
    for (int i = t; i < n*64; i += 1024) {
      const int r = i >> 6, f = i & 63;
      Z[i] = ACC[i] / fmaxf(deg[r], 1.f) + bias[f];
    }
    __syncthreads();
    float psum = 0.f;
    for (int r = w; r < n; r += 16) {
      float za = Z[r*64 + lane];
      for (int k = 0; k < 64; ++k)
        za = fmaf(X[r*64 + k], Wfull[k*64 + lane], za);
      za = fmaxf(za, 0.f);
      X[r*64 + lane] = za;
      psum += za;
    }
    ACC[w*64 + lane] = psum;
    __syncthreads();
    if (t < 64) {
      float s = 0.f;
      #pragma unroll
      for (int ww = 0; ww < 16; ++ww) s += ACC[ww*64 + t];
      xsl[xs_off + t] = s / (float)n;
    }
    __syncthreads();
  };

  conv57(57, eb, m0, cWr + 4096, cWl + 4096, cb + 64, 128);
  conv57(57, eb, m0, cWr + 8192, cWl + 8192, cb + 128, 192);

  // ---- pool1: 57 -> 7 ----
  {
    float* zs1 = wpf + 1536;
    float* sw1 = wpf + 1600;
    float* ss1 = wpf + 1664;
    const float pwrv = pwr[64 + lane], pwlv = pwl[64 + lane];
    for (int r = w; r < 57; r += 16) {
      float a = X[r*64 + lane] * pwrv, b = X[r*64 + lane] * pwlv;
      #pragma unroll
      for (int off = 32; off > 0; off >>= 1) {
        a += __shfl_xor(a, off);
        b += __shfl_xor(b, off);
      }
      if (lane == 0) { zs1[r] = a; sw1[r] = b; }
    }
    if (t >= 64 && t < 128) ACC[t - 64] = 0.f;
    __syncthreads();
    for (int e = t; e < m0; e += 1024) {
      const unsigned int pr = eb[e];
      atomicAdd(&ACC[pr >> 16], zs1[pr & 0xffff]);
    }
    __syncthreads();
    if (t < 57) ss1[t] = ACC[t] / fmaxf(deg[t], 1.f) + pb[1] + sw1[t];
    __syncthreads();
    if (w == 0) {
      unsigned long long k1 = 0ull;
      if (lane < 57) {
        unsigned int u = __float_as_uint(ss1[lane]);
        u = (u & 0x80000000u) ? ~u : (u | 0x80000000u);
        k1 = ((unsigned long long)u << 32) | (unsigned int)(~(unsigned int)lane);
      }
      for (int kk = 2; kk <= 64; kk <<= 1) {
        for (int j = kk >> 1; j > 0; j >>= 1) {
          const unsigned int lo = __shfl_xor((unsigned int)k1, j);
          const unsigned int hi = __shfl_xor((unsigned int)(k1 >> 32), j);
          const unsigned long long kp = ((unsigned long long)hi << 32) | lo;
          const bool keep_max = (((lane & kk) == 0) == ((lane & j) == 0));
          k1 = keep_max ? (k1 >= kp ? k1 : kp) : (k1 >= kp ? kp : k1);
        }
      }
      u2[lane] = k1;
    }
    __syncthreads();
    unsigned long long* keys = u2;
    short* np1 = reinterpret_cast<short*>(csrbuf);
    if (t < 64) np1[t] = -1;
    __syncthreads();
    if (t < 7)
      np1[(int)(~(unsigned int)(keys[t] & 0xffffffffull))] = (short)t;
    __syncthreads();
    float xv7 = 0.f;
    if (w < 7) {
      const int old7 = (int)(~(unsigned int)(keys[w] & 0xffffffffull));
      xv7 = X[old7*64 + lane] * tanhf(ss1[old7]);
    }
    if (t < 64) deg[t] = 0.f;
    if (t == 0) scnt = 0;
    __syncthreads();
    if (w < 7) X[w*64 + lane] = xv7;
    for (int e = t; e < m0; e += 1024) {
      const unsigned int pr = eb[e];
      const int ns = np1[pr & 0xffff], nd2 = np1[pr >> 16];
      if (ns >= 0 && nd2 >= 0) {
        const int slot = atomicAdd(&scnt, 1);
        eb1[slot] = (unsigned int)ns | ((unsigned int)nd2 << 16);
        atomicAdd(&deg[nd2], 1.f);
      }
    }
    __syncthreads();
  }
  const int m1 = scnt;

  conv57(7, eb1, m1, cWr + 12288, cWl + 12288, cb + 192, 256);
  conv57(7, eb1, m1, cWr + 16384, cWl + 16384, cb + 256, 320);

  // ---- ph8: head ----
  if (t < 64) {
    float acc = l1b[t];
    for (int j = 0; j < 384; ++j) acc = fmaf(xsl[j], l1W[j*64 + t], acc);
    wpf[t] = fmaxf(acc, 0.f);
  }
  __syncthreads();
  if (t < 2) {
    float a2 = l2b[t];
    for (int f2 = 0; f2 < 64; ++f2) a2 = fmaf(wpf[f2], l2W[f2*2 + t], a2);
    wpf[64 + t] = a2;
  }
  __syncthreads();
  if (t < 2) {
    const float mx = fmaxf(wpf[64], wpf[65]);
    const float lse = mx + logf(expf(wpf[64]-mx) + expf(wpf[65]-mx));
    out[g*2 + t] = wpf[64 + t] - lse;
  }
}

// ============================================================================
extern "C" void kernel_launch(void* const* d_in, const int* in_sizes, int n_in,
                              void* d_out, int out_size, void* d_ws, size_t ws_size,
                              hipStream_t stream)
{
  (void)in_sizes; (void)n_in; (void)d_ws; (void)ws_size; (void)out_size;
  const float* x    = (const float*)d_in[0];
  const int*   ei   = (const int*)d_in[1];
  const float* c1Wr = (const float*)d_in[2];
  const float* c1Wl = (const float*)d_in[3];
  const float* c1b  = (const float*)d_in[4];
  const float* cWr  = (const float*)d_in[5];
  const float* cWl  = (const float*)d_in[6];
  const float* cb   = (const float*)d_in[7];
  const float* pWr  = (const float*)d_in[8];
  const float* pWl  = (const float*)d_in[9];
  const float* pb   = (const float*)d_in[10];
  const float* l1W  = (const float*)d_in[11];
  const float* l1b  = (const float*)d_in[12];
  const float* l2W  = (const float*)d_in[13];
  const float* l2b  = (const float*)d_in[14];
  float* out = (float*)d_out;
  const int* esrc = ei;
  const int* edst = ei + ETOT;

  mono<<<NB, 1024, 0, stream>>>(x, esrc, edst, c1Wr, c1Wl, c1b,
                                cWr, cWl, cb, pWr, pWl, pb,
                                l1W, l1b, l2W, l2b, out);
}